// Round 1
// baseline (6887.888 us; speedup 1.0000x reference)
//
#include <hip/hip_runtime.h>

// ---------------------------------------------------------------------------
// M3Care forward, f32 correctness-first implementation.
// N=2048 samples, D=256, T=32 time steps, NE=34 tokens, heads=(4,1).
// ---------------------------------------------------------------------------

#define NN 2048
#define DD 256
#define LTOK 34

// ---------------- block reduce (blockDim.x == 256) ----------------
__device__ __forceinline__ float block_reduce_sum256(float v, float* red) {
    for (int o = 32; o > 0; o >>= 1) v += __shfl_down(v, o, 64);
    int tid = threadIdx.x;
    if ((tid & 63) == 0) red[tid >> 6] = v;
    __syncthreads();
    float s = red[0] + red[1] + red[2] + red[3];
    __syncthreads();
    return s;
}

// ---------------- generic tiled f32 GEMM: C (= or +=) A[M,K]@B[K,N] + bias, relu
// Requires M%64==0, N%64==0, K%16==0 (all call sites comply).
template <bool ADD, bool BIAS, bool RELU>
__global__ __launch_bounds__(256) void gemm_f32(
    const float* __restrict__ A, const float* __restrict__ B,
    const float* __restrict__ bias, float* __restrict__ C,
    int M, int N, int K)
{
    __shared__ float As[16][68];
    __shared__ float Bs[16][68];
    const int bm = blockIdx.y * 64, bn = blockIdx.x * 64;
    const int tid = threadIdx.x;
    const int tx = tid & 15, ty = tid >> 4;
    const int mA = tid >> 2, kqA = (tid & 3) * 4;
    const int kB = tid >> 4, nqB = (tid & 15) * 4;
    float acc[4][4] = {};
    for (int k0 = 0; k0 < K; k0 += 16) {
        float4 va = *(const float4*)(A + (size_t)(bm + mA) * K + k0 + kqA);
        float4 vb = *(const float4*)(B + (size_t)(k0 + kB) * N + bn + nqB);
        As[kqA + 0][mA] = va.x; As[kqA + 1][mA] = va.y;
        As[kqA + 2][mA] = va.z; As[kqA + 3][mA] = va.w;
        Bs[kB][nqB + 0] = vb.x; Bs[kB][nqB + 1] = vb.y;
        Bs[kB][nqB + 2] = vb.z; Bs[kB][nqB + 3] = vb.w;
        __syncthreads();
#pragma unroll
        for (int kk = 0; kk < 16; ++kk) {
            float a[4], b[4];
#pragma unroll
            for (int i = 0; i < 4; ++i) a[i] = As[kk][ty * 4 + i];
#pragma unroll
            for (int j = 0; j < 4; ++j) b[j] = Bs[kk][tx * 4 + j];
#pragma unroll
            for (int i = 0; i < 4; ++i)
#pragma unroll
                for (int j = 0; j < 4; ++j)
                    acc[i][j] = fmaf(a[i], b[j], acc[i][j]);
        }
        __syncthreads();
    }
#pragma unroll
    for (int i = 0; i < 4; ++i) {
        int row = bm + ty * 4 + i;
#pragma unroll
        for (int j = 0; j < 4; ++j) {
            int col = bn + tx * 4 + j;
            float v = acc[i][j];
            if (BIAS) v += bias[col];
            size_t idx = (size_t)row * N + col;
            if (ADD) v += C[idx];
            if (RELU) v = fmaxf(v, 0.f);
            C[idx] = v;
        }
    }
}

// ---------------- pairwise squared-L2: D[i,j] = max(sq[i]+sq[j]-2*x_i.x_j,0),
// plus per-block partial sums for the bandwidth scalar. X is [2048,256].
__global__ __launch_bounds__(256) void dist_nt(
    const float* __restrict__ X, const float* __restrict__ sq,
    float* __restrict__ Dm, float* __restrict__ part)
{
    __shared__ float As[16][68], Bs[16][68];
    __shared__ float red[8];
    const int bi = blockIdx.y * 64, bj = blockIdx.x * 64;
    const int tid = threadIdx.x, tx = tid & 15, ty = tid >> 4;
    const int mA = tid >> 2, kq = (tid & 3) * 4;
    float acc[4][4] = {};
    for (int k0 = 0; k0 < 256; k0 += 16) {
        float4 va = *(const float4*)(X + (size_t)(bi + mA) * 256 + k0 + kq);
        float4 vb = *(const float4*)(X + (size_t)(bj + mA) * 256 + k0 + kq);
        As[kq + 0][mA] = va.x; As[kq + 1][mA] = va.y;
        As[kq + 2][mA] = va.z; As[kq + 3][mA] = va.w;
        Bs[kq + 0][mA] = vb.x; Bs[kq + 1][mA] = vb.y;
        Bs[kq + 2][mA] = vb.z; Bs[kq + 3][mA] = vb.w;
        __syncthreads();
#pragma unroll
        for (int kk = 0; kk < 16; ++kk) {
            float a[4], b[4];
#pragma unroll
            for (int i = 0; i < 4; ++i) a[i] = As[kk][ty * 4 + i];
#pragma unroll
            for (int j = 0; j < 4; ++j) b[j] = Bs[kk][tx * 4 + j];
#pragma unroll
            for (int i = 0; i < 4; ++i)
#pragma unroll
                for (int j = 0; j < 4; ++j)
                    acc[i][j] = fmaf(a[i], b[j], acc[i][j]);
        }
        __syncthreads();
    }
    float lsum = 0.f;
#pragma unroll
    for (int i = 0; i < 4; ++i) {
        int gi = bi + ty * 4 + i;
#pragma unroll
        for (int j = 0; j < 4; ++j) {
            int gj = bj + tx * 4 + j;
            float d = fmaxf(sq[gi] + sq[gj] - 2.f * acc[i][j], 0.f);
            Dm[(size_t)gi * NN + gj] = d;
            lsum += d;
        }
    }
    float bs = block_reduce_sum256(lsum, red);
    if (tid == 0) part[blockIdx.y * gridDim.x + blockIdx.x] = bs;
}

// ---------------- multi-bandwidth Gaussian kernel, in place on G
__global__ void gk_exp(float* __restrict__ G, const float* __restrict__ bwsum) {
    size_t idx = (size_t)blockIdx.x * 256 + threadIdx.x;
    float bw = bwsum[0] * (1.f / ((float)NN * NN - (float)NN)) * 0.5f; // / (n^2-n) / 2
    float i0 = 1.f / bw;
    float d = G[idx];
    G[idx] = expf(-d * i0) + expf(-d * (0.5f * i0)) + expf(-d * (0.25f * i0));
}

// ---------------- sim_sum accumulation
template <bool FIRST>
__global__ void sim_accum(const float* __restrict__ Gw, const float* __restrict__ Ge,
                          const int* __restrict__ mk, const float* __restrict__ epsp,
                          float* __restrict__ S) {
    size_t idx = (size_t)blockIdx.x * 256 + threadIdx.x;
    int i = (int)(idx >> 11), j = (int)(idx & (NN - 1));
    float eps = 1.f / (1.f + expf(-epsp[0]));
    float v = ((1.f - eps) * Gw[idx] + eps) * Ge[idx];
    v = (mk[i] && mk[j]) ? v : 0.f;
    S[idx] = FIRST ? v : S[idx] + v;
}

// ---------------- aggregation + threshold gate, in place on S
__global__ void agg_k(float* __restrict__ S, const int* __restrict__ mk0,
                      const int* __restrict__ mk1, const int* __restrict__ mk2,
                      const float* __restrict__ dissim) {
    size_t idx = (size_t)blockIdx.x * 256 + threadIdx.x;
    int i = (int)(idx >> 11), j = (int)(idx & (NN - 1));
    float thr = 1.f / (1.f + expf(-dissim[0]));
    int cnt = ((mk0[i] && mk0[j]) ? 1 : 0) + ((mk1[i] && mk1[j]) ? 1 : 0) +
              ((mk2[i] && mk2[j]) ? 1 : 0);
    float a = cnt ? S[idx] / (float)cnt : 0.f;
    S[idx] = (a > thr) ? a : 0.f;
}

// ---------------- BatchNorm column stats (mean/var over rows), optional relu on input
template <bool RELU_IN>
__global__ __launch_bounds__(256) void colstats(const float* __restrict__ X,
                                                float* __restrict__ mv, int nrows) {
    __shared__ float red[8];
    int c = blockIdx.x, tid = threadIdx.x;
    float s = 0.f, sq = 0.f;
    for (int r = tid; r < nrows; r += 256) {
        float v = X[(size_t)r * DD + c];
        if (RELU_IN) v = fmaxf(v, 0.f);
        s += v; sq += v * v;
    }
    float ts = block_reduce_sum256(s, red);
    float tq = block_reduce_sum256(sq, red);
    if (tid == 0) {
        float m = ts / (float)nrows;
        mv[c] = m;
        mv[DD + c] = tq / (float)nrows - m * m;
    }
}

template <bool RELU_IN>
__global__ void bn_apply(const float* __restrict__ X, const float* __restrict__ mv,
                         const float* __restrict__ g, const float* __restrict__ b,
                         float* __restrict__ Y) {
    int idx = blockIdx.x * 256 + threadIdx.x;
    int c = idx & (DD - 1);
    float v = X[idx];
    if (RELU_IN) v = fmaxf(v, 0.f);
    Y[idx] = (v - mv[c]) * rsqrtf(mv[DD + c] + 1e-5f) * g[c] + b[c];
}

__global__ __launch_bounds__(256) void rowsq(const float* __restrict__ X,
                                             float* __restrict__ SQ) {
    __shared__ float red[8];
    int r = blockIdx.x, tid = threadIdx.x;
    float v = X[(size_t)r * DD + tid];
    float s = block_reduce_sum256(v * v, red);
    if (tid == 0) SQ[r] = s;
}

// ---------------- sum-of-squares partial + tree reduce (deterministic, no atomics)
__global__ __launch_bounds__(256) void sumsq_partial(const float* __restrict__ X, int n,
                                                     float* __restrict__ part) {
    __shared__ float red[8];
    int tid = threadIdx.x;
    float s = 0.f;
    for (size_t idx = (size_t)blockIdx.x * 256 + tid; idx < (size_t)n;
         idx += (size_t)gridDim.x * 256) {
        float v = X[idx];
        s += v * v;
    }
    float bs = block_reduce_sum256(s, red);
    if (tid == 0) part[blockIdx.x] = bs;
}

__global__ __launch_bounds__(256) void reduce_sum(const float* __restrict__ part, int n,
                                                  float* __restrict__ dst) {
    __shared__ float red[8];
    int tid = threadIdx.x;
    float s = 0.f;
    for (int i = tid; i < n; i += 256) s += part[i];
    float bs = block_reduce_sum256(s, red);
    if (tid == 0) dst[0] = bs;
}

// ---------------- adapt-gate imputation (one block per sample)
__global__ __launch_bounds__(256) void impute_k(
    const float* __restrict__ E, const float* __restrict__ H,
    const float* __restrict__ aw, const float* __restrict__ ab,
    const int* __restrict__ mk, float* __restrict__ OUT) {
    __shared__ float red[8];
    int i = blockIdx.x, tid = threadIdx.x;
    float e = E[(size_t)i * DD + tid], h = H[(size_t)i * DD + tid], w = aw[tid];
    float se = block_reduce_sum256(e * w, red);
    float sh = block_reduce_sum256(h * w, red);
    float s = 1.f / (1.f + expf(-(se + ab[0])));
    float o = 1.f / (1.f + expf(-(sh + ab[0])));
    s = s / (s + o);
    float imp = s * e + (1.f - s) * h;
    float m = mk[i] ? 1.f : 0.f;
    OUT[(size_t)i * DD + tid] = imp * m + (1.f - m) * h;
}

// ---------------- mask dtype detection + normalization --------------------
// msk1 is all-ones by construction: int32 read -> 1; uint8 read as int -> 0x01010101;
// f32 read -> 1.0f. Store mode in an int slot of scratch.
__global__ void detect_mode(const void* __restrict__ m1, int* __restrict__ modep) {
    if (threadIdx.x == 0 && blockIdx.x == 0) {
        int vi = ((const int*)m1)[0];
        float vf = ((const float*)m1)[0];
        modep[0] = (vi == 1) ? 0 : ((vf == 1.0f) ? 2 : 1);
    }
}

__device__ __forceinline__ int rd_mask(const void* p, int idx, int mode) {
    if (mode == 0) return ((const int*)p)[idx] != 0;
    if (mode == 1) return ((const unsigned char*)p)[idx] != 0;
    return ((const float*)p)[idx] != 0.f;
}

__global__ void build_masks(const void* __restrict__ m0, const void* __restrict__ m1,
                            const void* __restrict__ m2, const int* __restrict__ modep,
                            int* __restrict__ MK, int* __restrict__ TOK) {
    int mode = modep[0];
    int idx = blockIdx.x * 256 + threadIdx.x;
    if (idx < NN) {
        MK[idx] = rd_mask(m0, idx * 32, mode);
        MK[NN + idx] = rd_mask(m1, idx, mode);
        MK[2 * NN + idx] = rd_mask(m2, idx, mode);
    }
    if (idx < NN * LTOK) {
        int i = idx / LTOK, t = idx - i * LTOK;
        TOK[idx] = (t < 32) ? rd_mask(m0, i * 32 + t, mode)
                            : ((t == 32) ? rd_mask(m1, i, mode) : rd_mask(m2, i, mode));
    }
}

// ---------------- misc gather / token-sequence build ----------------------
__global__ void gather_e0(const float* __restrict__ emb0, float* __restrict__ E0) {
    int i = blockIdx.x, c = threadIdx.x;
    E0[(size_t)i * DD + c] = emb0[(size_t)i * 32 * DD + c];
}

__global__ void build_z(const float* __restrict__ emb0, const float* __restrict__ i0,
                        const float* __restrict__ i1, const float* __restrict__ i2,
                        const float* __restrict__ type_emb, float* __restrict__ Z) {
    size_t idx = (size_t)blockIdx.x * 256 + threadIdx.x;
    int c = (int)(idx & (DD - 1));
    int t = (int)((idx >> 8) % LTOK);
    int i = (int)(idx / (LTOK * DD));
    float v;
    if (t < 32) {
        float base = (t == 0) ? i0[(size_t)i * DD + c]
                              : emb0[((size_t)i * 32 + t) * DD + c];
        int k2 = (c >> 1) * 2;  // arange(0, D, 2) value
        float div = expf((float)k2 * (-9.210340371976184f / 256.f));
        float ang = (float)t * div;
        float pe = (c & 1) ? cosf(ang) : sinf(ang);
        v = base + type_emb[c] + pe;
    } else if (t == 32) {
        v = i1[(size_t)i * DD + c] + type_emb[DD + c];
    } else {
        v = i2[(size_t)i * DD + c] + type_emb[2 * DD + c];
    }
    Z[idx] = v;
}

// ---------------- fused attention for one (sample, head) ------------------
template <int DH>
__global__ __launch_bounds__(256) void attn_fused(
    const float* __restrict__ Q, const float* __restrict__ K,
    const float* __restrict__ V, const int* __restrict__ tok,
    float* __restrict__ O, int sample0) {
    const int L = LTOK;
    __shared__ float Qs[L * DH], Ks[L * DH], Vs[L * DH];
    __shared__ float Sc[L][L + 2];
    int b = blockIdx.x, hh = blockIdx.y;
    int tid = threadIdx.x;
    const float scale = rsqrtf((float)DH);
    for (int idx = tid; idx < L * DH; idx += 256) {
        int t = idx / DH, d = idx - t * DH;
        size_t g = (size_t)(b * L + t) * DD + hh * DH + d;
        Qs[idx] = Q[g]; Ks[idx] = K[g]; Vs[idx] = V[g];
    }
    __syncthreads();
    const int* tk = tok + (size_t)(sample0 + b) * L;
    for (int idx = tid; idx < L * L; idx += 256) {
        int i = idx / L, j = idx - i * L;
        float acc = 0.f;
#pragma unroll 8
        for (int d = 0; d < DH; ++d) acc = fmaf(Qs[i * DH + d], Ks[j * DH + d], acc);
        Sc[i][j] = (tk[i] && tk[j]) ? acc * scale : -1e9f;
    }
    __syncthreads();
    if (tid < L) {  // serial softmax per row: 34x34 is tiny
        float mx = -1e30f;
        for (int j = 0; j < L; ++j) mx = fmaxf(mx, Sc[tid][j]);
        float s = 0.f;
        for (int j = 0; j < L; ++j) {
            float e = expf(Sc[tid][j] - mx);
            Sc[tid][j] = e; s += e;
        }
        float inv = 1.f / s;
        for (int j = 0; j < L; ++j) Sc[tid][j] *= inv;
    }
    __syncthreads();
    for (int idx = tid; idx < L * DH; idx += 256) {
        int i = idx / DH, d = idx - i * DH;
        float acc = 0.f;
        for (int j = 0; j < L; ++j) acc = fmaf(Sc[i][j], Vs[j * DH + d], acc);
        O[(size_t)(b * L + i) * DD + hh * DH + d] = acc;
    }
}

// ---------------- residual-free in-place LayerNorm (row = 256 features) ----
template <bool RELU>
__global__ __launch_bounds__(256) void ln_inplace(float* __restrict__ Z,
                                                  const float* __restrict__ g,
                                                  const float* __restrict__ b) {
    __shared__ float red[8];
    size_t row = blockIdx.x;
    float* z = Z + row * DD;
    int tid = threadIdx.x;
    float x = z[tid];
    float mean = block_reduce_sum256(x, red) * (1.f / 256.f);
    float d = x - mean;
    float var = block_reduce_sum256(d * d, red) * (1.f / 256.f);
    float y = d * rsqrtf(var + 1e-5f) * g[tid] + b[tid];
    if (RELU) y = fmaxf(y, 0.f);
    z[tid] = y;
}

// ---------------- final head: y[i] = dot(Y1[i,:512], w) + b ---------------
__global__ __launch_bounds__(256) void head2(const float* __restrict__ Y1,
                                             const float* __restrict__ w,
                                             const float* __restrict__ b,
                                             float* __restrict__ out) {
    __shared__ float red[8];
    int i = blockIdx.x, tid = threadIdx.x;
    float s = Y1[(size_t)i * 512 + tid] * w[tid] +
              Y1[(size_t)i * 512 + 256 + tid] * w[256 + tid];
    float bs = block_reduce_sum256(s, red);
    if (tid == 0) out[i] = bs + b[0];
}

__global__ void lstab_k(const float* __restrict__ SC, float* __restrict__ dst) {
    if (threadIdx.x == 0 && blockIdx.x == 0) {
        float s = 0.f;
        for (int m = 0; m < 3; ++m)
            s += fabsf(sqrtf(SC[6 + m]) - sqrtf(SC[9 + m]));
        dst[0] = s;
    }
}

// ===========================================================================
#define LAUNCH_GEMM(ADD_, BIAS_, RELU_, A_, B_, BI_, C_, M_, N_, K_)            \
    gemm_f32<ADD_, BIAS_, RELU_>                                                \
        <<<dim3((N_) / 64, (M_) / 64), 256, 0, stream>>>((A_), (B_), (BI_),     \
                                                         (C_), (M_), (N_), (K_))

extern "C" void kernel_launch(void* const* d_in, const int* in_sizes, int n_in,
                              void* d_out, int out_size, void* d_ws, size_t ws_size,
                              hipStream_t stream) {
    (void)in_sizes; (void)n_in; (void)out_size; (void)ws_size;
    const float* emb0 = (const float*)d_in[0];
    const float* emb1 = (const float*)d_in[1];
    const float* emb2 = (const float*)d_in[2];
    const void* msk0 = d_in[3];
    const void* msk1 = d_in[4];
    const void* msk2 = d_in[5];
    const float* simi_w = (const float*)d_in[6];
    const float* simi_b = (const float*)d_in[7];
    const float* bn_g = (const float*)d_in[8];
    const float* bn_b = (const float*)d_in[9];
    const float* simi_eps = (const float*)d_in[10];
    const float* dissim = (const float*)d_in[11];
    const float* gcn_w = (const float*)d_in[12];
    const float* gcn_b = (const float*)d_in[13];
    const float* adapt_w = (const float*)d_in[14];
    const float* adapt_b = (const float*)d_in[15];
    const float* type_emb = (const float*)d_in[16];
    const float* attn_w = (const float*)d_in[17];
    const float* attn_b = (const float*)d_in[18];
    const float* ffn_w1 = (const float*)d_in[19];
    const float* ffn_b1 = (const float*)d_in[20];
    const float* ffn_w2 = (const float*)d_in[21];
    const float* ffn_b2 = (const float*)d_in[22];
    const float* ln_g = (const float*)d_in[23];
    const float* ln_b = (const float*)d_in[24];
    const float* out_w1 = (const float*)d_in[25];
    const float* out_b1 = (const float*)d_in[26];
    const float* out_w2 = (const float*)d_in[27];
    const float* out_b2 = (const float*)d_in[28];
    float* out = (float*)d_out;

    // ---- workspace layout (same every call; ~187 MB total) ----
    char* wp = (char*)d_ws;
    auto alloc = [&](size_t bytes) -> char* {
        char* p = wp;
        wp += (bytes + 255) & ~(size_t)255;
        return p;
    };
    float* Z = (float*)alloc((size_t)NN * LTOK * DD * 4);     // 71.3 MB
    char* UN = alloc((size_t)8704 * 1024 * 4);                // 35.7 MB union
    float* Qc = (float*)UN;
    float* Kc = (float*)(UN + (size_t)8704 * 256 * 4);
    float* Vc = (float*)(UN + (size_t)8704 * 256 * 8);
    float* Oc = (float*)(UN + (size_t)8704 * 256 * 12);
    float* Hf = (float*)UN;                                   // FFN hidden chunk
    float* G1 = (float*)alloc((size_t)NN * NN * 4);           // 16 MB
    float* G2 = (float*)alloc((size_t)NN * NN * 4);
    float* S = (float*)alloc((size_t)NN * NN * 4);            // sim_sum -> agg
    float* E0 = (float*)alloc((size_t)NN * DD * 4);
    float* P = (float*)alloc((size_t)NN * DD * 4);
    float* T1 = (float*)alloc((size_t)NN * DD * 4);
    float* T2 = (float*)alloc((size_t)NN * DD * 4);
    float* XB = (float*)alloc((size_t)NN * DD * 4);
    float* TB = (float*)alloc((size_t)NN * DD * 4);
    float* HB = (float*)alloc((size_t)NN * DD * 4);
    float* TB2 = (float*)alloc((size_t)NN * DD * 4);
    float* HB2 = (float*)alloc((size_t)NN * DD * 4);
    float* I0 = (float*)alloc((size_t)NN * DD * 4);
    float* I1 = (float*)alloc((size_t)NN * DD * 4);
    float* I2 = (float*)alloc((size_t)NN * DD * 4);
    float* Y1 = (float*)alloc((size_t)NN * 512 * 4);
    float* MV = (float*)alloc(512 * 4);
    float* SQ = (float*)alloc(NN * 4);
    float* PART = (float*)alloc(2048 * 4);
    float* SC = (float*)alloc(64 * 4);  // scalar slots: 0/1 bw, 6..8 |p|^2, 9..11 |e|^2, 16 mask-mode
    int* TOK = (int*)alloc((size_t)NN * LTOK * 4);
    int* MK = (int*)alloc((size_t)3 * NN * 4);

    // ---- prep ----
    gather_e0<<<NN, 256, 0, stream>>>(emb0, E0);
    detect_mode<<<1, 64, 0, stream>>>(msk1, (int*)SC + 16);
    build_masks<<<(NN * LTOK + 255) / 256, 256, 0, stream>>>(msk0, msk1, msk2,
                                                             (int*)SC + 16, MK, TOK);

    const float* Eptr[3] = {E0, emb1, emb2};

    // ---- Stage A: per-modal similarity kernels ----
    for (int m = 0; m < 3; ++m) {
        const float* E = Eptr[m];
        LAUNCH_GEMM(false, true, true, E, simi_w + (size_t)(m * 3 + 0) * 65536,
                    simi_b + (m * 3 + 0) * 256, T1, NN, 256, 256);
        LAUNCH_GEMM(false, true, true, T1, simi_w + (size_t)(m * 3 + 1) * 65536,
                    simi_b + (m * 3 + 1) * 256, T2, NN, 256, 256);
        LAUNCH_GEMM(false, true, false, T2, simi_w + (size_t)(m * 3 + 2) * 65536,
                    simi_b + (m * 3 + 2) * 256, P, NN, 256, 256);
        sumsq_partial<<<512, 256, 0, stream>>>(P, NN * DD, PART);
        reduce_sum<<<1, 256, 0, stream>>>(PART, 512, SC + 6 + m);
        sumsq_partial<<<512, 256, 0, stream>>>(E, NN * DD, PART);
        reduce_sum<<<1, 256, 0, stream>>>(PART, 512, SC + 9 + m);
        // wgk = gk(bn(relu(p)))
        colstats<true><<<256, 256, 0, stream>>>(P, MV, NN);
        bn_apply<true><<<NN, 256, 0, stream>>>(P, MV, bn_g, bn_b, XB);
        rowsq<<<NN, 256, 0, stream>>>(XB, SQ);
        dist_nt<<<dim3(32, 32), 256, 0, stream>>>(XB, SQ, G1, PART);
        reduce_sum<<<1, 256, 0, stream>>>(PART, 1024, SC + 0);
        gk_exp<<<NN * NN / 256, 256, 0, stream>>>(G1, SC + 0);
        // gk = gk(bn(e))
        colstats<false><<<256, 256, 0, stream>>>(E, MV, NN);
        bn_apply<false><<<NN, 256, 0, stream>>>(E, MV, bn_g, bn_b, XB);
        rowsq<<<NN, 256, 0, stream>>>(XB, SQ);
        dist_nt<<<dim3(32, 32), 256, 0, stream>>>(XB, SQ, G2, PART);
        reduce_sum<<<1, 256, 0, stream>>>(PART, 1024, SC + 1);
        gk_exp<<<NN * NN / 256, 256, 0, stream>>>(G2, SC + 1);
        if (m == 0)
            sim_accum<true><<<NN * NN / 256, 256, 0, stream>>>(G1, G2, MK, simi_eps + m, S);
        else
            sim_accum<false><<<NN * NN / 256, 256, 0, stream>>>(G1, G2, MK + m * NN,
                                                                simi_eps + m, S);
    }

    // ---- Stage B: aggregation + GCN imputation ----
    agg_k<<<NN * NN / 256, 256, 0, stream>>>(S, MK, MK + NN, MK + 2 * NN, dissim);
    float* IMP[3] = {I0, I1, I2};
    for (int m = 0; m < 3; ++m) {
        LAUNCH_GEMM(false, false, false, Eptr[m], gcn_w + (size_t)(m * 2 + 0) * 65536,
                    (const float*)nullptr, TB, NN, 256, 256);
        LAUNCH_GEMM(false, true, true, S, TB, gcn_b + (m * 2 + 0) * 256, HB, NN, 256, NN);
        LAUNCH_GEMM(false, false, false, HB, gcn_w + (size_t)(m * 2 + 1) * 65536,
                    (const float*)nullptr, TB2, NN, 256, 256);
        LAUNCH_GEMM(false, true, true, S, TB2, gcn_b + (m * 2 + 1) * 256, HB2, NN, 256, NN);
        impute_k<<<NN, 256, 0, stream>>>(Eptr[m], HB2, adapt_w + m * 256, adapt_b + m,
                                         MK + m * NN, IMP[m]);
    }

    // ---- Stage C: 34-token transformer ----
    build_z<<<NN * LTOK, 256, 0, stream>>>(emb0, I0, I1, I2, type_emb, Z);
    const int CH = 256, NCHUNK = NN / CH;       // 8 chunks of 8704 rows
    const int CROWS = CH * LTOK;                // 8704
    for (int li = 0; li < 2; ++li) {
        const float* wq = attn_w + (size_t)(li * 4 + 0) * 65536;
        const float* wk = attn_w + (size_t)(li * 4 + 1) * 65536;
        const float* wv = attn_w + (size_t)(li * 4 + 2) * 65536;
        const float* wo = attn_w + (size_t)(li * 4 + 3) * 65536;
        for (int c = 0; c < NCHUNK; ++c) {
            float* Zc = Z + (size_t)c * CROWS * DD;
            LAUNCH_GEMM(false, true, false, Zc, wq, attn_b + (li * 4 + 0) * 256, Qc,
                        CROWS, 256, 256);
            LAUNCH_GEMM(false, true, false, Zc, wk, attn_b + (li * 4 + 1) * 256, Kc,
                        CROWS, 256, 256);
            LAUNCH_GEMM(false, true, false, Zc, wv, attn_b + (li * 4 + 2) * 256, Vc,
                        CROWS, 256, 256);
            if (li == 0)
                attn_fused<64><<<dim3(CH, 4), 256, 0, stream>>>(Qc, Kc, Vc, TOK, Oc, c * CH);
            else
                attn_fused<256><<<dim3(CH, 1), 256, 0, stream>>>(Qc, Kc, Vc, TOK, Oc, c * CH);
            // residual: Z += Oc @ Wo + bo
            LAUNCH_GEMM(true, true, false, Oc, wo, attn_b + (li * 4 + 3) * 256, Zc,
                        CROWS, 256, 256);
        }
        ln_inplace<false><<<NN * LTOK, 256, 0, stream>>>(Z, ln_g + (li * 2 + 0) * 256,
                                                         ln_b + (li * 2 + 0) * 256);
        for (int c = 0; c < NCHUNK; ++c) {
            float* Zc = Z + (size_t)c * CROWS * DD;
            LAUNCH_GEMM(false, true, true, Zc, ffn_w1 + (size_t)li * 262144,
                        ffn_b1 + li * 1024, Hf, CROWS, 1024, 256);
            // residual: Z += H @ W2 + b2
            LAUNCH_GEMM(true, true, false, Hf, ffn_w2 + (size_t)li * 262144,
                        ffn_b2 + li * 256, Zc, CROWS, 256, 1024);
        }
        ln_inplace<true><<<NN * LTOK, 256, 0, stream>>>(Z, ln_g + (li * 2 + 1) * 256,
                                                        ln_b + (li * 2 + 1) * 256);
    }

    // ---- head ----
    LAUNCH_GEMM(false, true, true, Z, out_w1, out_b1, Y1, NN, 512, LTOK * DD);
    head2<<<NN, 256, 0, stream>>>(Y1, out_w2, out_b2, out);
    lstab_k<<<1, 64, 0, stream>>>(SC, out + NN);
}

// Round 2
// 2593.386 us; speedup vs baseline: 2.6559x; 2.6559x over previous
//
#include <hip/hip_runtime.h>
#include <hip/hip_bf16.h>

// ---------------------------------------------------------------------------
// M3Care forward — bf16 MFMA GEMMs, f32 elsewhere.
// N=2048 samples, D=256, T=32 steps, NE=34 tokens, heads=(4,1).
// ---------------------------------------------------------------------------

#define NN 2048
#define DD 256
#define LTOK 34

typedef __attribute__((ext_vector_type(8))) short bf16x8;
typedef __attribute__((ext_vector_type(4))) float f32x4;

__device__ __forceinline__ float bf2f(__hip_bfloat16 x) { return __bfloat162float(x); }
__device__ __forceinline__ __hip_bfloat16 f2bf(float x) { return __float2bfloat16(x); }

// ---------------- block reduce (blockDim.x == 256) ----------------
__device__ __forceinline__ float block_reduce_sum256(float v, float* red) {
    for (int o = 32; o > 0; o >>= 1) v += __shfl_down(v, o, 64);
    int tid = threadIdx.x;
    if ((tid & 63) == 0) red[tid >> 6] = v;
    __syncthreads();
    float s = red[0] + red[1] + red[2] + red[3];
    __syncthreads();
    return s;
}

// ---------------------------------------------------------------------------
// bf16 MFMA GEMM: C[M,N] = op(A[M,K] @ Bt[N,K]^T + bias)
// OUTM: 0 = f32 out, 1 = bf16 out, 2 = bf16 transposed out [N,M],
//       3 = bf16 in-place add (C += result)
// Requires M%128==0, N%128==0, K%64==0 (all call sites comply).
// LDS tiles 128x64 bf16, XOR-swizzled 16B slots (slot ^= row&7) to kill the
// 8-way bank conflict of 128B-row ds_read_b128 (G4 recipe).
// ---------------------------------------------------------------------------
template <int OUTM, bool BIAS, bool RELU>
__global__ __launch_bounds__(256) void gemm_mfma(
    const ushort* __restrict__ A, const ushort* __restrict__ Bt,
    const float* __restrict__ bias, void* __restrict__ Cout,
    int M, int N, int K)
{
    __shared__ __align__(16) ushort As[128 * 64];
    __shared__ __align__(16) ushort Bs[128 * 64];
    const int bm = blockIdx.y * 128, bn = blockIdx.x * 128;
    const int tid = threadIdx.x;
    const int l = tid & 63, wv = tid >> 6;
    const int wr = wv >> 1, wc = wv & 1;     // 2x2 wave grid, 64x64 each
    const int l16 = l >> 4, lr = l & 15;
    f32x4 zero = {0.f, 0.f, 0.f, 0.f};
    f32x4 acc[4][4];
#pragma unroll
    for (int i = 0; i < 4; ++i)
#pragma unroll
        for (int j = 0; j < 4; ++j) acc[i][j] = zero;

    for (int k0 = 0; k0 < K; k0 += 64) {
#pragma unroll
        for (int c = 0; c < 4; ++c) {
            int idx = c * 256 + tid;
            int row = idx >> 3, s = idx & 7;
            int lo = row * 64 + ((s ^ (row & 7)) * 8);
            *(bf16x8*)(As + lo) =
                *(const bf16x8*)(A + (size_t)(bm + row) * K + k0 + s * 8);
            *(bf16x8*)(Bs + lo) =
                *(const bf16x8*)(Bt + (size_t)(bn + row) * K + k0 + s * 8);
        }
        __syncthreads();
#pragma unroll
        for (int kk = 0; kk < 2; ++kk) {
            bf16x8 av[4], bv[4];
#pragma unroll
            for (int f = 0; f < 4; ++f) {
                int ra = wr * 64 + f * 16 + lr;
                av[f] = *(const bf16x8*)(As + ra * 64 + (((kk * 4 + l16) ^ (ra & 7)) * 8));
                int rb = wc * 64 + f * 16 + lr;
                bv[f] = *(const bf16x8*)(Bs + rb * 64 + (((kk * 4 + l16) ^ (rb & 7)) * 8));
            }
#pragma unroll
            for (int mf = 0; mf < 4; ++mf)
#pragma unroll
                for (int nf = 0; nf < 4; ++nf)
                    acc[mf][nf] = __builtin_amdgcn_mfma_f32_16x16x32_bf16(
                        av[mf], bv[nf], acc[mf][nf], 0, 0, 0);
        }
        __syncthreads();
    }
    // epilogue: C/D layout col=lane&15, row=(lane>>4)*4+reg  [m89-verified]
#pragma unroll
    for (int mf = 0; mf < 4; ++mf) {
#pragma unroll
        for (int nf = 0; nf < 4; ++nf) {
            int col = bn + wc * 64 + nf * 16 + lr;
            float bb = BIAS ? bias[col] : 0.f;
#pragma unroll
            for (int r = 0; r < 4; ++r) {
                int row = bm + wr * 64 + mf * 16 + l16 * 4 + r;
                float v = acc[mf][nf][r] + bb;
                if (OUTM == 3)
                    v += bf2f(((const __hip_bfloat16*)Cout)[(size_t)row * N + col]);
                if (RELU) v = fmaxf(v, 0.f);
                if (OUTM == 0)
                    ((float*)Cout)[(size_t)row * N + col] = v;
                else if (OUTM == 2)
                    ((__hip_bfloat16*)Cout)[(size_t)col * M + row] = f2bf(v);
                else
                    ((__hip_bfloat16*)Cout)[(size_t)row * N + col] = f2bf(v);
            }
        }
    }
}

// ---------------------------------------------------------------------------
// Pairwise distance via MFMA: G[i,j] = max(sq[i]+sq[j]-2*x_i.x_j, 0),
// fused per-block partial sums. X bf16 [2048,256]. Grid (16,16).
// ---------------------------------------------------------------------------
__global__ __launch_bounds__(256) void gemm_dist(
    const ushort* __restrict__ X, const float* __restrict__ sq,
    float* __restrict__ G, float* __restrict__ part)
{
    __shared__ __align__(16) ushort As[128 * 64];
    __shared__ __align__(16) ushort Bs[128 * 64];
    __shared__ float red[8];
    const int bm = blockIdx.y * 128, bn = blockIdx.x * 128;
    const int tid = threadIdx.x;
    const int l = tid & 63, wv = tid >> 6;
    const int wr = wv >> 1, wc = wv & 1;
    const int l16 = l >> 4, lr = l & 15;
    f32x4 zero = {0.f, 0.f, 0.f, 0.f};
    f32x4 acc[4][4];
#pragma unroll
    for (int i = 0; i < 4; ++i)
#pragma unroll
        for (int j = 0; j < 4; ++j) acc[i][j] = zero;

    for (int k0 = 0; k0 < 256; k0 += 64) {
#pragma unroll
        for (int c = 0; c < 4; ++c) {
            int idx = c * 256 + tid;
            int row = idx >> 3, s = idx & 7;
            int lo = row * 64 + ((s ^ (row & 7)) * 8);
            *(bf16x8*)(As + lo) =
                *(const bf16x8*)(X + (size_t)(bm + row) * 256 + k0 + s * 8);
            *(bf16x8*)(Bs + lo) =
                *(const bf16x8*)(X + (size_t)(bn + row) * 256 + k0 + s * 8);
        }
        __syncthreads();
#pragma unroll
        for (int kk = 0; kk < 2; ++kk) {
            bf16x8 av[4], bv[4];
#pragma unroll
            for (int f = 0; f < 4; ++f) {
                int ra = wr * 64 + f * 16 + lr;
                av[f] = *(const bf16x8*)(As + ra * 64 + (((kk * 4 + l16) ^ (ra & 7)) * 8));
                int rb = wc * 64 + f * 16 + lr;
                bv[f] = *(const bf16x8*)(Bs + rb * 64 + (((kk * 4 + l16) ^ (rb & 7)) * 8));
            }
#pragma unroll
            for (int mf = 0; mf < 4; ++mf)
#pragma unroll
                for (int nf = 0; nf < 4; ++nf)
                    acc[mf][nf] = __builtin_amdgcn_mfma_f32_16x16x32_bf16(
                        av[mf], bv[nf], acc[mf][nf], 0, 0, 0);
        }
        __syncthreads();
    }
    float lsum = 0.f;
#pragma unroll
    for (int mf = 0; mf < 4; ++mf) {
#pragma unroll
        for (int nf = 0; nf < 4; ++nf) {
            int col = bn + wc * 64 + nf * 16 + lr;
#pragma unroll
            for (int r = 0; r < 4; ++r) {
                int row = bm + wr * 64 + mf * 16 + l16 * 4 + r;
                float d = fmaxf(sq[row] + sq[col] - 2.f * acc[mf][nf][r], 0.f);
                G[(size_t)row * NN + col] = d;
                lsum += d;
            }
        }
    }
    float bs = block_reduce_sum256(lsum, red);
    if (tid == 0) part[blockIdx.y * gridDim.x + blockIdx.x] = bs;
}

// ---------------- conversions ----------------
__global__ void cvt_flat(const float* __restrict__ in, __hip_bfloat16* __restrict__ out,
                         int n4) {
    int i = blockIdx.x * 256 + threadIdx.x;
    if (i < n4) {
        float4 v = ((const float4*)in)[i];
        union { __hip_bfloat16 h[4]; ushort4 u; } pk;
        pk.h[0] = f2bf(v.x); pk.h[1] = f2bf(v.y);
        pk.h[2] = f2bf(v.z); pk.h[3] = f2bf(v.w);
        ((ushort4*)out)[i] = pk.u;
    }
}

// f32 [R,C] -> bf16 [C,R]; R,C multiples of 32.
__global__ __launch_bounds__(256) void cvt_trans(const float* __restrict__ in,
                                                 __hip_bfloat16* __restrict__ out,
                                                 int R, int C) {
    __shared__ float t[32][33];
    int bc = blockIdx.x * 32, br = blockIdx.y * 32;
    int tx = threadIdx.x & 31, ty = threadIdx.x >> 5;  // ty 0..7
#pragma unroll
    for (int i = 0; i < 32; i += 8)
        t[ty + i][tx] = in[(size_t)(br + ty + i) * C + bc + tx];
    __syncthreads();
#pragma unroll
    for (int i = 0; i < 32; i += 8)
        out[(size_t)(bc + ty + i) * R + br + tx] = f2bf(t[tx][ty + i]);
}

// ---------------- multi-bandwidth Gaussian kernel, in place on G
__global__ void gk_exp(float* __restrict__ G, const float* __restrict__ bwsum) {
    size_t idx = (size_t)blockIdx.x * 256 + threadIdx.x;
    float bw = bwsum[0] * (1.f / ((float)NN * NN - (float)NN)) * 0.5f;
    float i0 = 1.f / bw;
    float d = G[idx];
    G[idx] = __expf(-d * i0) + __expf(-d * (0.5f * i0)) + __expf(-d * (0.25f * i0));
}

// ---------------- sim_sum accumulation
template <bool FIRST>
__global__ void sim_accum(const float* __restrict__ Gw, const float* __restrict__ Ge,
                          const int* __restrict__ mk, const float* __restrict__ epsp,
                          float* __restrict__ S) {
    size_t idx = (size_t)blockIdx.x * 256 + threadIdx.x;
    int i = (int)(idx >> 11), j = (int)(idx & (NN - 1));
    float eps = 1.f / (1.f + __expf(-epsp[0]));
    float v = ((1.f - eps) * Gw[idx] + eps) * Ge[idx];
    v = (mk[i] && mk[j]) ? v : 0.f;
    S[idx] = FIRST ? v : S[idx] + v;
}

// ---------------- aggregation + threshold gate, in place on S
__global__ void agg_k(float* __restrict__ S, const int* __restrict__ mk0,
                      const int* __restrict__ mk1, const int* __restrict__ mk2,
                      const float* __restrict__ dissim) {
    size_t idx = (size_t)blockIdx.x * 256 + threadIdx.x;
    int i = (int)(idx >> 11), j = (int)(idx & (NN - 1));
    float thr = 1.f / (1.f + __expf(-dissim[0]));
    int cnt = ((mk0[i] && mk0[j]) ? 1 : 0) + ((mk1[i] && mk1[j]) ? 1 : 0) +
              ((mk2[i] && mk2[j]) ? 1 : 0);
    float a = cnt ? S[idx] / (float)cnt : 0.f;
    S[idx] = (a > thr) ? a : 0.f;
}

// ---------------- BatchNorm column stats (f32 input)
template <bool RELU_IN>
__global__ __launch_bounds__(256) void colstats(const float* __restrict__ X,
                                                float* __restrict__ mv, int nrows) {
    __shared__ float red[8];
    int c = blockIdx.x, tid = threadIdx.x;
    float s = 0.f, sq = 0.f;
    for (int r = tid; r < nrows; r += 256) {
        float v = X[(size_t)r * DD + c];
        if (RELU_IN) v = fmaxf(v, 0.f);
        s += v; sq += v * v;
    }
    float ts = block_reduce_sum256(s, red);
    float tq = block_reduce_sum256(sq, red);
    if (tid == 0) {
        float m = ts / (float)nrows;
        mv[c] = m;
        mv[DD + c] = tq / (float)nrows - m * m;
    }
}

// f32 in -> bf16 out (BN-normalized)
template <bool RELU_IN>
__global__ void bn_apply(const float* __restrict__ X, const float* __restrict__ mv,
                         const float* __restrict__ g, const float* __restrict__ b,
                         __hip_bfloat16* __restrict__ Y) {
    int idx = blockIdx.x * 256 + threadIdx.x;
    int c = idx & (DD - 1);
    float v = X[idx];
    if (RELU_IN) v = fmaxf(v, 0.f);
    Y[idx] = f2bf((v - mv[c]) * rsqrtf(mv[DD + c] + 1e-5f) * g[c] + b[c]);
}

__global__ __launch_bounds__(256) void rowsq(const __hip_bfloat16* __restrict__ X,
                                             float* __restrict__ SQ) {
    __shared__ float red[8];
    int r = blockIdx.x, tid = threadIdx.x;
    float v = bf2f(X[(size_t)r * DD + tid]);
    float s = block_reduce_sum256(v * v, red);
    if (tid == 0) SQ[r] = s;
}

// ---------------- sum-of-squares partial + tree reduce (deterministic)
__global__ __launch_bounds__(256) void sumsq_partial(const float* __restrict__ X, int n,
                                                     float* __restrict__ part) {
    __shared__ float red[8];
    int tid = threadIdx.x;
    float s = 0.f;
    for (size_t idx = (size_t)blockIdx.x * 256 + tid; idx < (size_t)n;
         idx += (size_t)gridDim.x * 256) {
        float v = X[idx];
        s += v * v;
    }
    float bs = block_reduce_sum256(s, red);
    if (tid == 0) part[blockIdx.x] = bs;
}

__global__ __launch_bounds__(256) void reduce_sum(const float* __restrict__ part, int n,
                                                  float* __restrict__ dst) {
    __shared__ float red[8];
    int tid = threadIdx.x;
    float s = 0.f;
    for (int i = tid; i < n; i += 256) s += part[i];
    float bs = block_reduce_sum256(s, red);
    if (tid == 0) dst[0] = bs;
}

// ---------------- adapt-gate imputation (one block per sample)
__global__ __launch_bounds__(256) void impute_k(
    const float* __restrict__ E, const __hip_bfloat16* __restrict__ H,
    const float* __restrict__ aw, const float* __restrict__ ab,
    const int* __restrict__ mk, float* __restrict__ OUT) {
    __shared__ float red[8];
    int i = blockIdx.x, tid = threadIdx.x;
    float e = E[(size_t)i * DD + tid], h = bf2f(H[(size_t)i * DD + tid]), w = aw[tid];
    float se = block_reduce_sum256(e * w, red);
    float sh = block_reduce_sum256(h * w, red);
    float s = 1.f / (1.f + __expf(-(se + ab[0])));
    float o = 1.f / (1.f + __expf(-(sh + ab[0])));
    s = s / (s + o);
    float imp = s * e + (1.f - s) * h;
    float m = mk[i] ? 1.f : 0.f;
    OUT[(size_t)i * DD + tid] = imp * m + (1.f - m) * h;
}

// ---------------- mask dtype detection + normalization --------------------
__global__ void detect_mode(const void* __restrict__ m1, int* __restrict__ modep) {
    if (threadIdx.x == 0 && blockIdx.x == 0) {
        int vi = ((const int*)m1)[0];
        float vf = ((const float*)m1)[0];
        modep[0] = (vi == 1) ? 0 : ((vf == 1.0f) ? 2 : 1);
    }
}

__device__ __forceinline__ int rd_mask(const void* p, int idx, int mode) {
    if (mode == 0) return ((const int*)p)[idx] != 0;
    if (mode == 1) return ((const unsigned char*)p)[idx] != 0;
    return ((const float*)p)[idx] != 0.f;
}

__global__ void build_masks(const void* __restrict__ m0, const void* __restrict__ m1,
                            const void* __restrict__ m2, const int* __restrict__ modep,
                            int* __restrict__ MK, int* __restrict__ TOK) {
    int mode = modep[0];
    int idx = blockIdx.x * 256 + threadIdx.x;
    if (idx < NN) {
        MK[idx] = rd_mask(m0, idx * 32, mode);
        MK[NN + idx] = rd_mask(m1, idx, mode);
        MK[2 * NN + idx] = rd_mask(m2, idx, mode);
    }
    if (idx < NN * LTOK) {
        int i = idx / LTOK, t = idx - i * LTOK;
        TOK[idx] = (t < 32) ? rd_mask(m0, i * 32 + t, mode)
                            : ((t == 32) ? rd_mask(m1, i, mode) : rd_mask(m2, i, mode));
    }
}

// ---------------- gather emb0[:,0,:] (f32 + bf16) ----------------
__global__ void gather_e0(const float* __restrict__ emb0, float* __restrict__ E0,
                          __hip_bfloat16* __restrict__ E0b) {
    int i = blockIdx.x, c = threadIdx.x;
    float v = emb0[(size_t)i * 32 * DD + c];
    E0[(size_t)i * DD + c] = v;
    E0b[(size_t)i * DD + c] = f2bf(v);
}

__global__ void build_z(const float* __restrict__ emb0, const float* __restrict__ i0,
                        const float* __restrict__ i1, const float* __restrict__ i2,
                        const float* __restrict__ type_emb,
                        __hip_bfloat16* __restrict__ Z) {
    size_t idx = (size_t)blockIdx.x * 256 + threadIdx.x;
    int c = (int)(idx & (DD - 1));
    int t = (int)((idx >> 8) % LTOK);
    int i = (int)(idx / (LTOK * DD));
    float v;
    if (t < 32) {
        float base = (t == 0) ? i0[(size_t)i * DD + c]
                              : emb0[((size_t)i * 32 + t) * DD + c];
        int k2 = (c >> 1) * 2;
        float div = expf((float)k2 * (-9.210340371976184f / 256.f));
        float ang = (float)t * div;
        float pe = (c & 1) ? cosf(ang) : sinf(ang);
        v = base + type_emb[c] + pe;
    } else if (t == 32) {
        v = i1[(size_t)i * DD + c] + type_emb[DD + c];
    } else {
        v = i2[(size_t)i * DD + c] + type_emb[2 * DD + c];
    }
    Z[idx] = f2bf(v);
}

// ---------------- fused attention; QKV packed [rows,768], O [rows,256] ----
template <int DH>
__global__ __launch_bounds__(256) void attn_fused(
    const __hip_bfloat16* __restrict__ QKV, const int* __restrict__ tok,
    __hip_bfloat16* __restrict__ O, int sample0) {
    const int L = LTOK;
    __shared__ float Qs[L * DH], Ks[L * DH], Vs[L * DH];
    __shared__ float Sc[L][L + 2];
    int b = blockIdx.x, hh = blockIdx.y;
    int tid = threadIdx.x;
    const float scale = rsqrtf((float)DH);
    for (int idx = tid; idx < L * DH; idx += 256) {
        int t = idx / DH, d = idx - t * DH;
        size_t g = (size_t)(b * L + t) * 768 + hh * DH + d;
        Qs[idx] = bf2f(QKV[g]);
        Ks[idx] = bf2f(QKV[g + 256]);
        Vs[idx] = bf2f(QKV[g + 512]);
    }
    __syncthreads();
    const int* tk = tok + (size_t)(sample0 + b) * L;
    for (int idx = tid; idx < L * L; idx += 256) {
        int i = idx / L, j = idx - i * L;
        float acc = 0.f;
#pragma unroll 8
        for (int d = 0; d < DH; ++d) acc = fmaf(Qs[i * DH + d], Ks[j * DH + d], acc);
        Sc[i][j] = (tk[i] && tk[j]) ? acc * scale : -1e9f;
    }
    __syncthreads();
    if (tid < L) {
        float mx = -1e30f;
        for (int j = 0; j < L; ++j) mx = fmaxf(mx, Sc[tid][j]);
        float s = 0.f;
        for (int j = 0; j < L; ++j) {
            float e = expf(Sc[tid][j] - mx);
            Sc[tid][j] = e; s += e;
        }
        float inv = 1.f / s;
        for (int j = 0; j < L; ++j) Sc[tid][j] *= inv;
    }
    __syncthreads();
    for (int idx = tid; idx < L * DH; idx += 256) {
        int i = idx / DH, d = idx - i * DH;
        float acc = 0.f;
        for (int j = 0; j < L; ++j) acc = fmaf(Sc[i][j], Vs[j * DH + d], acc);
        O[(size_t)(b * L + i) * DD + hh * DH + d] = f2bf(acc);
    }
}

// ---------------- in-place LayerNorm on bf16 rows of 256 ----
template <bool RELU>
__global__ __launch_bounds__(256) void ln_inplace(__hip_bfloat16* __restrict__ Z,
                                                  const float* __restrict__ g,
                                                  const float* __restrict__ b) {
    __shared__ float red[8];
    size_t row = blockIdx.x;
    __hip_bfloat16* z = Z + row * DD;
    int tid = threadIdx.x;
    float x = bf2f(z[tid]);
    float mean = block_reduce_sum256(x, red) * (1.f / 256.f);
    float d = x - mean;
    float var = block_reduce_sum256(d * d, red) * (1.f / 256.f);
    float y = d * rsqrtf(var + 1e-5f) * g[tid] + b[tid];
    if (RELU) y = fmaxf(y, 0.f);
    z[tid] = f2bf(y);
}

// ---------------- final head ----------------
__global__ __launch_bounds__(256) void head2(const __hip_bfloat16* __restrict__ Y1,
                                             const float* __restrict__ w,
                                             const float* __restrict__ b,
                                             float* __restrict__ out) {
    __shared__ float red[8];
    int i = blockIdx.x, tid = threadIdx.x;
    float s = bf2f(Y1[(size_t)i * 512 + tid]) * w[tid] +
              bf2f(Y1[(size_t)i * 512 + 256 + tid]) * w[256 + tid];
    float bs = block_reduce_sum256(s, red);
    if (tid == 0) out[i] = bs + b[0];
}

__global__ void lstab_k(const float* __restrict__ SC, float* __restrict__ dst) {
    if (threadIdx.x == 0 && blockIdx.x == 0) {
        float s = 0.f;
        for (int m = 0; m < 3; ++m)
            s += fabsf(sqrtf(SC[6 + m]) - sqrtf(SC[9 + m]));
        dst[0] = s;
    }
}

// ===========================================================================
#define GEMM(OUTM_, BIAS_, RELU_, A_, Bt_, BI_, C_, M_, N_, K_)                 \
    gemm_mfma<OUTM_, BIAS_, RELU_>                                              \
        <<<dim3((N_) / 128, (M_) / 128), 256, 0, stream>>>(                     \
            (const ushort*)(A_), (const ushort*)(Bt_), (BI_), (void*)(C_),      \
            (M_), (N_), (K_))

extern "C" void kernel_launch(void* const* d_in, const int* in_sizes, int n_in,
                              void* d_out, int out_size, void* d_ws, size_t ws_size,
                              hipStream_t stream) {
    (void)in_sizes; (void)n_in; (void)out_size; (void)ws_size;
    const float* emb0 = (const float*)d_in[0];
    const float* emb1 = (const float*)d_in[1];
    const float* emb2 = (const float*)d_in[2];
    const void* msk0 = d_in[3];
    const void* msk1 = d_in[4];
    const void* msk2 = d_in[5];
    const float* simi_w = (const float*)d_in[6];
    const float* simi_b = (const float*)d_in[7];
    const float* bn_g = (const float*)d_in[8];
    const float* bn_b = (const float*)d_in[9];
    const float* simi_eps = (const float*)d_in[10];
    const float* dissim = (const float*)d_in[11];
    const float* gcn_w = (const float*)d_in[12];
    const float* gcn_b = (const float*)d_in[13];
    const float* adapt_w = (const float*)d_in[14];
    const float* adapt_b = (const float*)d_in[15];
    const float* type_emb = (const float*)d_in[16];
    const float* attn_w = (const float*)d_in[17];
    const float* attn_b = (const float*)d_in[18];
    const float* ffn_w1 = (const float*)d_in[19];
    const float* ffn_b1 = (const float*)d_in[20];
    const float* ffn_w2 = (const float*)d_in[21];
    const float* ffn_b2 = (const float*)d_in[22];
    const float* ln_g = (const float*)d_in[23];
    const float* ln_b = (const float*)d_in[24];
    const float* out_w1 = (const float*)d_in[25];
    const float* out_b1 = (const float*)d_in[26];
    const float* out_w2 = (const float*)d_in[27];
    const float* out_b2 = (const float*)d_in[28];
    float* out = (float*)d_out;

    // ---- workspace layout (~167 MB) ----
    char* wp = (char*)d_ws;
    auto alloc = [&](size_t bytes) -> char* {
        char* p = wp;
        wp += (bytes + 255) & ~(size_t)255;
        return p;
    };
    const int ACH = 512, ACROWS = ACH * LTOK;  // 17408 rows per chunk, 4 chunks
    __hip_bfloat16* Zb = (__hip_bfloat16*)alloc((size_t)NN * LTOK * DD * 2);  // 35.7MB
    char* UN = alloc((size_t)ACROWS * 1024 * 2);                              // 35.7MB union
    __hip_bfloat16* QKVb = (__hip_bfloat16*)UN;                        // 17408x768
    __hip_bfloat16* Ob = (__hip_bfloat16*)(UN + (size_t)ACROWS * 768 * 2);
    __hip_bfloat16* Hfb = (__hip_bfloat16*)UN;                         // 17408x1024
    float* G1 = (float*)alloc((size_t)NN * NN * 4);
    float* G2 = (float*)alloc((size_t)NN * NN * 4);
    float* S = (float*)alloc((size_t)NN * NN * 4);
    __hip_bfloat16* Sb = (__hip_bfloat16*)alloc((size_t)NN * NN * 2);
    float* P = (float*)alloc((size_t)NN * DD * 4);
    float* E0 = (float*)alloc((size_t)NN * DD * 4);
    __hip_bfloat16* E0b = (__hip_bfloat16*)alloc((size_t)NN * DD * 2);
    __hip_bfloat16* e1b = (__hip_bfloat16*)alloc((size_t)NN * DD * 2);
    __hip_bfloat16* e2b = (__hip_bfloat16*)alloc((size_t)NN * DD * 2);
    __hip_bfloat16* T1b = (__hip_bfloat16*)alloc((size_t)NN * DD * 2);
    __hip_bfloat16* T2b = (__hip_bfloat16*)alloc((size_t)NN * DD * 2);
    __hip_bfloat16* XBb = (__hip_bfloat16*)alloc((size_t)NN * DD * 2);
    __hip_bfloat16* TBt = (__hip_bfloat16*)alloc((size_t)NN * DD * 2);
    __hip_bfloat16* TB2t = (__hip_bfloat16*)alloc((size_t)NN * DD * 2);
    __hip_bfloat16* HBb = (__hip_bfloat16*)alloc((size_t)NN * DD * 2);
    __hip_bfloat16* HB2b = (__hip_bfloat16*)alloc((size_t)NN * DD * 2);
    float* I0 = (float*)alloc((size_t)NN * DD * 4);
    float* I1 = (float*)alloc((size_t)NN * DD * 4);
    float* I2 = (float*)alloc((size_t)NN * DD * 4);
    __hip_bfloat16* Y1b = (__hip_bfloat16*)alloc((size_t)NN * 512 * 2);
    __hip_bfloat16* simi_wt = (__hip_bfloat16*)alloc((size_t)9 * 65536 * 2);
    __hip_bfloat16* gcn_wt = (__hip_bfloat16*)alloc((size_t)6 * 65536 * 2);
    __hip_bfloat16* attn_wt = (__hip_bfloat16*)alloc((size_t)8 * 65536 * 2);
    __hip_bfloat16* w1t = (__hip_bfloat16*)alloc((size_t)2 * 262144 * 2);
    __hip_bfloat16* w2t = (__hip_bfloat16*)alloc((size_t)2 * 262144 * 2);
    __hip_bfloat16* ow1t = (__hip_bfloat16*)alloc((size_t)8704 * 512 * 2);
    float* MV = (float*)alloc(512 * 4);
    float* SQ = (float*)alloc(NN * 4);
    float* PART = (float*)alloc(2048 * 4);
    float* SC = (float*)alloc(64 * 4);
    int* TOK = (int*)alloc((size_t)NN * LTOK * 4);
    int* MK = (int*)alloc((size_t)3 * NN * 4);

    // ---- weight transpose-convert (f32 [R,C] -> bf16 [C,R]) ----
    auto TR = [&](const float* src, __hip_bfloat16* dst, int R, int C) {
        cvt_trans<<<dim3(C / 32, R / 32), 256, 0, stream>>>(src, dst, R, C);
    };
    for (int i = 0; i < 9; ++i) TR(simi_w + (size_t)i * 65536, simi_wt + (size_t)i * 65536, 256, 256);
    for (int i = 0; i < 6; ++i) TR(gcn_w + (size_t)i * 65536, gcn_wt + (size_t)i * 65536, 256, 256);
    for (int i = 0; i < 8; ++i) TR(attn_w + (size_t)i * 65536, attn_wt + (size_t)i * 65536, 256, 256);
    for (int i = 0; i < 2; ++i) TR(ffn_w1 + (size_t)i * 262144, w1t + (size_t)i * 262144, 256, 1024);
    for (int i = 0; i < 2; ++i) TR(ffn_w2 + (size_t)i * 262144, w2t + (size_t)i * 262144, 1024, 256);
    TR(out_w1, ow1t, 8704, 512);

    // ---- prep ----
    gather_e0<<<NN, 256, 0, stream>>>(emb0, E0, E0b);
    cvt_flat<<<(NN * DD / 4 + 255) / 256, 256, 0, stream>>>(emb1, e1b, NN * DD / 4);
    cvt_flat<<<(NN * DD / 4 + 255) / 256, 256, 0, stream>>>(emb2, e2b, NN * DD / 4);
    detect_mode<<<1, 64, 0, stream>>>(msk1, (int*)SC + 16);
    build_masks<<<(NN * LTOK + 255) / 256, 256, 0, stream>>>(msk0, msk1, msk2,
                                                             (int*)SC + 16, MK, TOK);

    const float* Ef[3] = {E0, emb1, emb2};
    const __hip_bfloat16* Eb[3] = {E0b, e1b, e2b};

    // ---- Stage A: per-modal similarity kernels ----
    for (int m = 0; m < 3; ++m) {
        GEMM(1, true, true, Eb[m], simi_wt + (size_t)(m * 3 + 0) * 65536,
             simi_b + (m * 3 + 0) * 256, T1b, NN, 256, 256);
        GEMM(1, true, true, T1b, simi_wt + (size_t)(m * 3 + 1) * 65536,
             simi_b + (m * 3 + 1) * 256, T2b, NN, 256, 256);
        GEMM(0, true, false, T2b, simi_wt + (size_t)(m * 3 + 2) * 65536,
             simi_b + (m * 3 + 2) * 256, P, NN, 256, 256);
        sumsq_partial<<<512, 256, 0, stream>>>(P, NN * DD, PART);
        reduce_sum<<<1, 256, 0, stream>>>(PART, 512, SC + 6 + m);
        sumsq_partial<<<512, 256, 0, stream>>>(Ef[m], NN * DD, PART);
        reduce_sum<<<1, 256, 0, stream>>>(PART, 512, SC + 9 + m);
        // wgk = gk(bn(relu(p)))
        colstats<true><<<256, 256, 0, stream>>>(P, MV, NN);
        bn_apply<true><<<NN, 256, 0, stream>>>(P, MV, bn_g, bn_b, XBb);
        rowsq<<<NN, 256, 0, stream>>>(XBb, SQ);
        gemm_dist<<<dim3(16, 16), 256, 0, stream>>>((const ushort*)XBb, SQ, G1, PART);
        reduce_sum<<<1, 256, 0, stream>>>(PART, 256, SC + 0);
        gk_exp<<<NN * NN / 256, 256, 0, stream>>>(G1, SC + 0);
        // gk = gk(bn(e))
        colstats<false><<<256, 256, 0, stream>>>(Ef[m], MV, NN);
        bn_apply<false><<<NN, 256, 0, stream>>>(Ef[m], MV, bn_g, bn_b, XBb);
        rowsq<<<NN, 256, 0, stream>>>(XBb, SQ);
        gemm_dist<<<dim3(16, 16), 256, 0, stream>>>((const ushort*)XBb, SQ, G2, PART);
        reduce_sum<<<1, 256, 0, stream>>>(PART, 256, SC + 1);
        gk_exp<<<NN * NN / 256, 256, 0, stream>>>(G2, SC + 1);
        if (m == 0)
            sim_accum<true><<<NN * NN / 256, 256, 0, stream>>>(G1, G2, MK, simi_eps + m, S);
        else
            sim_accum<false><<<NN * NN / 256, 256, 0, stream>>>(G1, G2, MK + m * NN,
                                                                simi_eps + m, S);
    }

    // ---- Stage B: aggregation + GCN imputation ----
    agg_k<<<NN * NN / 256, 256, 0, stream>>>(S, MK, MK + NN, MK + 2 * NN, dissim);
    cvt_flat<<<(NN * NN / 4 + 255) / 256, 256, 0, stream>>>(S, Sb, NN * NN / 4);
    float* IMP[3] = {I0, I1, I2};
    for (int m = 0; m < 3; ++m) {
        GEMM(2, false, false, Eb[m], gcn_wt + (size_t)(m * 2 + 0) * 65536,
             (const float*)nullptr, TBt, NN, 256, 256);
        GEMM(1, true, true, Sb, TBt, gcn_b + (m * 2 + 0) * 256, HBb, NN, 256, NN);
        GEMM(2, false, false, HBb, gcn_wt + (size_t)(m * 2 + 1) * 65536,
             (const float*)nullptr, TB2t, NN, 256, 256);
        GEMM(1, true, true, Sb, TB2t, gcn_b + (m * 2 + 1) * 256, HB2b, NN, 256, NN);
        impute_k<<<NN, 256, 0, stream>>>(Ef[m], HB2b, adapt_w + m * 256, adapt_b + m,
                                         MK + m * NN, IMP[m]);
    }

    // ---- Stage C: 34-token transformer (bf16 Z) ----
    build_z<<<NN * LTOK, 256, 0, stream>>>(emb0, I0, I1, I2, type_emb, Zb);
    const int NCHUNK = NN / ACH;  // 4
    for (int li = 0; li < 2; ++li) {
        for (int c = 0; c < NCHUNK; ++c) {
            __hip_bfloat16* Zc = Zb + (size_t)c * ACROWS * DD;
            GEMM(1, true, false, Zc, attn_wt + (size_t)(li * 4) * 65536,
                 attn_b + li * 4 * 256, QKVb, ACROWS, 768, 256);
            if (li == 0)
                attn_fused<64><<<dim3(ACH, 4), 256, 0, stream>>>(QKVb, TOK, Ob, c * ACH);
            else
                attn_fused<256><<<dim3(ACH, 1), 256, 0, stream>>>(QKVb, TOK, Ob, c * ACH);
            GEMM(3, true, false, Ob, attn_wt + (size_t)(li * 4 + 3) * 65536,
                 attn_b + (li * 4 + 3) * 256, Zc, ACROWS, 256, 256);
        }
        ln_inplace<false><<<NN * LTOK, 256, 0, stream>>>(Zb, ln_g + (li * 2 + 0) * 256,
                                                         ln_b + (li * 2 + 0) * 256);
        for (int c = 0; c < NCHUNK; ++c) {
            __hip_bfloat16* Zc = Zb + (size_t)c * ACROWS * DD;
            GEMM(1, true, true, Zc, w1t + (size_t)li * 262144, ffn_b1 + li * 1024,
                 Hfb, ACROWS, 1024, 256);
            GEMM(3, true, false, Hfb, w2t + (size_t)li * 262144, ffn_b2 + li * 256,
                 Zc, ACROWS, 256, 1024);
        }
        ln_inplace<true><<<NN * LTOK, 256, 0, stream>>>(Zb, ln_g + (li * 2 + 1) * 256,
                                                        ln_b + (li * 2 + 1) * 256);
    }

    // ---- head ----
    GEMM(1, true, true, Zb, ow1t, out_b1, Y1b, NN, 512, LTOK * DD);
    head2<<<NN, 256, 0, stream>>>(Y1b, out_w2, out_b2, out);
    lstab_k<<<1, 64, 0, stream>>>(SC, out + NN);
}

// Round 3
// 2114.428 us; speedup vs baseline: 3.2576x; 1.2265x over previous
//
#include <hip/hip_runtime.h>
#include <hip/hip_bf16.h>

// ---------------------------------------------------------------------------
// M3Care forward — bf16 MFMA GEMMs (global_load_lds staging + XCD swizzle +
// split-K), fused elementwise. N=2048, D=256, T=32, NE=34 tokens, heads=(4,1).
// ---------------------------------------------------------------------------

#define NN 2048
#define DD 256
#define LTOK 34

typedef __attribute__((ext_vector_type(8))) short bf16x8;
typedef __attribute__((ext_vector_type(4))) float f32x4;

__device__ __forceinline__ float bf2f(__hip_bfloat16 x) { return __bfloat162float(x); }
__device__ __forceinline__ __hip_bfloat16 f2bf(float x) { return __float2bfloat16(x); }

// ---------------- block reduce (blockDim.x == 256) ----------------
__device__ __forceinline__ float block_reduce_sum256(float v, float* red) {
    for (int o = 32; o > 0; o >>= 1) v += __shfl_down(v, o, 64);
    int tid = threadIdx.x;
    if ((tid & 63) == 0) red[tid >> 6] = v;
    __syncthreads();
    float s = red[0] + red[1] + red[2] + red[3];
    __syncthreads();
    return s;
}

// XCD-chunked bijective remap (T1, m204 variant). nwg = gridDim.x*gridDim.y.
__device__ __forceinline__ int xcd_remap(int lin, int nwg) {
    int q = nwg >> 3, r = nwg & 7;
    int xcd = lin & 7, pos = lin >> 3;
    return (xcd < r ? xcd * (q + 1) : r * (q + 1) + (xcd - r) * q) + pos;
}

// Stage one 128x64 bf16 tile via global_load_lds (16B/lane), linear LDS dest,
// inverse-XOR-swizzled per-lane GLOBAL source (rule #21): LDS[row][s] gets
// source k-slot s^(row&7); the MFMA read applies the same XOR -> linear k.
__device__ __forceinline__ void stage_tile(const ushort* __restrict__ src,
                                           ushort* lds, int grow0, size_t ldk,
                                           int k0, int wv, int l) {
#pragma unroll
    for (int c = 0; c < 4; ++c) {
        int rowbase = wv * 32 + c * 8;
        int row = rowbase + (l >> 3);
        int sx = ((l & 7) ^ (row & 7)) * 8;
        __builtin_amdgcn_global_load_lds(
            (const __attribute__((address_space(1))) void*)(src + (size_t)(grow0 + row) * ldk + k0 + sx),
            (__attribute__((address_space(3))) void*)(lds + rowbase * 64), 16, 0, 0);
    }
}

// ---------------------------------------------------------------------------
// bf16 MFMA GEMM: C[M,N] = op(A[M,K] @ Bt[N,K]^T + bias)
// OUTM: 0 = f32 out (slice offset z*M*N for split-K), 1 = bf16 out,
//       2 = bf16 transposed out [N,M], 3 = bf16 in-place add.
// M%128==0, N%128==0, K%(64*gridDim.z)==0.
// ---------------------------------------------------------------------------
template <int OUTM, bool BIAS, bool RELU>
__global__ __launch_bounds__(256) void gemm_mfma(
    const ushort* __restrict__ A, const ushort* __restrict__ Bt,
    const float* __restrict__ bias, void* __restrict__ Cout,
    int M, int N, int K)
{
    __shared__ __align__(16) ushort As[128 * 64];
    __shared__ __align__(16) ushort Bs[128 * 64];
    const int gx = gridDim.x;
    int lin = xcd_remap(blockIdx.y * gx + blockIdx.x, gx * gridDim.y);
    const int bm = (lin / gx) * 128, bn = (lin % gx) * 128;
    const int tid = threadIdx.x;
    const int l = tid & 63, wv = tid >> 6;
    const int wr = wv >> 1, wc = wv & 1;     // 2x2 wave grid, 64x64 each
    const int l16 = l >> 4, lr = l & 15;
    const int kpz = K / gridDim.z;
    const int kbeg = blockIdx.z * kpz, kend = kbeg + kpz;
    f32x4 zero = {0.f, 0.f, 0.f, 0.f};
    f32x4 acc[4][4];
#pragma unroll
    for (int i = 0; i < 4; ++i)
#pragma unroll
        for (int j = 0; j < 4; ++j) acc[i][j] = zero;

    for (int k0 = kbeg; k0 < kend; k0 += 64) {
        stage_tile(A, As, bm, K, k0, wv, l);
        stage_tile(Bt, Bs, bn, K, k0, wv, l);
        __syncthreads();
#pragma unroll
        for (int kk = 0; kk < 2; ++kk) {
            bf16x8 av[4], bv[4];
#pragma unroll
            for (int f = 0; f < 4; ++f) {
                int ra = wr * 64 + f * 16 + lr;
                av[f] = *(const bf16x8*)(As + ra * 64 + (((kk * 4 + l16) ^ (ra & 7)) * 8));
                int rb = wc * 64 + f * 16 + lr;
                bv[f] = *(const bf16x8*)(Bs + rb * 64 + (((kk * 4 + l16) ^ (rb & 7)) * 8));
            }
#pragma unroll
            for (int mf = 0; mf < 4; ++mf)
#pragma unroll
                for (int nf = 0; nf < 4; ++nf)
                    acc[mf][nf] = __builtin_amdgcn_mfma_f32_16x16x32_bf16(
                        av[mf], bv[nf], acc[mf][nf], 0, 0, 0);
        }
        __syncthreads();
    }
    // epilogue: C/D layout col=lane&15, row=(lane>>4)*4+reg  [m89-verified]
    float* Cf = (float*)Cout + (size_t)blockIdx.z * M * N;
#pragma unroll
    for (int mf = 0; mf < 4; ++mf) {
#pragma unroll
        for (int nf = 0; nf < 4; ++nf) {
            int col = bn + wc * 64 + nf * 16 + lr;
            float bb = BIAS ? bias[col] : 0.f;
#pragma unroll
            for (int r = 0; r < 4; ++r) {
                int row = bm + wr * 64 + mf * 16 + l16 * 4 + r;
                float v = acc[mf][nf][r] + bb;
                if (OUTM == 3)
                    v += bf2f(((const __hip_bfloat16*)Cout)[(size_t)row * N + col]);
                if (RELU) v = fmaxf(v, 0.f);
                if (OUTM == 0)
                    Cf[(size_t)row * N + col] = v;
                else if (OUTM == 2)
                    ((__hip_bfloat16*)Cout)[(size_t)col * M + row] = f2bf(v);
                else
                    ((__hip_bfloat16*)Cout)[(size_t)row * N + col] = f2bf(v);
            }
        }
    }
}

// ---------------------------------------------------------------------------
// Pairwise distance via MFMA: G[i,j] = max(sq[i]+sq[j]-2*x_i.x_j, 0),
// fused per-block partial sums. X bf16 [2048,256]. Grid (16,16).
// ---------------------------------------------------------------------------
__global__ __launch_bounds__(256) void gemm_dist(
    const ushort* __restrict__ X, const float* __restrict__ sq,
    float* __restrict__ G, float* __restrict__ part)
{
    __shared__ __align__(16) ushort As[128 * 64];
    __shared__ __align__(16) ushort Bs[128 * 64];
    __shared__ float red[8];
    const int gx = gridDim.x;
    const int lin0 = blockIdx.y * gx + blockIdx.x;
    int lin = xcd_remap(lin0, gx * gridDim.y);
    const int bm = (lin / gx) * 128, bn = (lin % gx) * 128;
    const int tid = threadIdx.x;
    const int l = tid & 63, wv = tid >> 6;
    const int wr = wv >> 1, wc = wv & 1;
    const int l16 = l >> 4, lr = l & 15;
    f32x4 zero = {0.f, 0.f, 0.f, 0.f};
    f32x4 acc[4][4];
#pragma unroll
    for (int i = 0; i < 4; ++i)
#pragma unroll
        for (int j = 0; j < 4; ++j) acc[i][j] = zero;

    for (int k0 = 0; k0 < 256; k0 += 64) {
        stage_tile(X, As, bm, 256, k0, wv, l);
        stage_tile(X, Bs, bn, 256, k0, wv, l);
        __syncthreads();
#pragma unroll
        for (int kk = 0; kk < 2; ++kk) {
            bf16x8 av[4], bv[4];
#pragma unroll
            for (int f = 0; f < 4; ++f) {
                int ra = wr * 64 + f * 16 + lr;
                av[f] = *(const bf16x8*)(As + ra * 64 + (((kk * 4 + l16) ^ (ra & 7)) * 8));
                int rb = wc * 64 + f * 16 + lr;
                bv[f] = *(const bf16x8*)(Bs + rb * 64 + (((kk * 4 + l16) ^ (rb & 7)) * 8));
            }
#pragma unroll
            for (int mf = 0; mf < 4; ++mf)
#pragma unroll
                for (int nf = 0; nf < 4; ++nf)
                    acc[mf][nf] = __builtin_amdgcn_mfma_f32_16x16x32_bf16(
                        av[mf], bv[nf], acc[mf][nf], 0, 0, 0);
        }
        __syncthreads();
    }
    float lsum = 0.f;
#pragma unroll
    for (int mf = 0; mf < 4; ++mf) {
#pragma unroll
        for (int nf = 0; nf < 4; ++nf) {
            int col = bn + wc * 64 + nf * 16 + lr;
#pragma unroll
            for (int r = 0; r < 4; ++r) {
                int row = bm + wr * 64 + mf * 16 + l16 * 4 + r;
                float d = fmaxf(sq[row] + sq[col] - 2.f * acc[mf][nf][r], 0.f);
                G[(size_t)row * NN + col] = d;
                lsum += d;
            }
        }
    }
    float bs = block_reduce_sum256(lsum, red);
    if (tid == 0) part[lin0] = bs;
}

// ---------------- split-K finalize: out = relu(sum_z SL[z] + bias), bf16 ----
template <int Z, bool RELU>
__global__ __launch_bounds__(256) void slice_fin(const float* __restrict__ SL,
                                                 const float* __restrict__ bias,
                                                 __hip_bfloat16* __restrict__ out,
                                                 int N, size_t MN) {
    size_t v = (size_t)blockIdx.x * 256 + threadIdx.x;  // float4 index
    const float4* S4 = (const float4*)SL;
    size_t MN4 = MN >> 2;
    float4 s = S4[v];
#pragma unroll
    for (int z = 1; z < Z; ++z) {
        float4 t = S4[(size_t)z * MN4 + v];
        s.x += t.x; s.y += t.y; s.z += t.z; s.w += t.w;
    }
    float4 bb = ((const float4*)bias)[v % (size_t)(N >> 2)];
    s.x += bb.x; s.y += bb.y; s.z += bb.z; s.w += bb.w;
    if (RELU) {
        s.x = fmaxf(s.x, 0.f); s.y = fmaxf(s.y, 0.f);
        s.z = fmaxf(s.z, 0.f); s.w = fmaxf(s.w, 0.f);
    }
    union { __hip_bfloat16 h[4]; ushort4 u; } pk;
    pk.h[0] = f2bf(s.x); pk.h[1] = f2bf(s.y);
    pk.h[2] = f2bf(s.z); pk.h[3] = f2bf(s.w);
    ((ushort4*)out)[v] = pk.u;
}

// ---------------- conversions ----------------
__global__ void cvt_flat(const float* __restrict__ in, __hip_bfloat16* __restrict__ out,
                         int n4) {
    int i = blockIdx.x * 256 + threadIdx.x;
    if (i < n4) {
        float4 v = ((const float4*)in)[i];
        union { __hip_bfloat16 h[4]; ushort4 u; } pk;
        pk.h[0] = f2bf(v.x); pk.h[1] = f2bf(v.y);
        pk.h[2] = f2bf(v.z); pk.h[3] = f2bf(v.w);
        ((ushort4*)out)[i] = pk.u;
    }
}

// f32 [R,C] -> bf16 [C,R]; R,C multiples of 32.
__global__ __launch_bounds__(256) void cvt_trans(const float* __restrict__ in,
                                                 __hip_bfloat16* __restrict__ out,
                                                 int R, int C) {
    __shared__ float t[32][33];
    int bc = blockIdx.x * 32, br = blockIdx.y * 32;
    int tx = threadIdx.x & 31, ty = threadIdx.x >> 5;  // ty 0..7
#pragma unroll
    for (int i = 0; i < 32; i += 8)
        t[ty + i][tx] = in[(size_t)(br + ty + i) * C + bc + tx];
    __syncthreads();
#pragma unroll
    for (int i = 0; i < 32; i += 8)
        out[(size_t)(bc + ty + i) * R + br + tx] = f2bf(t[tx][ty + i]);
}

// ---------------- fused multi-bandwidth GK + sim accumulation --------------
// S (+)= ((1-eps)*gk3(G1,bw1) + eps) * gk3(G2,bw2) * mask
template <bool FIRST>
__global__ __launch_bounds__(256) void gk_sim_fused(
    const float4* __restrict__ G1, const float4* __restrict__ G2,
    const float* __restrict__ bws, const int* __restrict__ mk,
    const float* __restrict__ epsp, float4* __restrict__ S) {
    size_t v = (size_t)blockIdx.x * 256 + threadIdx.x;
    int i = (int)(v >> 9);             // row (512 float4 per 2048-col row)
    int j0 = (int)((v & 511) << 2);
    float eps = 1.f / (1.f + __expf(-epsp[0]));
    const float cnn = 1.f / ((float)NN * NN - (float)NN);
    float ia = 2.f / (bws[0] * cnn);   // 1/(sum*cnn*0.5)
    float ib = 2.f / (bws[1] * cnn);
    float4 d1 = G1[v], d2 = G2[v];
    int mi = mk[i];
    float4 r;
#define GKCOMP(X, J)                                                              \
    {                                                                             \
        float w = __expf(-d1.X * ia) + __expf(-d1.X * (0.5f * ia)) +              \
                  __expf(-d1.X * (0.25f * ia));                                   \
        float g = __expf(-d2.X * ib) + __expf(-d2.X * (0.5f * ib)) +              \
                  __expf(-d2.X * (0.25f * ib));                                   \
        float val = ((1.f - eps) * w + eps) * g;                                  \
        r.X = (mi && mk[j0 + J]) ? val : 0.f;                                     \
    }
    GKCOMP(x, 0) GKCOMP(y, 1) GKCOMP(z, 2) GKCOMP(w, 3)
#undef GKCOMP
    if (FIRST) {
        S[v] = r;
    } else {
        float4 o = S[v];
        r.x += o.x; r.y += o.y; r.z += o.z; r.w += o.w;
        S[v] = r;
    }
}

// ---------------- aggregation + threshold gate + bf16 convert --------------
__global__ __launch_bounds__(256) void agg_cvt(
    const float4* __restrict__ S, const int* __restrict__ mk0,
    const int* __restrict__ mk1, const int* __restrict__ mk2,
    const float* __restrict__ dissim, ushort4* __restrict__ Sb) {
    size_t v = (size_t)blockIdx.x * 256 + threadIdx.x;
    int i = (int)(v >> 9);
    int j0 = (int)((v & 511) << 2);
    float thr = 1.f / (1.f + __expf(-dissim[0]));
    float4 s = S[v];
    int m0i = mk0[i], m1i = mk1[i], m2i = mk2[i];
    union { __hip_bfloat16 h[4]; ushort4 u; } pk;
#define AGGC(X, J)                                                                \
    {                                                                             \
        int j = j0 + J;                                                           \
        int cnt = ((m0i && mk0[j]) ? 1 : 0) + ((m1i && mk1[j]) ? 1 : 0) +         \
                  ((m2i && mk2[j]) ? 1 : 0);                                      \
        float a = cnt ? s.X / (float)cnt : 0.f;                                   \
        pk.h[J] = f2bf((a > thr) ? a : 0.f);                                      \
    }
    AGGC(x, 0) AGGC(y, 1) AGGC(z, 2) AGGC(w, 3)
#undef AGGC
    Sb[v] = pk.u;
}

// ---------------- BatchNorm column stats (f32 input)
template <bool RELU_IN>
__global__ __launch_bounds__(256) void colstats(const float* __restrict__ X,
                                                float* __restrict__ mv, int nrows) {
    __shared__ float red[8];
    int c = blockIdx.x, tid = threadIdx.x;
    float s = 0.f, sq = 0.f;
    for (int r = tid; r < nrows; r += 256) {
        float v = X[(size_t)r * DD + c];
        if (RELU_IN) v = fmaxf(v, 0.f);
        s += v; sq += v * v;
    }
    float ts = block_reduce_sum256(s, red);
    float tq = block_reduce_sum256(sq, red);
    if (tid == 0) {
        float m = ts / (float)nrows;
        mv[c] = m;
        mv[DD + c] = tq / (float)nrows - m * m;
    }
}

// f32 in -> bf16 out (BN-normalized)
template <bool RELU_IN>
__global__ void bn_apply(const float* __restrict__ X, const float* __restrict__ mv,
                         const float* __restrict__ g, const float* __restrict__ b,
                         __hip_bfloat16* __restrict__ Y) {
    int idx = blockIdx.x * 256 + threadIdx.x;
    int c = idx & (DD - 1);
    float v = X[idx];
    if (RELU_IN) v = fmaxf(v, 0.f);
    Y[idx] = f2bf((v - mv[c]) * rsqrtf(mv[DD + c] + 1e-5f) * g[c] + b[c]);
}

__global__ __launch_bounds__(256) void rowsq(const __hip_bfloat16* __restrict__ X,
                                             float* __restrict__ SQ) {
    __shared__ float red[8];
    int r = blockIdx.x, tid = threadIdx.x;
    float v = bf2f(X[(size_t)r * DD + tid]);
    float s = block_reduce_sum256(v * v, red);
    if (tid == 0) SQ[r] = s;
}

// ---------------- sum-of-squares partial + tree reduce (deterministic)
__global__ __launch_bounds__(256) void sumsq_partial(const float* __restrict__ X, int n,
                                                     float* __restrict__ part) {
    __shared__ float red[8];
    int tid = threadIdx.x;
    float s = 0.f;
    for (size_t idx = (size_t)blockIdx.x * 256 + tid; idx < (size_t)n;
         idx += (size_t)gridDim.x * 256) {
        float v = X[idx];
        s += v * v;
    }
    float bs = block_reduce_sum256(s, red);
    if (tid == 0) part[blockIdx.x] = bs;
}

__global__ __launch_bounds__(256) void reduce_sum(const float* __restrict__ part, int n,
                                                  float* __restrict__ dst) {
    __shared__ float red[8];
    int tid = threadIdx.x;
    float s = 0.f;
    for (int i = tid; i < n; i += 256) s += part[i];
    float bs = block_reduce_sum256(s, red);
    if (tid == 0) dst[0] = bs;
}

// ---------------- adapt-gate imputation (one block per sample)
__global__ __launch_bounds__(256) void impute_k(
    const float* __restrict__ E, const __hip_bfloat16* __restrict__ H,
    const float* __restrict__ aw, const float* __restrict__ ab,
    const int* __restrict__ mk, float* __restrict__ OUT) {
    __shared__ float red[8];
    int i = blockIdx.x, tid = threadIdx.x;
    float e = E[(size_t)i * DD + tid], h = bf2f(H[(size_t)i * DD + tid]), w = aw[tid];
    float se = block_reduce_sum256(e * w, red);
    float sh = block_reduce_sum256(h * w, red);
    float s = 1.f / (1.f + __expf(-(se + ab[0])));
    float o = 1.f / (1.f + __expf(-(sh + ab[0])));
    s = s / (s + o);
    float imp = s * e + (1.f - s) * h;
    float m = mk[i] ? 1.f : 0.f;
    OUT[(size_t)i * DD + tid] = imp * m + (1.f - m) * h;
}

// ---------------- mask dtype detection + normalization --------------------
__global__ void detect_mode(const void* __restrict__ m1, int* __restrict__ modep) {
    if (threadIdx.x == 0 && blockIdx.x == 0) {
        int vi = ((const int*)m1)[0];
        float vf = ((const float*)m1)[0];
        modep[0] = (vi == 1) ? 0 : ((vf == 1.0f) ? 2 : 1);
    }
}

__device__ __forceinline__ int rd_mask(const void* p, int idx, int mode) {
    if (mode == 0) return ((const int*)p)[idx] != 0;
    if (mode == 1) return ((const unsigned char*)p)[idx] != 0;
    return ((const float*)p)[idx] != 0.f;
}

__global__ void build_masks(const void* __restrict__ m0, const void* __restrict__ m1,
                            const void* __restrict__ m2, const int* __restrict__ modep,
                            int* __restrict__ MK, int* __restrict__ TOK) {
    int mode = modep[0];
    int idx = blockIdx.x * 256 + threadIdx.x;
    if (idx < NN) {
        MK[idx] = rd_mask(m0, idx * 32, mode);
        MK[NN + idx] = rd_mask(m1, idx, mode);
        MK[2 * NN + idx] = rd_mask(m2, idx, mode);
    }
    if (idx < NN * LTOK) {
        int i = idx / LTOK, t = idx - i * LTOK;
        TOK[idx] = (t < 32) ? rd_mask(m0, i * 32 + t, mode)
                            : ((t == 32) ? rd_mask(m1, i, mode) : rd_mask(m2, i, mode));
    }
}

// ---------------- gather emb0[:,0,:] (f32 + bf16) ----------------
__global__ void gather_e0(const float* __restrict__ emb0, float* __restrict__ E0,
                          __hip_bfloat16* __restrict__ E0b) {
    int i = blockIdx.x, c = threadIdx.x;
    float v = emb0[(size_t)i * 32 * DD + c];
    E0[(size_t)i * DD + c] = v;
    E0b[(size_t)i * DD + c] = f2bf(v);
}

__global__ void build_z(const float* __restrict__ emb0, const float* __restrict__ i0,
                        const float* __restrict__ i1, const float* __restrict__ i2,
                        const float* __restrict__ type_emb,
                        __hip_bfloat16* __restrict__ Z) {
    size_t idx = (size_t)blockIdx.x * 256 + threadIdx.x;
    int c = (int)(idx & (DD - 1));
    int t = (int)((idx >> 8) % LTOK);
    int i = (int)(idx / (LTOK * DD));
    float v;
    if (t < 32) {
        float base = (t == 0) ? i0[(size_t)i * DD + c]
                              : emb0[((size_t)i * 32 + t) * DD + c];
        int k2 = (c >> 1) * 2;
        float div = expf((float)k2 * (-9.210340371976184f / 256.f));
        float ang = (float)t * div;
        float pe = (c & 1) ? cosf(ang) : sinf(ang);
        v = base + type_emb[c] + pe;
    } else if (t == 32) {
        v = i1[(size_t)i * DD + c] + type_emb[DD + c];
    } else {
        v = i2[(size_t)i * DD + c] + type_emb[2 * DD + c];
    }
    Z[idx] = f2bf(v);
}

// ---------------- fused attention; QKV packed [rows,768], O [rows,256] ----
template <int DH>
__global__ __launch_bounds__(256) void attn_fused(
    const __hip_bfloat16* __restrict__ QKV, const int* __restrict__ tok,
    __hip_bfloat16* __restrict__ O, int sample0) {
    const int L = LTOK;
    __shared__ float Qs[L * DH], Ks[L * DH], Vs[L * DH];
    __shared__ float Sc[L][L + 2];
    int b = blockIdx.x, hh = blockIdx.y;
    int tid = threadIdx.x;
    const float scale = rsqrtf((float)DH);
    for (int idx = tid; idx < L * DH; idx += 256) {
        int t = idx / DH, d = idx - t * DH;
        size_t g = (size_t)(b * L + t) * 768 + hh * DH + d;
        Qs[idx] = bf2f(QKV[g]);
        Ks[idx] = bf2f(QKV[g + 256]);
        Vs[idx] = bf2f(QKV[g + 512]);
    }
    __syncthreads();
    const int* tk = tok + (size_t)(sample0 + b) * L;
    for (int idx = tid; idx < L * L; idx += 256) {
        int i = idx / L, j = idx - i * L;
        float acc = 0.f;
#pragma unroll 8
        for (int d = 0; d < DH; ++d) acc = fmaf(Qs[i * DH + d], Ks[j * DH + d], acc);
        Sc[i][j] = (tk[i] && tk[j]) ? acc * scale : -1e9f;
    }
    __syncthreads();
    if (tid < L) {
        float mx = -1e30f;
        for (int j = 0; j < L; ++j) mx = fmaxf(mx, Sc[tid][j]);
        float s = 0.f;
        for (int j = 0; j < L; ++j) {
            float e = expf(Sc[tid][j] - mx);
            Sc[tid][j] = e; s += e;
        }
        float inv = 1.f / s;
        for (int j = 0; j < L; ++j) Sc[tid][j] *= inv;
    }
    __syncthreads();
    for (int idx = tid; idx < L * DH; idx += 256) {
        int i = idx / DH, d = idx - i * DH;
        float acc = 0.f;
        for (int j = 0; j < L; ++j) acc = fmaf(Sc[i][j], Vs[j * DH + d], acc);
        O[(size_t)(b * L + i) * DD + hh * DH + d] = f2bf(acc);
    }
}

// ---------------- wave-per-row LayerNorm on bf16 rows of 256 ----
template <bool RELU>
__global__ __launch_bounds__(256) void ln_rows(__hip_bfloat16* __restrict__ Z,
                                               const float* __restrict__ g,
                                               const float* __restrict__ b) {
    int row = (blockIdx.x << 2) + (threadIdx.x >> 6);
    int l = threadIdx.x & 63;
    ushort4 u = ((ushort4*)(Z + (size_t)row * DD))[l];
    float x0 = bf2f(*(__hip_bfloat16*)&u.x), x1 = bf2f(*(__hip_bfloat16*)&u.y);
    float x2 = bf2f(*(__hip_bfloat16*)&u.z), x3 = bf2f(*(__hip_bfloat16*)&u.w);
    float s = x0 + x1 + x2 + x3;
    for (int o = 1; o < 64; o <<= 1) s += __shfl_xor(s, o, 64);
    float mean = s * (1.f / 256.f);
    float d0 = x0 - mean, d1 = x1 - mean, d2 = x2 - mean, d3 = x3 - mean;
    float q = d0 * d0 + d1 * d1 + d2 * d2 + d3 * d3;
    for (int o = 1; o < 64; o <<= 1) q += __shfl_xor(q, o, 64);
    float rst = rsqrtf(q * (1.f / 256.f) + 1e-5f);
    float4 gg = ((const float4*)g)[l], bb = ((const float4*)b)[l];
    float y0 = d0 * rst * gg.x + bb.x, y1 = d1 * rst * gg.y + bb.y;
    float y2 = d2 * rst * gg.z + bb.z, y3 = d3 * rst * gg.w + bb.w;
    if (RELU) {
        y0 = fmaxf(y0, 0.f); y1 = fmaxf(y1, 0.f);
        y2 = fmaxf(y2, 0.f); y3 = fmaxf(y3, 0.f);
    }
    union { __hip_bfloat16 h[4]; ushort4 v; } pk;
    pk.h[0] = f2bf(y0); pk.h[1] = f2bf(y1); pk.h[2] = f2bf(y2); pk.h[3] = f2bf(y3);
    ((ushort4*)(Z + (size_t)row * DD))[l] = pk.v;
}

// ---------------- final head ----------------
__global__ __launch_bounds__(256) void head2(const __hip_bfloat16* __restrict__ Y1,
                                             const float* __restrict__ w,
                                             const float* __restrict__ b,
                                             float* __restrict__ out) {
    __shared__ float red[8];
    int i = blockIdx.x, tid = threadIdx.x;
    float s = bf2f(Y1[(size_t)i * 512 + tid]) * w[tid] +
              bf2f(Y1[(size_t)i * 512 + 256 + tid]) * w[256 + tid];
    float bs = block_reduce_sum256(s, red);
    if (tid == 0) out[i] = bs + b[0];
}

__global__ void lstab_k(const float* __restrict__ SC, float* __restrict__ dst) {
    if (threadIdx.x == 0 && blockIdx.x == 0) {
        float s = 0.f;
        for (int m = 0; m < 3; ++m)
            s += fabsf(sqrtf(SC[6 + m]) - sqrtf(SC[9 + m]));
        dst[0] = s;
    }
}

// ===========================================================================
#define GEMM(OUTM_, BIAS_, RELU_, A_, Bt_, BI_, C_, M_, N_, K_)                 \
    gemm_mfma<OUTM_, BIAS_, RELU_>                                              \
        <<<dim3((N_) / 128, (M_) / 128), 256, 0, stream>>>(                     \
            (const ushort*)(A_), (const ushort*)(Bt_), (BI_), (void*)(C_),      \
            (M_), (N_), (K_))
#define GEMMZ(A_, Bt_, C_, M_, N_, K_, Z_)                                      \
    gemm_mfma<0, false, false>                                                  \
        <<<dim3((N_) / 128, (M_) / 128, (Z_)), 256, 0, stream>>>(               \
            (const ushort*)(A_), (const ushort*)(Bt_), (const float*)nullptr,   \
            (void*)(C_), (M_), (N_), (K_))

extern "C" void kernel_launch(void* const* d_in, const int* in_sizes, int n_in,
                              void* d_out, int out_size, void* d_ws, size_t ws_size,
                              hipStream_t stream) {
    (void)in_sizes; (void)n_in; (void)out_size; (void)ws_size;
    const float* emb0 = (const float*)d_in[0];
    const float* emb1 = (const float*)d_in[1];
    const float* emb2 = (const float*)d_in[2];
    const void* msk0 = d_in[3];
    const void* msk1 = d_in[4];
    const void* msk2 = d_in[5];
    const float* simi_w = (const float*)d_in[6];
    const float* simi_b = (const float*)d_in[7];
    const float* bn_g = (const float*)d_in[8];
    const float* bn_b = (const float*)d_in[9];
    const float* simi_eps = (const float*)d_in[10];
    const float* dissim = (const float*)d_in[11];
    const float* gcn_w = (const float*)d_in[12];
    const float* gcn_b = (const float*)d_in[13];
    const float* adapt_w = (const float*)d_in[14];
    const float* adapt_b = (const float*)d_in[15];
    const float* type_emb = (const float*)d_in[16];
    const float* attn_w = (const float*)d_in[17];
    const float* attn_b = (const float*)d_in[18];
    const float* ffn_w1 = (const float*)d_in[19];
    const float* ffn_b1 = (const float*)d_in[20];
    const float* ffn_w2 = (const float*)d_in[21];
    const float* ffn_b2 = (const float*)d_in[22];
    const float* ln_g = (const float*)d_in[23];
    const float* ln_b = (const float*)d_in[24];
    const float* out_w1 = (const float*)d_in[25];
    const float* out_b1 = (const float*)d_in[26];
    const float* out_w2 = (const float*)d_in[27];
    const float* out_b2 = (const float*)d_in[28];
    float* out = (float*)d_out;

    // ---- workspace layout (~180 MB) ----
    char* wp = (char*)d_ws;
    auto alloc = [&](size_t bytes) -> char* {
        char* p = wp;
        wp += (bytes + 255) & ~(size_t)255;
        return p;
    };
    const int ACH = 512, ACROWS = ACH * LTOK;  // 17408 rows per chunk, 4 chunks
    __hip_bfloat16* Zb = (__hip_bfloat16*)alloc((size_t)NN * LTOK * DD * 2);  // 35.7MB
    char* UN = alloc((size_t)ACROWS * 1024 * 2);                              // 35.7MB union
    __hip_bfloat16* QKVb = (__hip_bfloat16*)UN;                        // 17408x768
    __hip_bfloat16* Ob = (__hip_bfloat16*)(UN + (size_t)ACROWS * 768 * 2);
    __hip_bfloat16* Hfb = (__hip_bfloat16*)UN;                         // 17408x1024
    float* G1 = (float*)alloc((size_t)NN * NN * 4);
    float* G2 = (float*)alloc((size_t)NN * NN * 4);
    float* S = (float*)alloc((size_t)NN * NN * 4);
    __hip_bfloat16* Sb = (__hip_bfloat16*)alloc((size_t)NN * NN * 2);
    float* SLICE = (float*)alloc((size_t)8 * NN * 256 * 4);            // 16MB split-K
    float* P = (float*)alloc((size_t)NN * DD * 4);
    float* E0 = (float*)alloc((size_t)NN * DD * 4);
    __hip_bfloat16* E0b = (__hip_bfloat16*)alloc((size_t)NN * DD * 2);
    __hip_bfloat16* e1b = (__hip_bfloat16*)alloc((size_t)NN * DD * 2);
    __hip_bfloat16* e2b = (__hip_bfloat16*)alloc((size_t)NN * DD * 2);
    __hip_bfloat16* T1b = (__hip_bfloat16*)alloc((size_t)NN * DD * 2);
    __hip_bfloat16* T2b = (__hip_bfloat16*)alloc((size_t)NN * DD * 2);
    __hip_bfloat16* XBb = (__hip_bfloat16*)alloc((size_t)NN * DD * 2);
    __hip_bfloat16* TBt = (__hip_bfloat16*)alloc((size_t)NN * DD * 2);
    __hip_bfloat16* HBb = (__hip_bfloat16*)alloc((size_t)NN * DD * 2);
    __hip_bfloat16* HB2b = (__hip_bfloat16*)alloc((size_t)NN * DD * 2);
    float* I0 = (float*)alloc((size_t)NN * DD * 4);
    float* I1 = (float*)alloc((size_t)NN * DD * 4);
    float* I2 = (float*)alloc((size_t)NN * DD * 4);
    __hip_bfloat16* Y1b = (__hip_bfloat16*)alloc((size_t)NN * 512 * 2);
    __hip_bfloat16* simi_wt = (__hip_bfloat16*)alloc((size_t)9 * 65536 * 2);
    __hip_bfloat16* gcn_wt = (__hip_bfloat16*)alloc((size_t)6 * 65536 * 2);
    __hip_bfloat16* attn_wt = (__hip_bfloat16*)alloc((size_t)8 * 65536 * 2);
    __hip_bfloat16* w1t = (__hip_bfloat16*)alloc((size_t)2 * 262144 * 2);
    __hip_bfloat16* w2t = (__hip_bfloat16*)alloc((size_t)2 * 262144 * 2);
    __hip_bfloat16* ow1t = (__hip_bfloat16*)alloc((size_t)8704 * 512 * 2);
    float* MV = (float*)alloc(512 * 4);
    float* SQ = (float*)alloc(NN * 4);
    float* PART = (float*)alloc(2048 * 4);
    float* SC = (float*)alloc(64 * 4);
    int* TOK = (int*)alloc((size_t)NN * LTOK * 4);
    int* MK = (int*)alloc((size_t)3 * NN * 4);

    // ---- weight transpose-convert (f32 [R,C] -> bf16 [C,R]) ----
    auto TR = [&](const float* src, __hip_bfloat16* dst, int R, int C) {
        cvt_trans<<<dim3(C / 32, R / 32), 256, 0, stream>>>(src, dst, R, C);
    };
    for (int i = 0; i < 9; ++i) TR(simi_w + (size_t)i * 65536, simi_wt + (size_t)i * 65536, 256, 256);
    for (int i = 0; i < 6; ++i) TR(gcn_w + (size_t)i * 65536, gcn_wt + (size_t)i * 65536, 256, 256);
    for (int i = 0; i < 8; ++i) TR(attn_w + (size_t)i * 65536, attn_wt + (size_t)i * 65536, 256, 256);
    for (int i = 0; i < 2; ++i) TR(ffn_w1 + (size_t)i * 262144, w1t + (size_t)i * 262144, 256, 1024);
    for (int i = 0; i < 2; ++i) TR(ffn_w2 + (size_t)i * 262144, w2t + (size_t)i * 262144, 1024, 256);
    TR(out_w1, ow1t, 8704, 512);

    // ---- prep ----
    gather_e0<<<NN, 256, 0, stream>>>(emb0, E0, E0b);
    cvt_flat<<<(NN * DD / 4 + 255) / 256, 256, 0, stream>>>(emb1, e1b, NN * DD / 4);
    cvt_flat<<<(NN * DD / 4 + 255) / 256, 256, 0, stream>>>(emb2, e2b, NN * DD / 4);
    detect_mode<<<1, 64, 0, stream>>>(msk1, (int*)SC + 16);
    build_masks<<<(NN * LTOK + 255) / 256, 256, 0, stream>>>(msk0, msk1, msk2,
                                                             (int*)SC + 16, MK, TOK);

    const float* Ef[3] = {E0, emb1, emb2};
    const __hip_bfloat16* Eb[3] = {E0b, e1b, e2b};

    // ---- Stage A: per-modal similarity kernels ----
    for (int m = 0; m < 3; ++m) {
        GEMM(1, true, true, Eb[m], simi_wt + (size_t)(m * 3 + 0) * 65536,
             simi_b + (m * 3 + 0) * 256, T1b, NN, 256, 256);
        GEMM(1, true, true, T1b, simi_wt + (size_t)(m * 3 + 1) * 65536,
             simi_b + (m * 3 + 1) * 256, T2b, NN, 256, 256);
        GEMM(0, true, false, T2b, simi_wt + (size_t)(m * 3 + 2) * 65536,
             simi_b + (m * 3 + 2) * 256, P, NN, 256, 256);
        sumsq_partial<<<512, 256, 0, stream>>>(P, NN * DD, PART);
        reduce_sum<<<1, 256, 0, stream>>>(PART, 512, SC + 6 + m);
        sumsq_partial<<<512, 256, 0, stream>>>(Ef[m], NN * DD, PART);
        reduce_sum<<<1, 256, 0, stream>>>(PART, 512, SC + 9 + m);
        // wgk = gk(bn(relu(p)))
        colstats<true><<<256, 256, 0, stream>>>(P, MV, NN);
        bn_apply<true><<<NN, 256, 0, stream>>>(P, MV, bn_g, bn_b, XBb);
        rowsq<<<NN, 256, 0, stream>>>(XBb, SQ);
        gemm_dist<<<dim3(16, 16), 256, 0, stream>>>((const ushort*)XBb, SQ, G1, PART);
        reduce_sum<<<1, 256, 0, stream>>>(PART, 256, SC + 0);
        // gk = gk(bn(e))
        colstats<false><<<256, 256, 0, stream>>>(Ef[m], MV, NN);
        bn_apply<false><<<NN, 256, 0, stream>>>(Ef[m], MV, bn_g, bn_b, XBb);
        rowsq<<<NN, 256, 0, stream>>>(XBb, SQ);
        gemm_dist<<<dim3(16, 16), 256, 0, stream>>>((const ushort*)XBb, SQ, G2, PART);
        reduce_sum<<<1, 256, 0, stream>>>(PART, 256, SC + 1);
        if (m == 0)
            gk_sim_fused<true><<<4096, 256, 0, stream>>>(
                (const float4*)G1, (const float4*)G2, SC, MK, simi_eps + m, (float4*)S);
        else
            gk_sim_fused<false><<<4096, 256, 0, stream>>>(
                (const float4*)G1, (const float4*)G2, SC, MK + m * NN, simi_eps + m,
                (float4*)S);
    }

    // ---- Stage B: aggregation + GCN imputation (split-K Z=8) ----
    agg_cvt<<<4096, 256, 0, stream>>>((const float4*)S, MK, MK + NN, MK + 2 * NN,
                                      dissim, (ushort4*)Sb);
    float* IMP[3] = {I0, I1, I2};
    for (int m = 0; m < 3; ++m) {
        GEMM(2, false, false, Eb[m], gcn_wt + (size_t)(m * 2 + 0) * 65536,
             (const float*)nullptr, TBt, NN, 256, 256);
        GEMMZ(Sb, TBt, SLICE, NN, 256, NN, 8);
        slice_fin<8, true><<<512, 256, 0, stream>>>(SLICE, gcn_b + (m * 2 + 0) * 256,
                                                    HBb, 256, (size_t)NN * 256);
        GEMM(2, false, false, HBb, gcn_wt + (size_t)(m * 2 + 1) * 65536,
             (const float*)nullptr, TBt, NN, 256, 256);
        GEMMZ(Sb, TBt, SLICE, NN, 256, NN, 8);
        slice_fin<8, true><<<512, 256, 0, stream>>>(SLICE, gcn_b + (m * 2 + 1) * 256,
                                                    HB2b, 256, (size_t)NN * 256);
        impute_k<<<NN, 256, 0, stream>>>(Ef[m], HB2b, adapt_w + m * 256, adapt_b + m,
                                         MK + m * NN, IMP[m]);
    }

    // ---- Stage C: 34-token transformer (bf16 Z) ----
    build_z<<<NN * LTOK, 256, 0, stream>>>(emb0, I0, I1, I2, type_emb, Zb);
    const int NCHUNK = NN / ACH;  // 4
    for (int li = 0; li < 2; ++li) {
        for (int c = 0; c < NCHUNK; ++c) {
            __hip_bfloat16* Zc = Zb + (size_t)c * ACROWS * DD;
            GEMM(1, true, false, Zc, attn_wt + (size_t)(li * 4) * 65536,
                 attn_b + li * 4 * 256, QKVb, ACROWS, 768, 256);
            if (li == 0)
                attn_fused<64><<<dim3(ACH, 4), 256, 0, stream>>>(QKVb, TOK, Ob, c * ACH);
            else
                attn_fused<256><<<dim3(ACH, 1), 256, 0, stream>>>(QKVb, TOK, Ob, c * ACH);
            GEMM(3, true, false, Ob, attn_wt + (size_t)(li * 4 + 3) * 65536,
                 attn_b + (li * 4 + 3) * 256, Zc, ACROWS, 256, 256);
        }
        ln_rows<false><<<NN * LTOK / 4, 256, 0, stream>>>(Zb, ln_g + (li * 2 + 0) * 256,
                                                          ln_b + (li * 2 + 0) * 256);
        for (int c = 0; c < NCHUNK; ++c) {
            __hip_bfloat16* Zc = Zb + (size_t)c * ACROWS * DD;
            GEMM(1, true, true, Zc, w1t + (size_t)li * 262144, ffn_b1 + li * 1024,
                 Hfb, ACROWS, 1024, 256);
            GEMM(3, true, false, Hfb, w2t + (size_t)li * 262144, ffn_b2 + li * 256,
                 Zc, ACROWS, 256, 1024);
        }
        ln_rows<true><<<NN * LTOK / 4, 256, 0, stream>>>(Zb, ln_g + (li * 2 + 1) * 256,
                                                         ln_b + (li * 2 + 1) * 256);
    }

    // ---- head (split-K Z=4) ----
    GEMMZ(Zb, ow1t, SLICE, NN, 512, LTOK * DD, 4);
    slice_fin<4, true><<<1024, 256, 0, stream>>>(SLICE, out_b1, Y1b, 512,
                                                 (size_t)NN * 512);
    head2<<<NN, 256, 0, stream>>>(Y1b, out_w2, out_b2, out);
    lstab_k<<<1, 64, 0, stream>>>(SC, out + NN);
}

// Round 4
// 1665.185 us; speedup vs baseline: 4.1364x; 1.2698x over previous
//
#include <hip/hip_runtime.h>
#include <hip/hip_bf16.h>

// ---------------------------------------------------------------------------
// M3Care forward — bf16 MFMA GEMMs (global_load_lds staging + XCD swizzle +
// split-K), fused elementwise, conflict-free bf16 attention.
// N=2048, D=256, T=32, NE=34 tokens, heads=(4,1).
// ---------------------------------------------------------------------------

#define NN 2048
#define DD 256
#define LTOK 34

typedef __attribute__((ext_vector_type(8))) short bf16x8;
typedef __attribute__((ext_vector_type(4))) float f32x4;

__device__ __forceinline__ float bf2f(__hip_bfloat16 x) { return __bfloat162float(x); }
__device__ __forceinline__ __hip_bfloat16 f2bf(float x) { return __float2bfloat16(x); }
// raw ushort (bf16 bits) -> f32: one shift
__device__ __forceinline__ float us2f(ushort u) {
    unsigned x = (unsigned)u << 16;
    float f;
    __builtin_memcpy(&f, &x, 4);
    return f;
}

// ---------------- block reduce (blockDim.x == 256) ----------------
__device__ __forceinline__ float block_reduce_sum256(float v, float* red) {
    for (int o = 32; o > 0; o >>= 1) v += __shfl_down(v, o, 64);
    int tid = threadIdx.x;
    if ((tid & 63) == 0) red[tid >> 6] = v;
    __syncthreads();
    float s = red[0] + red[1] + red[2] + red[3];
    __syncthreads();
    return s;
}

// XCD-chunked bijective remap (T1, m204 variant). nwg = gridDim.x*gridDim.y.
__device__ __forceinline__ int xcd_remap(int lin, int nwg) {
    int q = nwg >> 3, r = nwg & 7;
    int xcd = lin & 7, pos = lin >> 3;
    return (xcd < r ? xcd * (q + 1) : r * (q + 1) + (xcd - r) * q) + pos;
}

// Stage one 128x64 bf16 tile via global_load_lds (16B/lane), linear LDS dest,
// inverse-XOR-swizzled per-lane GLOBAL source (rule #21): LDS[row][s] gets
// source k-slot s^(row&7); the MFMA read applies the same XOR -> linear k.
__device__ __forceinline__ void stage_tile(const ushort* __restrict__ src,
                                           ushort* lds, int grow0, size_t ldk,
                                           int k0, int wv, int l) {
#pragma unroll
    for (int c = 0; c < 4; ++c) {
        int rowbase = wv * 32 + c * 8;
        int row = rowbase + (l >> 3);
        int sx = ((l & 7) ^ (row & 7)) * 8;
        __builtin_amdgcn_global_load_lds(
            (const __attribute__((address_space(1))) void*)(src + (size_t)(grow0 + row) * ldk + k0 + sx),
            (__attribute__((address_space(3))) void*)(lds + rowbase * 64), 16, 0, 0);
    }
}

// ---------------------------------------------------------------------------
// bf16 MFMA GEMM: C[M,N] = op(A[M,K] @ Bt[N,K]^T + bias)
// OUTM: 0 = f32 out (slice offset z*M*N for split-K), 1 = bf16 out,
//       2 = bf16 transposed out [N,M], 3 = bf16 in-place add.
// M%128==0, N%128==0, K%(64*gridDim.z)==0.
// ---------------------------------------------------------------------------
template <int OUTM, bool BIAS, bool RELU>
__global__ __launch_bounds__(256) void gemm_mfma(
    const ushort* __restrict__ A, const ushort* __restrict__ Bt,
    const float* __restrict__ bias, void* __restrict__ Cout,
    int M, int N, int K)
{
    __shared__ __align__(16) ushort As[128 * 64];
    __shared__ __align__(16) ushort Bs[128 * 64];
    const int gx = gridDim.x;
    int lin = xcd_remap(blockIdx.y * gx + blockIdx.x, gx * gridDim.y);
    const int bm = (lin / gx) * 128, bn = (lin % gx) * 128;
    const int tid = threadIdx.x;
    const int l = tid & 63, wv = tid >> 6;
    const int wr = wv >> 1, wc = wv & 1;     // 2x2 wave grid, 64x64 each
    const int l16 = l >> 4, lr = l & 15;
    const int kpz = K / gridDim.z;
    const int kbeg = blockIdx.z * kpz, kend = kbeg + kpz;
    f32x4 zero = {0.f, 0.f, 0.f, 0.f};
    f32x4 acc[4][4];
#pragma unroll
    for (int i = 0; i < 4; ++i)
#pragma unroll
        for (int j = 0; j < 4; ++j) acc[i][j] = zero;

    for (int k0 = kbeg; k0 < kend; k0 += 64) {
        stage_tile(A, As, bm, K, k0, wv, l);
        stage_tile(Bt, Bs, bn, K, k0, wv, l);
        __syncthreads();
#pragma unroll
        for (int kk = 0; kk < 2; ++kk) {
            bf16x8 av[4], bv[4];
#pragma unroll
            for (int f = 0; f < 4; ++f) {
                int ra = wr * 64 + f * 16 + lr;
                av[f] = *(const bf16x8*)(As + ra * 64 + (((kk * 4 + l16) ^ (ra & 7)) * 8));
                int rb = wc * 64 + f * 16 + lr;
                bv[f] = *(const bf16x8*)(Bs + rb * 64 + (((kk * 4 + l16) ^ (rb & 7)) * 8));
            }
#pragma unroll
            for (int mf = 0; mf < 4; ++mf)
#pragma unroll
                for (int nf = 0; nf < 4; ++nf)
                    acc[mf][nf] = __builtin_amdgcn_mfma_f32_16x16x32_bf16(
                        av[mf], bv[nf], acc[mf][nf], 0, 0, 0);
        }
        __syncthreads();
    }
    // epilogue: C/D layout col=lane&15, row=(lane>>4)*4+reg  [m89-verified]
    float* Cf = (float*)Cout + (size_t)blockIdx.z * M * N;
#pragma unroll
    for (int mf = 0; mf < 4; ++mf) {
#pragma unroll
        for (int nf = 0; nf < 4; ++nf) {
            int col = bn + wc * 64 + nf * 16 + lr;
            float bb = BIAS ? bias[col] : 0.f;
#pragma unroll
            for (int r = 0; r < 4; ++r) {
                int row = bm + wr * 64 + mf * 16 + l16 * 4 + r;
                float v = acc[mf][nf][r] + bb;
                if (OUTM == 3)
                    v += bf2f(((const __hip_bfloat16*)Cout)[(size_t)row * N + col]);
                if (RELU) v = fmaxf(v, 0.f);
                if (OUTM == 0)
                    Cf[(size_t)row * N + col] = v;
                else if (OUTM == 2)
                    ((__hip_bfloat16*)Cout)[(size_t)col * M + row] = f2bf(v);
                else
                    ((__hip_bfloat16*)Cout)[(size_t)row * N + col] = f2bf(v);
            }
        }
    }
}

// ---------------------------------------------------------------------------
// Pairwise distance via MFMA: G[i,j] = max(sq[i]+sq[j]-2*x_i.x_j, 0),
// fused per-block partial sums. X bf16 [2048,256]. Grid (16,16).
// ---------------------------------------------------------------------------
__global__ __launch_bounds__(256) void gemm_dist(
    const ushort* __restrict__ X, const float* __restrict__ sq,
    float* __restrict__ G, float* __restrict__ part)
{
    __shared__ __align__(16) ushort As[128 * 64];
    __shared__ __align__(16) ushort Bs[128 * 64];
    __shared__ float red[8];
    const int gx = gridDim.x;
    const int lin0 = blockIdx.y * gx + blockIdx.x;
    int lin = xcd_remap(lin0, gx * gridDim.y);
    const int bm = (lin / gx) * 128, bn = (lin % gx) * 128;
    const int tid = threadIdx.x;
    const int l = tid & 63, wv = tid >> 6;
    const int wr = wv >> 1, wc = wv & 1;
    const int l16 = l >> 4, lr = l & 15;
    f32x4 zero = {0.f, 0.f, 0.f, 0.f};
    f32x4 acc[4][4];
#pragma unroll
    for (int i = 0; i < 4; ++i)
#pragma unroll
        for (int j = 0; j < 4; ++j) acc[i][j] = zero;

    for (int k0 = 0; k0 < 256; k0 += 64) {
        stage_tile(X, As, bm, 256, k0, wv, l);
        stage_tile(X, Bs, bn, 256, k0, wv, l);
        __syncthreads();
#pragma unroll
        for (int kk = 0; kk < 2; ++kk) {
            bf16x8 av[4], bv[4];
#pragma unroll
            for (int f = 0; f < 4; ++f) {
                int ra = wr * 64 + f * 16 + lr;
                av[f] = *(const bf16x8*)(As + ra * 64 + (((kk * 4 + l16) ^ (ra & 7)) * 8));
                int rb = wc * 64 + f * 16 + lr;
                bv[f] = *(const bf16x8*)(Bs + rb * 64 + (((kk * 4 + l16) ^ (rb & 7)) * 8));
            }
#pragma unroll
            for (int mf = 0; mf < 4; ++mf)
#pragma unroll
                for (int nf = 0; nf < 4; ++nf)
                    acc[mf][nf] = __builtin_amdgcn_mfma_f32_16x16x32_bf16(
                        av[mf], bv[nf], acc[mf][nf], 0, 0, 0);
        }
        __syncthreads();
    }
    float lsum = 0.f;
#pragma unroll
    for (int mf = 0; mf < 4; ++mf) {
#pragma unroll
        for (int nf = 0; nf < 4; ++nf) {
            int col = bn + wc * 64 + nf * 16 + lr;
#pragma unroll
            for (int r = 0; r < 4; ++r) {
                int row = bm + wr * 64 + mf * 16 + l16 * 4 + r;
                float d = fmaxf(sq[row] + sq[col] - 2.f * acc[mf][nf][r], 0.f);
                G[(size_t)row * NN + col] = d;
                lsum += d;
            }
        }
    }
    float bs = block_reduce_sum256(lsum, red);
    if (tid == 0) part[lin0] = bs;
}

// ---------------- split-K finalize: out = relu(sum_z SL[z] + bias), bf16 ----
template <int Z, bool RELU>
__global__ __launch_bounds__(256) void slice_fin(const float* __restrict__ SL,
                                                 const float* __restrict__ bias,
                                                 __hip_bfloat16* __restrict__ out,
                                                 int N, size_t MN) {
    size_t v = (size_t)blockIdx.x * 256 + threadIdx.x;  // float4 index
    const float4* S4 = (const float4*)SL;
    size_t MN4 = MN >> 2;
    float4 s = S4[v];
#pragma unroll
    for (int z = 1; z < Z; ++z) {
        float4 t = S4[(size_t)z * MN4 + v];
        s.x += t.x; s.y += t.y; s.z += t.z; s.w += t.w;
    }
    float4 bb = ((const float4*)bias)[v % (size_t)(N >> 2)];
    s.x += bb.x; s.y += bb.y; s.z += bb.z; s.w += bb.w;
    if (RELU) {
        s.x = fmaxf(s.x, 0.f); s.y = fmaxf(s.y, 0.f);
        s.z = fmaxf(s.z, 0.f); s.w = fmaxf(s.w, 0.f);
    }
    union { __hip_bfloat16 h[4]; ushort4 u; } pk;
    pk.h[0] = f2bf(s.x); pk.h[1] = f2bf(s.y);
    pk.h[2] = f2bf(s.z); pk.h[3] = f2bf(s.w);
    ((ushort4*)out)[v] = pk.u;
}

// ---------------- conversions ----------------
__global__ void cvt_flat(const float* __restrict__ in, __hip_bfloat16* __restrict__ out,
                         int n4) {
    int i = blockIdx.x * 256 + threadIdx.x;
    if (i < n4) {
        float4 v = ((const float4*)in)[i];
        union { __hip_bfloat16 h[4]; ushort4 u; } pk;
        pk.h[0] = f2bf(v.x); pk.h[1] = f2bf(v.y);
        pk.h[2] = f2bf(v.z); pk.h[3] = f2bf(v.w);
        ((ushort4*)out)[i] = pk.u;
    }
}

// f32 [R,C] -> bf16 [C,R]; R,C multiples of 32.
__global__ __launch_bounds__(256) void cvt_trans(const float* __restrict__ in,
                                                 __hip_bfloat16* __restrict__ out,
                                                 int R, int C) {
    __shared__ float t[32][33];
    int bc = blockIdx.x * 32, br = blockIdx.y * 32;
    int tx = threadIdx.x & 31, ty = threadIdx.x >> 5;  // ty 0..7
#pragma unroll
    for (int i = 0; i < 32; i += 8)
        t[ty + i][tx] = in[(size_t)(br + ty + i) * C + bc + tx];
    __syncthreads();
#pragma unroll
    for (int i = 0; i < 32; i += 8)
        out[(size_t)(bc + ty + i) * R + br + tx] = f2bf(t[tx][ty + i]);
}

// ---------------- fused multi-bandwidth GK + sim accumulation --------------
// S (+)= ((1-eps)*gk3(G1,bw1) + eps) * gk3(G2,bw2) * mask
template <bool FIRST>
__global__ __launch_bounds__(256) void gk_sim_fused(
    const float4* __restrict__ G1, const float4* __restrict__ G2,
    const float* __restrict__ bws, const int* __restrict__ mk,
    const float* __restrict__ epsp, float4* __restrict__ S) {
    size_t v = (size_t)blockIdx.x * 256 + threadIdx.x;
    int i = (int)(v >> 9);             // row (512 float4 per 2048-col row)
    int j0 = (int)((v & 511) << 2);
    float eps = 1.f / (1.f + __expf(-epsp[0]));
    const float cnn = 1.f / ((float)NN * NN - (float)NN);
    float ia = 2.f / (bws[0] * cnn);   // 1/(sum*cnn*0.5)
    float ib = 2.f / (bws[1] * cnn);
    float4 d1 = G1[v], d2 = G2[v];
    int mi = mk[i];
    float4 r;
#define GKCOMP(X, J)                                                              \
    {                                                                             \
        float w = __expf(-d1.X * ia) + __expf(-d1.X * (0.5f * ia)) +              \
                  __expf(-d1.X * (0.25f * ia));                                   \
        float g = __expf(-d2.X * ib) + __expf(-d2.X * (0.5f * ib)) +              \
                  __expf(-d2.X * (0.25f * ib));                                   \
        float val = ((1.f - eps) * w + eps) * g;                                  \
        r.X = (mi && mk[j0 + J]) ? val : 0.f;                                     \
    }
    GKCOMP(x, 0) GKCOMP(y, 1) GKCOMP(z, 2) GKCOMP(w, 3)
#undef GKCOMP
    if (FIRST) {
        S[v] = r;
    } else {
        float4 o = S[v];
        r.x += o.x; r.y += o.y; r.z += o.z; r.w += o.w;
        S[v] = r;
    }
}

// ---------------- aggregation + threshold gate + bf16 convert --------------
__global__ __launch_bounds__(256) void agg_cvt(
    const float4* __restrict__ S, const int* __restrict__ mk0,
    const int* __restrict__ mk1, const int* __restrict__ mk2,
    const float* __restrict__ dissim, ushort4* __restrict__ Sb) {
    size_t v = (size_t)blockIdx.x * 256 + threadIdx.x;
    int i = (int)(v >> 9);
    int j0 = (int)((v & 511) << 2);
    float thr = 1.f / (1.f + __expf(-dissim[0]));
    float4 s = S[v];
    int m0i = mk0[i], m1i = mk1[i], m2i = mk2[i];
    union { __hip_bfloat16 h[4]; ushort4 u; } pk;
#define AGGC(X, J)                                                                \
    {                                                                             \
        int j = j0 + J;                                                           \
        int cnt = ((m0i && mk0[j]) ? 1 : 0) + ((m1i && mk1[j]) ? 1 : 0) +         \
                  ((m2i && mk2[j]) ? 1 : 0);                                      \
        float a = cnt ? s.X / (float)cnt : 0.f;                                   \
        pk.h[J] = f2bf((a > thr) ? a : 0.f);                                      \
    }
    AGGC(x, 0) AGGC(y, 1) AGGC(z, 2) AGGC(w, 3)
#undef AGGC
    Sb[v] = pk.u;
}

// ---------------- BatchNorm column stats (f32 input)
template <bool RELU_IN>
__global__ __launch_bounds__(256) void colstats(const float* __restrict__ X,
                                                float* __restrict__ mv, int nrows) {
    __shared__ float red[8];
    int c = blockIdx.x, tid = threadIdx.x;
    float s = 0.f, sq = 0.f;
    for (int r = tid; r < nrows; r += 256) {
        float v = X[(size_t)r * DD + c];
        if (RELU_IN) v = fmaxf(v, 0.f);
        s += v; sq += v * v;
    }
    float ts = block_reduce_sum256(s, red);
    float tq = block_reduce_sum256(sq, red);
    if (tid == 0) {
        float m = ts / (float)nrows;
        mv[c] = m;
        mv[DD + c] = tq / (float)nrows - m * m;
    }
}

// f32 in -> bf16 out (BN-normalized)
template <bool RELU_IN>
__global__ void bn_apply(const float* __restrict__ X, const float* __restrict__ mv,
                         const float* __restrict__ g, const float* __restrict__ b,
                         __hip_bfloat16* __restrict__ Y) {
    int idx = blockIdx.x * 256 + threadIdx.x;
    int c = idx & (DD - 1);
    float v = X[idx];
    if (RELU_IN) v = fmaxf(v, 0.f);
    Y[idx] = f2bf((v - mv[c]) * rsqrtf(mv[DD + c] + 1e-5f) * g[c] + b[c]);
}

__global__ __launch_bounds__(256) void rowsq(const __hip_bfloat16* __restrict__ X,
                                             float* __restrict__ SQ) {
    __shared__ float red[8];
    int r = blockIdx.x, tid = threadIdx.x;
    float v = bf2f(X[(size_t)r * DD + tid]);
    float s = block_reduce_sum256(v * v, red);
    if (tid == 0) SQ[r] = s;
}

// ---------------- sum-of-squares partial + tree reduce (deterministic)
__global__ __launch_bounds__(256) void sumsq_partial(const float* __restrict__ X, int n,
                                                     float* __restrict__ part) {
    __shared__ float red[8];
    int tid = threadIdx.x;
    float s = 0.f;
    for (size_t idx = (size_t)blockIdx.x * 256 + tid; idx < (size_t)n;
         idx += (size_t)gridDim.x * 256) {
        float v = X[idx];
        s += v * v;
    }
    float bs = block_reduce_sum256(s, red);
    if (tid == 0) part[blockIdx.x] = bs;
}

__global__ __launch_bounds__(256) void reduce_sum(const float* __restrict__ part, int n,
                                                  float* __restrict__ dst) {
    __shared__ float red[8];
    int tid = threadIdx.x;
    float s = 0.f;
    for (int i = tid; i < n; i += 256) s += part[i];
    float bs = block_reduce_sum256(s, red);
    if (tid == 0) dst[0] = bs;
}

// ---------------- adapt-gate imputation (one block per sample)
__global__ __launch_bounds__(256) void impute_k(
    const float* __restrict__ E, const __hip_bfloat16* __restrict__ H,
    const float* __restrict__ aw, const float* __restrict__ ab,
    const int* __restrict__ mk, float* __restrict__ OUT) {
    __shared__ float red[8];
    int i = blockIdx.x, tid = threadIdx.x;
    float e = E[(size_t)i * DD + tid], h = bf2f(H[(size_t)i * DD + tid]), w = aw[tid];
    float se = block_reduce_sum256(e * w, red);
    float sh = block_reduce_sum256(h * w, red);
    float s = 1.f / (1.f + __expf(-(se + ab[0])));
    float o = 1.f / (1.f + __expf(-(sh + ab[0])));
    s = s / (s + o);
    float imp = s * e + (1.f - s) * h;
    float m = mk[i] ? 1.f : 0.f;
    OUT[(size_t)i * DD + tid] = imp * m + (1.f - m) * h;
}

// ---------------- mask dtype detection + normalization --------------------
__global__ void detect_mode(const void* __restrict__ m1, int* __restrict__ modep) {
    if (threadIdx.x == 0 && blockIdx.x == 0) {
        int vi = ((const int*)m1)[0];
        float vf = ((const float*)m1)[0];
        modep[0] = (vi == 1) ? 0 : ((vf == 1.0f) ? 2 : 1);
    }
}

__device__ __forceinline__ int rd_mask(const void* p, int idx, int mode) {
    if (mode == 0) return ((const int*)p)[idx] != 0;
    if (mode == 1) return ((const unsigned char*)p)[idx] != 0;
    return ((const float*)p)[idx] != 0.f;
}

__global__ void build_masks(const void* __restrict__ m0, const void* __restrict__ m1,
                            const void* __restrict__ m2, const int* __restrict__ modep,
                            int* __restrict__ MK, int* __restrict__ TOK) {
    int mode = modep[0];
    int idx = blockIdx.x * 256 + threadIdx.x;
    if (idx < NN) {
        MK[idx] = rd_mask(m0, idx * 32, mode);
        MK[NN + idx] = rd_mask(m1, idx, mode);
        MK[2 * NN + idx] = rd_mask(m2, idx, mode);
    }
    if (idx < NN * LTOK) {
        int i = idx / LTOK, t = idx - i * LTOK;
        TOK[idx] = (t < 32) ? rd_mask(m0, i * 32 + t, mode)
                            : ((t == 32) ? rd_mask(m1, i, mode) : rd_mask(m2, i, mode));
    }
}

// ---------------- gather emb0[:,0,:] (f32 + bf16) ----------------
__global__ void gather_e0(const float* __restrict__ emb0, float* __restrict__ E0,
                          __hip_bfloat16* __restrict__ E0b) {
    int i = blockIdx.x, c = threadIdx.x;
    float v = emb0[(size_t)i * 32 * DD + c];
    E0[(size_t)i * DD + c] = v;
    E0b[(size_t)i * DD + c] = f2bf(v);
}

__global__ void build_z(const float* __restrict__ emb0, const float* __restrict__ i0,
                        const float* __restrict__ i1, const float* __restrict__ i2,
                        const float* __restrict__ type_emb,
                        __hip_bfloat16* __restrict__ Z) {
    size_t idx = (size_t)blockIdx.x * 256 + threadIdx.x;
    int c = (int)(idx & (DD - 1));
    int t = (int)((idx >> 8) % LTOK);
    int i = (int)(idx / (LTOK * DD));
    float v;
    if (t < 32) {
        float base = (t == 0) ? i0[(size_t)i * DD + c]
                              : emb0[((size_t)i * 32 + t) * DD + c];
        int k2 = (c >> 1) * 2;
        float div = expf((float)k2 * (-9.210340371976184f / 256.f));
        float ang = (float)t * div;
        float pe = (c & 1) ? cosf(ang) : sinf(ang);
        v = base + type_emb[c] + pe;
    } else if (t == 32) {
        v = i1[(size_t)i * DD + c] + type_emb[DD + c];
    } else {
        v = i2[(size_t)i * DD + c] + type_emb[2 * DD + c];
    }
    Z[idx] = f2bf(v);
}

// ---------------- fused attention; QKV packed [rows,768] bf16, O [rows,256]
// bf16 LDS, K stored transposed [DH][38] (pad 38: 76B stride, gcd(19,32)=1 ->
// conflict-free d-strided write AND j-contiguous read). Scores [34][35] f32.
template <int DH>
__global__ __launch_bounds__(256) void attn_fused(
    const __hip_bfloat16* __restrict__ QKV, const int* __restrict__ tok,
    __hip_bfloat16* __restrict__ O, int sample0) {
    const int L = LTOK;
    __shared__ ushort Qs[L * DH];       // [i][d]
    __shared__ ushort KT[DH * 38];      // [d][j]
    __shared__ ushort Vs[L * DH];       // [j][d]
    __shared__ float Sc[L][35];
    int b = blockIdx.x, hh = blockIdx.y;
    int tid = threadIdx.x;
    const float scale = rsqrtf((float)DH);
    for (int idx = tid; idx < L * DH; idx += 256) {
        int t = idx / DH, d = idx - t * DH;
        size_t g = (size_t)(b * L + t) * 768 + hh * DH + d;
        const ushort* q = (const ushort*)QKV;
        Qs[idx] = q[g];
        KT[d * 38 + t] = q[g + 256];
        Vs[idx] = q[g + 512];
    }
    __syncthreads();
    const int* tk = tok + (size_t)(sample0 + b) * L;
    for (int idx = tid; idx < L * L; idx += 256) {
        int i = idx / L, j = idx - i * L;
        float acc = 0.f;
#pragma unroll 16
        for (int d = 0; d < DH; ++d)
            acc = fmaf(us2f(Qs[i * DH + d]), us2f(KT[d * 38 + j]), acc);
        Sc[i][j] = (tk[i] && tk[j]) ? acc * scale : -1e9f;
    }
    __syncthreads();
    if (tid < L) {  // serial softmax per row: 34x34 tiny; stride 35 conflict-free
        float mx = -1e30f;
        for (int j = 0; j < L; ++j) mx = fmaxf(mx, Sc[tid][j]);
        float s = 0.f;
        for (int j = 0; j < L; ++j) {
            float e = __expf(Sc[tid][j] - mx);
            Sc[tid][j] = e; s += e;
        }
        float inv = 1.f / s;
        for (int j = 0; j < L; ++j) Sc[tid][j] *= inv;
    }
    __syncthreads();
    for (int idx = tid; idx < L * DH; idx += 256) {
        int i = idx / DH, d = idx - i * DH;
        float acc = 0.f;
#pragma unroll
        for (int j = 0; j < L; ++j) acc = fmaf(Sc[i][j], us2f(Vs[j * DH + d]), acc);
        O[(size_t)(b * L + i) * DD + hh * DH + d] = f2bf(acc);
    }
}

// ---------------- wave-per-row LayerNorm on bf16 rows of 256 ----
template <bool RELU>
__global__ __launch_bounds__(256) void ln_rows(__hip_bfloat16* __restrict__ Z,
                                               const float* __restrict__ g,
                                               const float* __restrict__ b) {
    int row = (blockIdx.x << 2) + (threadIdx.x >> 6);
    int l = threadIdx.x & 63;
    ushort4 u = ((ushort4*)(Z + (size_t)row * DD))[l];
    float x0 = us2f(u.x), x1 = us2f(u.y), x2 = us2f(u.z), x3 = us2f(u.w);
    float s = x0 + x1 + x2 + x3;
    for (int o = 1; o < 64; o <<= 1) s += __shfl_xor(s, o, 64);
    float mean = s * (1.f / 256.f);
    float d0 = x0 - mean, d1 = x1 - mean, d2 = x2 - mean, d3 = x3 - mean;
    float q = d0 * d0 + d1 * d1 + d2 * d2 + d3 * d3;
    for (int o = 1; o < 64; o <<= 1) q += __shfl_xor(q, o, 64);
    float rst = rsqrtf(q * (1.f / 256.f) + 1e-5f);
    float4 gg = ((const float4*)g)[l], bb = ((const float4*)b)[l];
    float y0 = d0 * rst * gg.x + bb.x, y1 = d1 * rst * gg.y + bb.y;
    float y2 = d2 * rst * gg.z + bb.z, y3 = d3 * rst * gg.w + bb.w;
    if (RELU) {
        y0 = fmaxf(y0, 0.f); y1 = fmaxf(y1, 0.f);
        y2 = fmaxf(y2, 0.f); y3 = fmaxf(y3, 0.f);
    }
    union { __hip_bfloat16 h[4]; ushort4 v; } pk;
    pk.h[0] = f2bf(y0); pk.h[1] = f2bf(y1); pk.h[2] = f2bf(y2); pk.h[3] = f2bf(y3);
    ((ushort4*)(Z + (size_t)row * DD))[l] = pk.v;
}

// ---------------- final head ----------------
__global__ __launch_bounds__(256) void head2(const __hip_bfloat16* __restrict__ Y1,
                                             const float* __restrict__ w,
                                             const float* __restrict__ b,
                                             float* __restrict__ out) {
    __shared__ float red[8];
    int i = blockIdx.x, tid = threadIdx.x;
    float s = bf2f(Y1[(size_t)i * 512 + tid]) * w[tid] +
              bf2f(Y1[(size_t)i * 512 + 256 + tid]) * w[256 + tid];
    float bs = block_reduce_sum256(s, red);
    if (tid == 0) out[i] = bs + b[0];
}

__global__ void lstab_k(const float* __restrict__ SC, float* __restrict__ dst) {
    if (threadIdx.x == 0 && blockIdx.x == 0) {
        float s = 0.f;
        for (int m = 0; m < 3; ++m)
            s += fabsf(sqrtf(SC[6 + m]) - sqrtf(SC[9 + m]));
        dst[0] = s;
    }
}

// ===========================================================================
#define GEMM(OUTM_, BIAS_, RELU_, A_, Bt_, BI_, C_, M_, N_, K_)                 \
    gemm_mfma<OUTM_, BIAS_, RELU_>                                              \
        <<<dim3((N_) / 128, (M_) / 128), 256, 0, stream>>>(                     \
            (const ushort*)(A_), (const ushort*)(Bt_), (BI_), (void*)(C_),      \
            (M_), (N_), (K_))
#define GEMMZ(A_, Bt_, C_, M_, N_, K_, Z_)                                      \
    gemm_mfma<0, false, false>                                                  \
        <<<dim3((N_) / 128, (M_) / 128, (Z_)), 256, 0, stream>>>(               \
            (const ushort*)(A_), (const ushort*)(Bt_), (const float*)nullptr,   \
            (void*)(C_), (M_), (N_), (K_))

extern "C" void kernel_launch(void* const* d_in, const int* in_sizes, int n_in,
                              void* d_out, int out_size, void* d_ws, size_t ws_size,
                              hipStream_t stream) {
    (void)in_sizes; (void)n_in; (void)out_size; (void)ws_size;
    const float* emb0 = (const float*)d_in[0];
    const float* emb1 = (const float*)d_in[1];
    const float* emb2 = (const float*)d_in[2];
    const void* msk0 = d_in[3];
    const void* msk1 = d_in[4];
    const void* msk2 = d_in[5];
    const float* simi_w = (const float*)d_in[6];
    const float* simi_b = (const float*)d_in[7];
    const float* bn_g = (const float*)d_in[8];
    const float* bn_b = (const float*)d_in[9];
    const float* simi_eps = (const float*)d_in[10];
    const float* dissim = (const float*)d_in[11];
    const float* gcn_w = (const float*)d_in[12];
    const float* gcn_b = (const float*)d_in[13];
    const float* adapt_w = (const float*)d_in[14];
    const float* adapt_b = (const float*)d_in[15];
    const float* type_emb = (const float*)d_in[16];
    const float* attn_w = (const float*)d_in[17];
    const float* attn_b = (const float*)d_in[18];
    const float* ffn_w1 = (const float*)d_in[19];
    const float* ffn_b1 = (const float*)d_in[20];
    const float* ffn_w2 = (const float*)d_in[21];
    const float* ffn_b2 = (const float*)d_in[22];
    const float* ln_g = (const float*)d_in[23];
    const float* ln_b = (const float*)d_in[24];
    const float* out_w1 = (const float*)d_in[25];
    const float* out_b1 = (const float*)d_in[26];
    const float* out_w2 = (const float*)d_in[27];
    const float* out_b2 = (const float*)d_in[28];
    float* out = (float*)d_out;

    // ---- workspace layout (~180 MB) ----
    char* wp = (char*)d_ws;
    auto alloc = [&](size_t bytes) -> char* {
        char* p = wp;
        wp += (bytes + 255) & ~(size_t)255;
        return p;
    };
    const int ACH = 512, ACROWS = ACH * LTOK;  // 17408 rows per chunk, 4 chunks
    __hip_bfloat16* Zb = (__hip_bfloat16*)alloc((size_t)NN * LTOK * DD * 2);  // 35.7MB
    char* UN = alloc((size_t)ACROWS * 1024 * 2);                              // 35.7MB union
    __hip_bfloat16* QKVb = (__hip_bfloat16*)UN;                        // 17408x768
    __hip_bfloat16* Ob = (__hip_bfloat16*)(UN + (size_t)ACROWS * 768 * 2);
    __hip_bfloat16* Hfb = (__hip_bfloat16*)UN;                         // 17408x1024
    float* G1 = (float*)alloc((size_t)NN * NN * 4);
    float* G2 = (float*)alloc((size_t)NN * NN * 4);
    float* S = (float*)alloc((size_t)NN * NN * 4);
    __hip_bfloat16* Sb = (__hip_bfloat16*)alloc((size_t)NN * NN * 2);
    float* SLICE = (float*)alloc((size_t)8 * NN * 256 * 4);            // 16MB split-K
    float* P = (float*)alloc((size_t)NN * DD * 4);
    float* E0 = (float*)alloc((size_t)NN * DD * 4);
    __hip_bfloat16* E0b = (__hip_bfloat16*)alloc((size_t)NN * DD * 2);
    __hip_bfloat16* e1b = (__hip_bfloat16*)alloc((size_t)NN * DD * 2);
    __hip_bfloat16* e2b = (__hip_bfloat16*)alloc((size_t)NN * DD * 2);
    __hip_bfloat16* T1b = (__hip_bfloat16*)alloc((size_t)NN * DD * 2);
    __hip_bfloat16* T2b = (__hip_bfloat16*)alloc((size_t)NN * DD * 2);
    __hip_bfloat16* XBb = (__hip_bfloat16*)alloc((size_t)NN * DD * 2);
    __hip_bfloat16* TBt = (__hip_bfloat16*)alloc((size_t)NN * DD * 2);
    __hip_bfloat16* HBb = (__hip_bfloat16*)alloc((size_t)NN * DD * 2);
    __hip_bfloat16* HB2b = (__hip_bfloat16*)alloc((size_t)NN * DD * 2);
    float* I0 = (float*)alloc((size_t)NN * DD * 4);
    float* I1 = (float*)alloc((size_t)NN * DD * 4);
    float* I2 = (float*)alloc((size_t)NN * DD * 4);
    __hip_bfloat16* Y1b = (__hip_bfloat16*)alloc((size_t)NN * 512 * 2);
    __hip_bfloat16* simi_wt = (__hip_bfloat16*)alloc((size_t)9 * 65536 * 2);
    __hip_bfloat16* gcn_wt = (__hip_bfloat16*)alloc((size_t)6 * 65536 * 2);
    __hip_bfloat16* attn_wt = (__hip_bfloat16*)alloc((size_t)8 * 65536 * 2);
    __hip_bfloat16* w1t = (__hip_bfloat16*)alloc((size_t)2 * 262144 * 2);
    __hip_bfloat16* w2t = (__hip_bfloat16*)alloc((size_t)2 * 262144 * 2);
    __hip_bfloat16* ow1t = (__hip_bfloat16*)alloc((size_t)8704 * 512 * 2);
    float* MV = (float*)alloc(512 * 4);
    float* SQ = (float*)alloc(NN * 4);
    float* PART = (float*)alloc(2048 * 4);
    float* SC = (float*)alloc(64 * 4);
    int* TOK = (int*)alloc((size_t)NN * LTOK * 4);
    int* MK = (int*)alloc((size_t)3 * NN * 4);

    // ---- weight transpose-convert (f32 [R,C] -> bf16 [C,R]) ----
    auto TR = [&](const float* src, __hip_bfloat16* dst, int R, int C) {
        cvt_trans<<<dim3(C / 32, R / 32), 256, 0, stream>>>(src, dst, R, C);
    };
    for (int i = 0; i < 9; ++i) TR(simi_w + (size_t)i * 65536, simi_wt + (size_t)i * 65536, 256, 256);
    for (int i = 0; i < 6; ++i) TR(gcn_w + (size_t)i * 65536, gcn_wt + (size_t)i * 65536, 256, 256);
    for (int i = 0; i < 8; ++i) TR(attn_w + (size_t)i * 65536, attn_wt + (size_t)i * 65536, 256, 256);
    for (int i = 0; i < 2; ++i) TR(ffn_w1 + (size_t)i * 262144, w1t + (size_t)i * 262144, 256, 1024);
    for (int i = 0; i < 2; ++i) TR(ffn_w2 + (size_t)i * 262144, w2t + (size_t)i * 262144, 1024, 256);
    TR(out_w1, ow1t, 8704, 512);

    // ---- prep ----
    gather_e0<<<NN, 256, 0, stream>>>(emb0, E0, E0b);
    cvt_flat<<<(NN * DD / 4 + 255) / 256, 256, 0, stream>>>(emb1, e1b, NN * DD / 4);
    cvt_flat<<<(NN * DD / 4 + 255) / 256, 256, 0, stream>>>(emb2, e2b, NN * DD / 4);
    detect_mode<<<1, 64, 0, stream>>>(msk1, (int*)SC + 16);
    build_masks<<<(NN * LTOK + 255) / 256, 256, 0, stream>>>(msk0, msk1, msk2,
                                                             (int*)SC + 16, MK, TOK);

    const float* Ef[3] = {E0, emb1, emb2};
    const __hip_bfloat16* Eb[3] = {E0b, e1b, e2b};

    // ---- Stage A: per-modal similarity kernels ----
    for (int m = 0; m < 3; ++m) {
        GEMM(1, true, true, Eb[m], simi_wt + (size_t)(m * 3 + 0) * 65536,
             simi_b + (m * 3 + 0) * 256, T1b, NN, 256, 256);
        GEMM(1, true, true, T1b, simi_wt + (size_t)(m * 3 + 1) * 65536,
             simi_b + (m * 3 + 1) * 256, T2b, NN, 256, 256);
        GEMM(0, true, false, T2b, simi_wt + (size_t)(m * 3 + 2) * 65536,
             simi_b + (m * 3 + 2) * 256, P, NN, 256, 256);
        sumsq_partial<<<512, 256, 0, stream>>>(P, NN * DD, PART);
        reduce_sum<<<1, 256, 0, stream>>>(PART, 512, SC + 6 + m);
        sumsq_partial<<<512, 256, 0, stream>>>(Ef[m], NN * DD, PART);
        reduce_sum<<<1, 256, 0, stream>>>(PART, 512, SC + 9 + m);
        // wgk = gk(bn(relu(p)))
        colstats<true><<<256, 256, 0, stream>>>(P, MV, NN);
        bn_apply<true><<<NN, 256, 0, stream>>>(P, MV, bn_g, bn_b, XBb);
        rowsq<<<NN, 256, 0, stream>>>(XBb, SQ);
        gemm_dist<<<dim3(16, 16), 256, 0, stream>>>((const ushort*)XBb, SQ, G1, PART);
        reduce_sum<<<1, 256, 0, stream>>>(PART, 256, SC + 0);
        // gk = gk(bn(e))
        colstats<false><<<256, 256, 0, stream>>>(Ef[m], MV, NN);
        bn_apply<false><<<NN, 256, 0, stream>>>(Ef[m], MV, bn_g, bn_b, XBb);
        rowsq<<<NN, 256, 0, stream>>>(XBb, SQ);
        gemm_dist<<<dim3(16, 16), 256, 0, stream>>>((const ushort*)XBb, SQ, G2, PART);
        reduce_sum<<<1, 256, 0, stream>>>(PART, 256, SC + 1);
        if (m == 0)
            gk_sim_fused<true><<<4096, 256, 0, stream>>>(
                (const float4*)G1, (const float4*)G2, SC, MK, simi_eps + m, (float4*)S);
        else
            gk_sim_fused<false><<<4096, 256, 0, stream>>>(
                (const float4*)G1, (const float4*)G2, SC, MK + m * NN, simi_eps + m,
                (float4*)S);
    }

    // ---- Stage B: aggregation + GCN imputation (split-K Z=8) ----
    agg_cvt<<<4096, 256, 0, stream>>>((const float4*)S, MK, MK + NN, MK + 2 * NN,
                                      dissim, (ushort4*)Sb);
    float* IMP[3] = {I0, I1, I2};
    for (int m = 0; m < 3; ++m) {
        GEMM(2, false, false, Eb[m], gcn_wt + (size_t)(m * 2 + 0) * 65536,
             (const float*)nullptr, TBt, NN, 256, 256);
        GEMMZ(Sb, TBt, SLICE, NN, 256, NN, 8);
        slice_fin<8, true><<<512, 256, 0, stream>>>(SLICE, gcn_b + (m * 2 + 0) * 256,
                                                    HBb, 256, (size_t)NN * 256);
        GEMM(2, false, false, HBb, gcn_wt + (size_t)(m * 2 + 1) * 65536,
             (const float*)nullptr, TBt, NN, 256, 256);
        GEMMZ(Sb, TBt, SLICE, NN, 256, NN, 8);
        slice_fin<8, true><<<512, 256, 0, stream>>>(SLICE, gcn_b + (m * 2 + 1) * 256,
                                                    HB2b, 256, (size_t)NN * 256);
        impute_k<<<NN, 256, 0, stream>>>(Ef[m], HB2b, adapt_w + m * 256, adapt_b + m,
                                         MK + m * NN, IMP[m]);
    }

    // ---- Stage C: 34-token transformer (bf16 Z) ----
    build_z<<<NN * LTOK, 256, 0, stream>>>(emb0, I0, I1, I2, type_emb, Zb);
    const int NCHUNK = NN / ACH;  // 4
    for (int li = 0; li < 2; ++li) {
        for (int c = 0; c < NCHUNK; ++c) {
            __hip_bfloat16* Zc = Zb + (size_t)c * ACROWS * DD;
            GEMM(1, true, false, Zc, attn_wt + (size_t)(li * 4) * 65536,
                 attn_b + li * 4 * 256, QKVb, ACROWS, 768, 256);
            if (li == 0)
                attn_fused<64><<<dim3(ACH, 4), 256, 0, stream>>>(QKVb, TOK, Ob, c * ACH);
            else
                attn_fused<256><<<dim3(ACH, 1), 256, 0, stream>>>(QKVb, TOK, Ob, c * ACH);
            GEMM(3, true, false, Ob, attn_wt + (size_t)(li * 4 + 3) * 65536,
                 attn_b + (li * 4 + 3) * 256, Zc, ACROWS, 256, 256);
        }
        ln_rows<false><<<NN * LTOK / 4, 256, 0, stream>>>(Zb, ln_g + (li * 2 + 0) * 256,
                                                          ln_b + (li * 2 + 0) * 256);
        for (int c = 0; c < NCHUNK; ++c) {
            __hip_bfloat16* Zc = Zb + (size_t)c * ACROWS * DD;
            GEMM(1, true, true, Zc, w1t + (size_t)li * 262144, ffn_b1 + li * 1024,
                 Hfb, ACROWS, 1024, 256);
            GEMM(3, true, false, Hfb, w2t + (size_t)li * 262144, ffn_b2 + li * 256,
                 Zc, ACROWS, 256, 1024);
        }
        ln_rows<true><<<NN * LTOK / 4, 256, 0, stream>>>(Zb, ln_g + (li * 2 + 1) * 256,
                                                         ln_b + (li * 2 + 1) * 256);
    }

    // ---- head (split-K Z=4) ----
    GEMMZ(Zb, ow1t, SLICE, NN, 512, LTOK * DD, 4);
    slice_fin<4, true><<<1024, 256, 0, stream>>>(SLICE, out_b1, Y1b, 512,
                                                 (size_t)NN * 512);
    head2<<<NN, 256, 0, stream>>>(Y1b, out_w2, out_b2, out);
    lstab_k<<<1, 64, 0, stream>>>(SC, out + NN);
}

// Round 5
// 1421.181 us; speedup vs baseline: 4.8466x; 1.1717x over previous
//
#include <hip/hip_runtime.h>
#include <hip/hip_bf16.h>

// ---------------------------------------------------------------------------
// M3Care forward — bf16 MFMA GEMMs (global_load_lds staging + XCD swizzle +
// split-K + z-batched small GEMMs), fused elementwise, PE table, conflict-free
// bf16 attention. N=2048, D=256, T=32, NE=34 tokens, heads=(4,1).
// ---------------------------------------------------------------------------

#define NN 2048
#define DD 256
#define LTOK 34

typedef __attribute__((ext_vector_type(8))) short bf16x8;
typedef __attribute__((ext_vector_type(4))) float f32x4;

__device__ __forceinline__ float bf2f(__hip_bfloat16 x) { return __bfloat162float(x); }
__device__ __forceinline__ __hip_bfloat16 f2bf(float x) { return __float2bfloat16(x); }
__device__ __forceinline__ float us2f(ushort u) {
    unsigned x = (unsigned)u << 16;
    float f;
    __builtin_memcpy(&f, &x, 4);
    return f;
}

// ---------------- block reduce (blockDim.x == 256) ----------------
__device__ __forceinline__ float block_reduce_sum256(float v, float* red) {
    for (int o = 32; o > 0; o >>= 1) v += __shfl_down(v, o, 64);
    int tid = threadIdx.x;
    if ((tid & 63) == 0) red[tid >> 6] = v;
    __syncthreads();
    float s = red[0] + red[1] + red[2] + red[3];
    __syncthreads();
    return s;
}

// XCD-chunked bijective remap (T1, m204 variant).
__device__ __forceinline__ int xcd_remap(int lin, int nwg) {
    int q = nwg >> 3, r = nwg & 7;
    int xcd = lin & 7, pos = lin >> 3;
    return (xcd < r ? xcd * (q + 1) : r * (q + 1) + (xcd - r) * q) + pos;
}

// Stage one 128x64 bf16 tile via global_load_lds (16B/lane), linear LDS dest,
// inverse-XOR-swizzled per-lane GLOBAL source (rule #21).
__device__ __forceinline__ void stage_tile(const ushort* __restrict__ src,
                                           ushort* lds, int grow0, size_t ldk,
                                           int k0, int wv, int l) {
#pragma unroll
    for (int c = 0; c < 4; ++c) {
        int rowbase = wv * 32 + c * 8;
        int row = rowbase + (l >> 3);
        int sx = ((l & 7) ^ (row & 7)) * 8;
        __builtin_amdgcn_global_load_lds(
            (const __attribute__((address_space(1))) void*)(src + (size_t)(grow0 + row) * ldk + k0 + sx),
            (__attribute__((address_space(3))) void*)(lds + rowbase * 64), 16, 0, 0);
    }
}

// ---------------------------------------------------------------------------
// bf16 MFMA GEMM (big/split-K): C[M,N] = A[M,K] @ Bt[N,K]^T (+bias)
// OUTM: 0 = f32 out (slice z*M*N), 1 = bf16 out, 3 = bf16 in-place add.
// ---------------------------------------------------------------------------
template <int OUTM, bool BIAS, bool RELU>
__global__ __launch_bounds__(256) void gemm_mfma(
    const ushort* __restrict__ A, const ushort* __restrict__ Bt,
    const float* __restrict__ bias, void* __restrict__ Cout,
    int M, int N, int K)
{
    __shared__ __align__(16) ushort As[128 * 64];
    __shared__ __align__(16) ushort Bs[128 * 64];
    const int gx = gridDim.x;
    int lin = xcd_remap(blockIdx.y * gx + blockIdx.x, gx * gridDim.y);
    const int bm = (lin / gx) * 128, bn = (lin % gx) * 128;
    const int tid = threadIdx.x;
    const int l = tid & 63, wv = tid >> 6;
    const int wr = wv >> 1, wc = wv & 1;
    const int l16 = l >> 4, lr = l & 15;
    const int kpz = K / gridDim.z;
    const int kbeg = blockIdx.z * kpz, kend = kbeg + kpz;
    f32x4 zero = {0.f, 0.f, 0.f, 0.f};
    f32x4 acc[4][4];
#pragma unroll
    for (int i = 0; i < 4; ++i)
#pragma unroll
        for (int j = 0; j < 4; ++j) acc[i][j] = zero;

    for (int k0 = kbeg; k0 < kend; k0 += 64) {
        stage_tile(A, As, bm, K, k0, wv, l);
        stage_tile(Bt, Bs, bn, K, k0, wv, l);
        __syncthreads();
#pragma unroll
        for (int kk = 0; kk < 2; ++kk) {
            bf16x8 av[4], bv[4];
#pragma unroll
            for (int f = 0; f < 4; ++f) {
                int ra = wr * 64 + f * 16 + lr;
                av[f] = *(const bf16x8*)(As + ra * 64 + (((kk * 4 + l16) ^ (ra & 7)) * 8));
                int rb = wc * 64 + f * 16 + lr;
                bv[f] = *(const bf16x8*)(Bs + rb * 64 + (((kk * 4 + l16) ^ (rb & 7)) * 8));
            }
#pragma unroll
            for (int mf = 0; mf < 4; ++mf)
#pragma unroll
                for (int nf = 0; nf < 4; ++nf)
                    acc[mf][nf] = __builtin_amdgcn_mfma_f32_16x16x32_bf16(
                        av[mf], bv[nf], acc[mf][nf], 0, 0, 0);
        }
        __syncthreads();
    }
    float* Cf = (float*)Cout + (size_t)blockIdx.z * M * N;
#pragma unroll
    for (int mf = 0; mf < 4; ++mf) {
#pragma unroll
        for (int nf = 0; nf < 4; ++nf) {
            int col = bn + wc * 64 + nf * 16 + lr;
            float bb = BIAS ? bias[col] : 0.f;
#pragma unroll
            for (int r = 0; r < 4; ++r) {
                int row = bm + wr * 64 + mf * 16 + l16 * 4 + r;
                float v = acc[mf][nf][r] + bb;
                if (OUTM == 3)
                    v += bf2f(((const __hip_bfloat16*)Cout)[(size_t)row * N + col]);
                if (RELU) v = fmaxf(v, 0.f);
                if (OUTM == 0)
                    Cf[(size_t)row * N + col] = v;
                else
                    ((__hip_bfloat16*)Cout)[(size_t)row * N + col] = f2bf(v);
            }
        }
    }
}

// ---------------------------------------------------------------------------
// z-batched small GEMM (K<=256, one K-loop; z = batch index):
// A += z*aoffZ (row stride lda), Bt += z*boffZ, bias += z*biasoffZ,
// C += z*coffZ. OUTM: 0=f32 [row*ldc+col], 1=bf16 [row*ldc+col],
// 2=bf16 transposed [col*M+row]. PSUM: per-block sum of v^2 -> psum.
// ---------------------------------------------------------------------------
template <int OUTM, bool RELU, bool BIAS, bool PSUM>
__global__ __launch_bounds__(256) void gemm_batch(
    const ushort* __restrict__ A, int lda, size_t aoffZ,
    const ushort* __restrict__ Bt, size_t boffZ,
    const float* __restrict__ bias, int biasoffZ,
    void* __restrict__ Cout, int ldc, size_t coffZ,
    float* __restrict__ psum, int M, int N, int K)
{
    __shared__ __align__(16) ushort As[128 * 64];
    __shared__ __align__(16) ushort Bs[128 * 64];
    __shared__ float red[8];
    const int gx = gridDim.x;
    const int lin0 = blockIdx.y * gx + blockIdx.x;
    int lin = xcd_remap(lin0, gx * gridDim.y);
    const int bm = (lin / gx) * 128, bn = (lin % gx) * 128;
    const int z = blockIdx.z;
    A += (size_t)z * aoffZ;
    Bt += (size_t)z * boffZ;
    if (BIAS) bias += (size_t)z * biasoffZ;
    const int tid = threadIdx.x;
    const int l = tid & 63, wv = tid >> 6;
    const int wr = wv >> 1, wc = wv & 1;
    const int l16 = l >> 4, lr = l & 15;
    f32x4 zero = {0.f, 0.f, 0.f, 0.f};
    f32x4 acc[4][4];
#pragma unroll
    for (int i = 0; i < 4; ++i)
#pragma unroll
        for (int j = 0; j < 4; ++j) acc[i][j] = zero;

    for (int k0 = 0; k0 < K; k0 += 64) {
        stage_tile(A, As, bm, lda, k0, wv, l);
        stage_tile(Bt, Bs, bn, K, k0, wv, l);
        __syncthreads();
#pragma unroll
        for (int kk = 0; kk < 2; ++kk) {
            bf16x8 av[4], bv[4];
#pragma unroll
            for (int f = 0; f < 4; ++f) {
                int ra = wr * 64 + f * 16 + lr;
                av[f] = *(const bf16x8*)(As + ra * 64 + (((kk * 4 + l16) ^ (ra & 7)) * 8));
                int rb = wc * 64 + f * 16 + lr;
                bv[f] = *(const bf16x8*)(Bs + rb * 64 + (((kk * 4 + l16) ^ (rb & 7)) * 8));
            }
#pragma unroll
            for (int mf = 0; mf < 4; ++mf)
#pragma unroll
                for (int nf = 0; nf < 4; ++nf)
                    acc[mf][nf] = __builtin_amdgcn_mfma_f32_16x16x32_bf16(
                        av[mf], bv[nf], acc[mf][nf], 0, 0, 0);
        }
        __syncthreads();
    }
    float lsq = 0.f;
#pragma unroll
    for (int mf = 0; mf < 4; ++mf) {
#pragma unroll
        for (int nf = 0; nf < 4; ++nf) {
            int col = bn + wc * 64 + nf * 16 + lr;
            float bb = BIAS ? bias[col] : 0.f;
#pragma unroll
            for (int r = 0; r < 4; ++r) {
                int row = bm + wr * 64 + mf * 16 + l16 * 4 + r;
                float v = acc[mf][nf][r] + bb;
                if (RELU) v = fmaxf(v, 0.f);
                if (PSUM) lsq += v * v;
                if (OUTM == 0)
                    ((float*)Cout + (size_t)z * coffZ)[(size_t)row * ldc + col] = v;
                else if (OUTM == 2)
                    ((__hip_bfloat16*)Cout + (size_t)z * coffZ)[(size_t)col * M + row] = f2bf(v);
                else
                    ((__hip_bfloat16*)Cout + (size_t)z * coffZ)[(size_t)row * ldc + col] = f2bf(v);
            }
        }
    }
    if (PSUM) {
        float bs = block_reduce_sum256(lsq, red);
        if (tid == 0) psum[z * gx * gridDim.y + lin0] = bs;
    }
}

// ---------------------------------------------------------------------------
// Pairwise distance (z-batched over 2 inputs): G[z][i,j] = max(sq+sq-2dot,0)
// ---------------------------------------------------------------------------
__global__ __launch_bounds__(256) void gemm_dist2(
    const ushort* __restrict__ XB, const float* __restrict__ SQ,
    float* __restrict__ Gx, float* __restrict__ part)
{
    __shared__ __align__(16) ushort As[128 * 64];
    __shared__ __align__(16) ushort Bs[128 * 64];
    __shared__ float red[8];
    const int gx = gridDim.x;
    const int lin0 = blockIdx.y * gx + blockIdx.x;
    int lin = xcd_remap(lin0, gx * gridDim.y);
    const int bm = (lin / gx) * 128, bn = (lin % gx) * 128;
    const int z = blockIdx.z;
    const ushort* X = XB + (size_t)z * NN * DD;
    const float* sq = SQ + (size_t)z * NN;
    float* G = Gx + (size_t)z * NN * NN;
    const int tid = threadIdx.x;
    const int l = tid & 63, wv = tid >> 6;
    const int wr = wv >> 1, wc = wv & 1;
    const int l16 = l >> 4, lr = l & 15;
    f32x4 zero = {0.f, 0.f, 0.f, 0.f};
    f32x4 acc[4][4];
#pragma unroll
    for (int i = 0; i < 4; ++i)
#pragma unroll
        for (int j = 0; j < 4; ++j) acc[i][j] = zero;

    for (int k0 = 0; k0 < 256; k0 += 64) {
        stage_tile(X, As, bm, 256, k0, wv, l);
        stage_tile(X, Bs, bn, 256, k0, wv, l);
        __syncthreads();
#pragma unroll
        for (int kk = 0; kk < 2; ++kk) {
            bf16x8 av[4], bv[4];
#pragma unroll
            for (int f = 0; f < 4; ++f) {
                int ra = wr * 64 + f * 16 + lr;
                av[f] = *(const bf16x8*)(As + ra * 64 + (((kk * 4 + l16) ^ (ra & 7)) * 8));
                int rb = wc * 64 + f * 16 + lr;
                bv[f] = *(const bf16x8*)(Bs + rb * 64 + (((kk * 4 + l16) ^ (rb & 7)) * 8));
            }
#pragma unroll
            for (int mf = 0; mf < 4; ++mf)
#pragma unroll
                for (int nf = 0; nf < 4; ++nf)
                    acc[mf][nf] = __builtin_amdgcn_mfma_f32_16x16x32_bf16(
                        av[mf], bv[nf], acc[mf][nf], 0, 0, 0);
        }
        __syncthreads();
    }
    float lsum = 0.f;
#pragma unroll
    for (int mf = 0; mf < 4; ++mf) {
#pragma unroll
        for (int nf = 0; nf < 4; ++nf) {
            int col = bn + wc * 64 + nf * 16 + lr;
#pragma unroll
            for (int r = 0; r < 4; ++r) {
                int row = bm + wr * 64 + mf * 16 + l16 * 4 + r;
                float d = fmaxf(sq[row] + sq[col] - 2.f * acc[mf][nf][r], 0.f);
                G[(size_t)row * NN + col] = d;
                lsum += d;
            }
        }
    }
    float bs = block_reduce_sum256(lsum, red);
    if (tid == 0) part[z * 256 + lin0] = bs;
}

// ---------------- split-K finalize ----------------
template <int Z, bool RELU>
__global__ __launch_bounds__(256) void slice_fin(const float* __restrict__ SL,
                                                 const float* __restrict__ bias,
                                                 __hip_bfloat16* __restrict__ out,
                                                 int N, size_t MN) {
    size_t v = (size_t)blockIdx.x * 256 + threadIdx.x;
    const float4* S4 = (const float4*)SL;
    size_t MN4 = MN >> 2;
    float4 s = S4[v];
#pragma unroll
    for (int z = 1; z < Z; ++z) {
        float4 t = S4[(size_t)z * MN4 + v];
        s.x += t.x; s.y += t.y; s.z += t.z; s.w += t.w;
    }
    float4 bb = ((const float4*)bias)[v % (size_t)(N >> 2)];
    s.x += bb.x; s.y += bb.y; s.z += bb.z; s.w += bb.w;
    if (RELU) {
        s.x = fmaxf(s.x, 0.f); s.y = fmaxf(s.y, 0.f);
        s.z = fmaxf(s.z, 0.f); s.w = fmaxf(s.w, 0.f);
    }
    union { __hip_bfloat16 h[4]; ushort4 u; } pk;
    pk.h[0] = f2bf(s.x); pk.h[1] = f2bf(s.y);
    pk.h[2] = f2bf(s.z); pk.h[3] = f2bf(s.w);
    ((ushort4*)out)[v] = pk.u;
}

// ---------------- conversions ----------------
__global__ void cvt_flat(const float* __restrict__ in, __hip_bfloat16* __restrict__ out,
                         int n4) {
    int i = blockIdx.x * 256 + threadIdx.x;
    if (i < n4) {
        float4 v = ((const float4*)in)[i];
        union { __hip_bfloat16 h[4]; ushort4 u; } pk;
        pk.h[0] = f2bf(v.x); pk.h[1] = f2bf(v.y);
        pk.h[2] = f2bf(v.z); pk.h[3] = f2bf(v.w);
        ((ushort4*)out)[i] = pk.u;
    }
}

__global__ __launch_bounds__(256) void cvt_trans(const float* __restrict__ in,
                                                 __hip_bfloat16* __restrict__ out,
                                                 int R, int C) {
    __shared__ float t[32][33];
    int bc = blockIdx.x * 32, br = blockIdx.y * 32;
    int tx = threadIdx.x & 31, ty = threadIdx.x >> 5;
#pragma unroll
    for (int i = 0; i < 32; i += 8)
        t[ty + i][tx] = in[(size_t)(br + ty + i) * C + bc + tx];
    __syncthreads();
#pragma unroll
    for (int i = 0; i < 32; i += 8)
        out[(size_t)(bc + ty + i) * R + br + tx] = f2bf(t[tx][ty + i]);
}

// ---------------- fused multi-bandwidth GK + sim accumulation --------------
template <bool FIRST>
__global__ __launch_bounds__(256) void gk_sim_fused(
    const float4* __restrict__ G1, const float4* __restrict__ G2,
    const float* __restrict__ bws, const int* __restrict__ mk,
    const float* __restrict__ epsp, float4* __restrict__ S) {
    size_t v = (size_t)blockIdx.x * 256 + threadIdx.x;
    int i = (int)(v >> 9);
    int j0 = (int)((v & 511) << 2);
    float eps = 1.f / (1.f + __expf(-epsp[0]));
    const float cnn = 1.f / ((float)NN * NN - (float)NN);
    float ia = 2.f / (bws[0] * cnn);
    float ib = 2.f / (bws[1] * cnn);
    float4 d1 = G1[v], d2 = G2[v];
    int mi = mk[i];
    float4 r;
#define GKCOMP(X, J)                                                              \
    {                                                                             \
        float w = __expf(-d1.X * ia) + __expf(-d1.X * (0.5f * ia)) +              \
                  __expf(-d1.X * (0.25f * ia));                                   \
        float g = __expf(-d2.X * ib) + __expf(-d2.X * (0.5f * ib)) +              \
                  __expf(-d2.X * (0.25f * ib));                                   \
        float val = ((1.f - eps) * w + eps) * g;                                  \
        r.X = (mi && mk[j0 + J]) ? val : 0.f;                                     \
    }
    GKCOMP(x, 0) GKCOMP(y, 1) GKCOMP(z, 2) GKCOMP(w, 3)
#undef GKCOMP
    if (FIRST) {
        S[v] = r;
    } else {
        float4 o = S[v];
        r.x += o.x; r.y += o.y; r.z += o.z; r.w += o.w;
        S[v] = r;
    }
}

// ---------------- aggregation + threshold gate + bf16 convert --------------
__global__ __launch_bounds__(256) void agg_cvt(
    const float4* __restrict__ S, const int* __restrict__ mk0,
    const int* __restrict__ mk1, const int* __restrict__ mk2,
    const float* __restrict__ dissim, ushort4* __restrict__ Sb) {
    size_t v = (size_t)blockIdx.x * 256 + threadIdx.x;
    int i = (int)(v >> 9);
    int j0 = (int)((v & 511) << 2);
    float thr = 1.f / (1.f + __expf(-dissim[0]));
    float4 s = S[v];
    int m0i = mk0[i], m1i = mk1[i], m2i = mk2[i];
    union { __hip_bfloat16 h[4]; ushort4 u; } pk;
#define AGGC(X, J)                                                                \
    {                                                                             \
        int j = j0 + J;                                                           \
        int cnt = ((m0i && mk0[j]) ? 1 : 0) + ((m1i && mk1[j]) ? 1 : 0) +         \
                  ((m2i && mk2[j]) ? 1 : 0);                                      \
        float a = cnt ? s.X / (float)cnt : 0.f;                                   \
        pk.h[J] = f2bf((a > thr) ? a : 0.f);                                      \
    }
    AGGC(x, 0) AGGC(y, 1) AGGC(z, 2) AGGC(w, 3)
#undef AGGC
    Sb[v] = pk.u;
}

// ---------------- BatchNorm column stats, z-batched over {P(relu), E} ------
__global__ __launch_bounds__(256) void colstats2(const float* __restrict__ X0,
                                                 const float* __restrict__ X1,
                                                 float* __restrict__ mv, int nrows) {
    __shared__ float red[8];
    int c = blockIdx.x, z = blockIdx.y, tid = threadIdx.x;
    const float* X = z ? X1 : X0;
    float s = 0.f, sq = 0.f;
    for (int r = tid; r < nrows; r += 256) {
        float v = X[(size_t)r * DD + c];
        if (z == 0) v = fmaxf(v, 0.f);
        s += v; sq += v * v;
    }
    float ts = block_reduce_sum256(s, red);
    float tq = block_reduce_sum256(sq, red);
    if (tid == 0) {
        float m = ts / (float)nrows;
        mv[z * 512 + c] = m;
        mv[z * 512 + 256 + c] = tq / (float)nrows - m * m;
    }
}

// ---------------- fused BN-apply + rowsq, z-batched (block = row) ----------
__global__ __launch_bounds__(256) void bn_fuse2(const float* __restrict__ X0,
                                                const float* __restrict__ X1,
                                                const float* __restrict__ mv,
                                                const float* __restrict__ g,
                                                const float* __restrict__ b,
                                                ushort* __restrict__ XB,
                                                float* __restrict__ SQ) {
    __shared__ float red[8];
    int r = blockIdx.x, z = blockIdx.y, c = threadIdx.x;
    float v = (z ? X1 : X0)[(size_t)r * DD + c];
    if (z == 0) v = fmaxf(v, 0.f);
    float y = (v - mv[z * 512 + c]) * rsqrtf(mv[z * 512 + 256 + c] + 1e-5f) * g[c] + b[c];
    __hip_bfloat16 yb = f2bf(y);
    XB[(size_t)z * NN * DD + (size_t)r * DD + c] = *(ushort*)&yb;
    float yr = bf2f(yb);
    float s = block_reduce_sum256(yr * yr, red);
    if (c == 0) SQ[z * NN + r] = s;
}

// ---------------- sum-of-squares partial (deterministic) ----------------
__global__ __launch_bounds__(256) void sumsq_partial(const float* __restrict__ X, int n,
                                                     float* __restrict__ part) {
    __shared__ float red[8];
    int tid = threadIdx.x;
    float s = 0.f;
    for (size_t idx = (size_t)blockIdx.x * 256 + tid; idx < (size_t)n;
         idx += (size_t)gridDim.x * 256) {
        float v = X[idx];
        s += v * v;
    }
    float bs = block_reduce_sum256(s, red);
    if (tid == 0) part[blockIdx.x] = bs;
}

// ---------------- PART reductions ----------------
// reduce2: dist sums -> SC[0], SC[1]
__global__ __launch_bounds__(256) void reduce2(const float* __restrict__ part,
                                               float* __restrict__ SC) {
    __shared__ float red[8];
    int z = blockIdx.x, tid = threadIdx.x;
    float s = part[z * 256 + tid];
    float bs = block_reduce_sum256(s, red);
    if (tid == 0) SC[z] = bs;
}
// reduce6: blocks 0..2 -> |E|^2 (PART+512+b*512, n=512) -> SC[9+b];
//          blocks 3..5 -> |P|^2 (PART+2048+(b-3)*32, n=32) -> SC[6+(b-3)]
__global__ __launch_bounds__(256) void reduce6(const float* __restrict__ part,
                                               float* __restrict__ SC) {
    __shared__ float red[8];
    int b = blockIdx.x, tid = threadIdx.x;
    const float* src; int n, dst;
    if (b < 3) { src = part + 512 + b * 512; n = 512; dst = 9 + b; }
    else { src = part + 2048 + (b - 3) * 32; n = 32; dst = 6 + (b - 3); }
    float s = 0.f;
    for (int i = tid; i < n; i += 256) s += src[i];
    float bs = block_reduce_sum256(s, red);
    if (tid == 0) SC[dst] = bs;
}

// ---------------- adapt-gate imputation (one block per sample) -------------
__global__ __launch_bounds__(256) void impute_k(
    const float* __restrict__ E, const __hip_bfloat16* __restrict__ H, int ldh,
    const float* __restrict__ aw, const float* __restrict__ ab,
    const int* __restrict__ mk, float* __restrict__ OUT) {
    __shared__ float red[8];
    int i = blockIdx.x, tid = threadIdx.x;
    float e = E[(size_t)i * DD + tid], h = bf2f(H[(size_t)i * ldh + tid]), w = aw[tid];
    float se = block_reduce_sum256(e * w, red);
    float sh = block_reduce_sum256(h * w, red);
    float s = 1.f / (1.f + __expf(-(se + ab[0])));
    float o = 1.f / (1.f + __expf(-(sh + ab[0])));
    s = s / (s + o);
    float imp = s * e + (1.f - s) * h;
    float m = mk[i] ? 1.f : 0.f;
    OUT[(size_t)i * DD + tid] = imp * m + (1.f - m) * h;
}

// ---------------- masks ----------------
__global__ void detect_mode(const void* __restrict__ m1, int* __restrict__ modep) {
    if (threadIdx.x == 0 && blockIdx.x == 0) {
        int vi = ((const int*)m1)[0];
        float vf = ((const float*)m1)[0];
        modep[0] = (vi == 1) ? 0 : ((vf == 1.0f) ? 2 : 1);
    }
}

__device__ __forceinline__ int rd_mask(const void* p, int idx, int mode) {
    if (mode == 0) return ((const int*)p)[idx] != 0;
    if (mode == 1) return ((const unsigned char*)p)[idx] != 0;
    return ((const float*)p)[idx] != 0.f;
}

__global__ void build_masks(const void* __restrict__ m0, const void* __restrict__ m1,
                            const void* __restrict__ m2, const int* __restrict__ modep,
                            int* __restrict__ MK, int* __restrict__ TOK) {
    int mode = modep[0];
    int idx = blockIdx.x * 256 + threadIdx.x;
    if (idx < NN) {
        MK[idx] = rd_mask(m0, idx * 32, mode);
        MK[NN + idx] = rd_mask(m1, idx, mode);
        MK[2 * NN + idx] = rd_mask(m2, idx, mode);
    }
    if (idx < NN * LTOK) {
        int i = idx / LTOK, t = idx - i * LTOK;
        TOK[idx] = (t < 32) ? rd_mask(m0, i * 32 + t, mode)
                            : ((t == 32) ? rd_mask(m1, i, mode) : rd_mask(m2, i, mode));
    }
}

// ---------------- gather emb0[:,0,:] ----------------
__global__ void gather_e0(const float* __restrict__ emb0, float* __restrict__ E0,
                          __hip_bfloat16* __restrict__ E0b) {
    int i = blockIdx.x, c = threadIdx.x;
    float v = emb0[(size_t)i * 32 * DD + c];
    E0[(size_t)i * DD + c] = v;
    E0b[(size_t)i * DD + c] = f2bf(v);
}

// ---------------- PE + type_emb[0] table: PET[t][c] ----------------
__global__ void pe_table(const float* __restrict__ type_emb, float* __restrict__ PET) {
    int t = blockIdx.x, c = threadIdx.x;
    float div = __expf((float)((c >> 1) << 1) * (-9.210340371976184f / 256.f));
    float ang = (float)t * div;
    float pe = (c & 1) ? __cosf(ang) : __sinf(ang);
    PET[t * 256 + c] = type_emb[c] + pe;
}

// ---------------- build token sequence (vectorized, table-driven) ----------
__global__ void build_z2(const float4* __restrict__ emb0, const float4* __restrict__ i0,
                         const float4* __restrict__ i1, const float4* __restrict__ i2,
                         const float4* __restrict__ PET,
                         const float4* __restrict__ type_emb,
                         ushort4* __restrict__ Z) {
    int idx = blockIdx.x * 256 + threadIdx.x;   // float4 units
    int c4 = idx & 63;
    int t = (idx >> 6) % LTOK;
    int i = idx / (LTOK * 64);
    float4 v, a;
    if (t < 32) {
        v = (t == 0) ? i0[(size_t)i * 64 + c4]
                     : emb0[((size_t)i * 32 + t) * 64 + c4];
        a = PET[t * 64 + c4];
    } else if (t == 32) {
        v = i1[(size_t)i * 64 + c4];
        a = type_emb[64 + c4];
    } else {
        v = i2[(size_t)i * 64 + c4];
        a = type_emb[128 + c4];
    }
    union { __hip_bfloat16 h[4]; ushort4 u; } pk;
    pk.h[0] = f2bf(v.x + a.x); pk.h[1] = f2bf(v.y + a.y);
    pk.h[2] = f2bf(v.z + a.z); pk.h[3] = f2bf(v.w + a.w);
    Z[idx] = pk.u;
}

// ---------------- fused attention (bf16 LDS, KT pad-38) ----------
template <int DH>
__global__ __launch_bounds__(256) void attn_fused(
    const __hip_bfloat16* __restrict__ QKV, const int* __restrict__ tok,
    __hip_bfloat16* __restrict__ O, int sample0) {
    const int L = LTOK;
    __shared__ ushort Qs[L * DH];
    __shared__ ushort KT[DH * 38];
    __shared__ ushort Vs[L * DH];
    __shared__ float Sc[L][35];
    int b = blockIdx.x, hh = blockIdx.y;
    int tid = threadIdx.x;
    const float scale = rsqrtf((float)DH);
    for (int idx = tid; idx < L * DH; idx += 256) {
        int t = idx / DH, d = idx - t * DH;
        size_t g = (size_t)(b * L + t) * 768 + hh * DH + d;
        const ushort* q = (const ushort*)QKV;
        Qs[idx] = q[g];
        KT[d * 38 + t] = q[g + 256];
        Vs[idx] = q[g + 512];
    }
    __syncthreads();
    const int* tk = tok + (size_t)(sample0 + b) * L;
    for (int idx = tid; idx < L * L; idx += 256) {
        int i = idx / L, j = idx - i * L;
        float acc = 0.f;
#pragma unroll 16
        for (int d = 0; d < DH; ++d)
            acc = fmaf(us2f(Qs[i * DH + d]), us2f(KT[d * 38 + j]), acc);
        Sc[i][j] = (tk[i] && tk[j]) ? acc * scale : -1e9f;
    }
    __syncthreads();
    if (tid < L) {
        float mx = -1e30f;
        for (int j = 0; j < L; ++j) mx = fmaxf(mx, Sc[tid][j]);
        float s = 0.f;
        for (int j = 0; j < L; ++j) {
            float e = __expf(Sc[tid][j] - mx);
            Sc[tid][j] = e; s += e;
        }
        float inv = 1.f / s;
        for (int j = 0; j < L; ++j) Sc[tid][j] *= inv;
    }
    __syncthreads();
    for (int idx = tid; idx < L * DH; idx += 256) {
        int i = idx / DH, d = idx - i * DH;
        float acc = 0.f;
#pragma unroll
        for (int j = 0; j < L; ++j) acc = fmaf(Sc[i][j], us2f(Vs[j * DH + d]), acc);
        O[(size_t)(b * L + i) * DD + hh * DH + d] = f2bf(acc);
    }
}

// ---------------- wave-per-row LayerNorm ----------------
template <bool RELU>
__global__ __launch_bounds__(256) void ln_rows(__hip_bfloat16* __restrict__ Z,
                                               const float* __restrict__ g,
                                               const float* __restrict__ b) {
    int row = (blockIdx.x << 2) + (threadIdx.x >> 6);
    int l = threadIdx.x & 63;
    ushort4 u = ((ushort4*)(Z + (size_t)row * DD))[l];
    float x0 = us2f(u.x), x1 = us2f(u.y), x2 = us2f(u.z), x3 = us2f(u.w);
    float s = x0 + x1 + x2 + x3;
    for (int o = 1; o < 64; o <<= 1) s += __shfl_xor(s, o, 64);
    float mean = s * (1.f / 256.f);
    float d0 = x0 - mean, d1 = x1 - mean, d2 = x2 - mean, d3 = x3 - mean;
    float q = d0 * d0 + d1 * d1 + d2 * d2 + d3 * d3;
    for (int o = 1; o < 64; o <<= 1) q += __shfl_xor(q, o, 64);
    float rst = rsqrtf(q * (1.f / 256.f) + 1e-5f);
    float4 gg = ((const float4*)g)[l], bb = ((const float4*)b)[l];
    float y0 = d0 * rst * gg.x + bb.x, y1 = d1 * rst * gg.y + bb.y;
    float y2 = d2 * rst * gg.z + bb.z, y3 = d3 * rst * gg.w + bb.w;
    if (RELU) {
        y0 = fmaxf(y0, 0.f); y1 = fmaxf(y1, 0.f);
        y2 = fmaxf(y2, 0.f); y3 = fmaxf(y3, 0.f);
    }
    union { __hip_bfloat16 h[4]; ushort4 v; } pk;
    pk.h[0] = f2bf(y0); pk.h[1] = f2bf(y1); pk.h[2] = f2bf(y2); pk.h[3] = f2bf(y3);
    ((ushort4*)(Z + (size_t)row * DD))[l] = pk.v;
}

// ---------------- final head ----------------
__global__ __launch_bounds__(256) void head2(const __hip_bfloat16* __restrict__ Y1,
                                             const float* __restrict__ w,
                                             const float* __restrict__ b,
                                             float* __restrict__ out) {
    __shared__ float red[8];
    int i = blockIdx.x, tid = threadIdx.x;
    float s = bf2f(Y1[(size_t)i * 512 + tid]) * w[tid] +
              bf2f(Y1[(size_t)i * 512 + 256 + tid]) * w[256 + tid];
    float bs = block_reduce_sum256(s, red);
    if (tid == 0) out[i] = bs + b[0];
}

__global__ void lstab_k(const float* __restrict__ SC, float* __restrict__ dst) {
    if (threadIdx.x == 0 && blockIdx.x == 0) {
        float s = 0.f;
        for (int m = 0; m < 3; ++m)
            s += fabsf(sqrtf(SC[6 + m]) - sqrtf(SC[9 + m]));
        dst[0] = s;
    }
}

// gcn bias concat: Bcat[l*768 + m*256 + c] = gcn_b[(m*2+l)*256 + c]
__global__ void gcn_bias_cat(const float* __restrict__ gcn_b, float* __restrict__ Bcat) {
    int m = blockIdx.x, l = blockIdx.y, c = threadIdx.x;
    Bcat[l * 768 + m * 256 + c] = gcn_b[(m * 2 + l) * 256 + c];
}

// ===========================================================================
#define GEMM(OUTM_, BIAS_, RELU_, A_, Bt_, BI_, C_, M_, N_, K_)                 \
    gemm_mfma<OUTM_, BIAS_, RELU_>                                              \
        <<<dim3((N_) / 128, (M_) / 128), 256, 0, stream>>>(                     \
            (const ushort*)(A_), (const ushort*)(Bt_), (BI_), (void*)(C_),      \
            (M_), (N_), (K_))
#define GEMMZ(A_, Bt_, C_, M_, N_, K_, Z_)                                      \
    gemm_mfma<0, false, false>                                                  \
        <<<dim3((N_) / 128, (M_) / 128, (Z_)), 256, 0, stream>>>(               \
            (const ushort*)(A_), (const ushort*)(Bt_), (const float*)nullptr,   \
            (void*)(C_), (M_), (N_), (K_))

extern "C" void kernel_launch(void* const* d_in, const int* in_sizes, int n_in,
                              void* d_out, int out_size, void* d_ws, size_t ws_size,
                              hipStream_t stream) {
    (void)in_sizes; (void)n_in; (void)out_size; (void)ws_size;
    const float* emb0 = (const float*)d_in[0];
    const float* emb1 = (const float*)d_in[1];
    const float* emb2 = (const float*)d_in[2];
    const void* msk0 = d_in[3];
    const void* msk1 = d_in[4];
    const void* msk2 = d_in[5];
    const float* simi_w = (const float*)d_in[6];
    const float* simi_b = (const float*)d_in[7];
    const float* bn_g = (const float*)d_in[8];
    const float* bn_b = (const float*)d_in[9];
    const float* simi_eps = (const float*)d_in[10];
    const float* dissim = (const float*)d_in[11];
    const float* gcn_w = (const float*)d_in[12];
    const float* gcn_b = (const float*)d_in[13];
    const float* adapt_w = (const float*)d_in[14];
    const float* adapt_b = (const float*)d_in[15];
    const float* type_emb = (const float*)d_in[16];
    const float* attn_w = (const float*)d_in[17];
    const float* attn_b = (const float*)d_in[18];
    const float* ffn_w1 = (const float*)d_in[19];
    const float* ffn_b1 = (const float*)d_in[20];
    const float* ffn_w2 = (const float*)d_in[21];
    const float* ffn_b2 = (const float*)d_in[22];
    const float* ln_g = (const float*)d_in[23];
    const float* ln_b = (const float*)d_in[24];
    const float* out_w1 = (const float*)d_in[25];
    const float* out_b1 = (const float*)d_in[26];
    const float* out_w2 = (const float*)d_in[27];
    const float* out_b2 = (const float*)d_in[28];
    float* out = (float*)d_out;

    // ---- workspace layout (~175 MB) ----
    char* wp = (char*)d_ws;
    auto alloc = [&](size_t bytes) -> char* {
        char* p = wp;
        wp += (bytes + 255) & ~(size_t)255;
        return p;
    };
    const int ACH = 512, ACROWS = ACH * LTOK;  // 17408 rows/chunk, 4 chunks
    __hip_bfloat16* Zb = (__hip_bfloat16*)alloc((size_t)NN * LTOK * DD * 2);  // 35.7MB
    char* UN = alloc((size_t)ACROWS * 1024 * 2);   // 35.7MB union: QKV/O | Hf | SLICE
    __hip_bfloat16* QKVb = (__hip_bfloat16*)UN;
    __hip_bfloat16* Ob = (__hip_bfloat16*)(UN + (size_t)ACROWS * 768 * 2);
    __hip_bfloat16* Hfb = (__hip_bfloat16*)UN;
    float* SLICE = (float*)UN;
    float* Gx = (float*)alloc((size_t)2 * NN * NN * 4);   // 32MB
    float* S = (float*)alloc((size_t)NN * NN * 4);        // 16MB
    __hip_bfloat16* Sb = (__hip_bfloat16*)alloc((size_t)NN * NN * 2);  // 8MB
    float* P3 = (float*)alloc((size_t)3 * NN * DD * 4);   // 6MB
    float* E0 = (float*)alloc((size_t)NN * DD * 4);
    __hip_bfloat16* Eb3 = (__hip_bfloat16*)alloc((size_t)3 * NN * DD * 2);
    __hip_bfloat16* T1b3 = (__hip_bfloat16*)alloc((size_t)3 * NN * DD * 2);
    __hip_bfloat16* T2b3 = (__hip_bfloat16*)alloc((size_t)3 * NN * DD * 2);
    ushort* XB2 = (ushort*)alloc((size_t)2 * NN * DD * 2);
    __hip_bfloat16* TBt3 = (__hip_bfloat16*)alloc((size_t)3 * NN * DD * 2);
    __hip_bfloat16* HB3 = (__hip_bfloat16*)alloc((size_t)NN * 768 * 2);
    __hip_bfloat16* HB2_3 = (__hip_bfloat16*)alloc((size_t)NN * 768 * 2);
    float* I0 = (float*)alloc((size_t)NN * DD * 4);
    float* I1 = (float*)alloc((size_t)NN * DD * 4);
    float* I2 = (float*)alloc((size_t)NN * DD * 4);
    __hip_bfloat16* Y1b = (__hip_bfloat16*)alloc((size_t)NN * 512 * 2);
    __hip_bfloat16* simi_wt = (__hip_bfloat16*)alloc((size_t)9 * 65536 * 2);
    __hip_bfloat16* gcn_wt = (__hip_bfloat16*)alloc((size_t)6 * 65536 * 2);
    __hip_bfloat16* attn_wt = (__hip_bfloat16*)alloc((size_t)8 * 65536 * 2);
    __hip_bfloat16* w1t = (__hip_bfloat16*)alloc((size_t)2 * 262144 * 2);
    __hip_bfloat16* w2t = (__hip_bfloat16*)alloc((size_t)2 * 262144 * 2);
    __hip_bfloat16* ow1t = (__hip_bfloat16*)alloc((size_t)8704 * 512 * 2);
    float* PET = (float*)alloc(32 * 256 * 4);
    float* MV2 = (float*)alloc(1024 * 4);
    float* SQ2 = (float*)alloc(2 * NN * 4);
    float* PART = (float*)alloc(4096 * 4);  // [0:512) dist, [512:2048) E, [2048:2144) P
    float* SC = (float*)alloc(64 * 4);
    float* Bcat = (float*)alloc(1536 * 4);
    int* TOK = (int*)alloc((size_t)NN * LTOK * 4);
    int* MK = (int*)alloc((size_t)3 * NN * 4);

    // ---- weight transpose-convert (f32 [R,C] -> bf16 [C,R]) ----
    auto TR = [&](const float* src, __hip_bfloat16* dst, int R, int C) {
        cvt_trans<<<dim3(C / 32, R / 32), 256, 0, stream>>>(src, dst, R, C);
    };
    for (int i = 0; i < 9; ++i) TR(simi_w + (size_t)i * 65536, simi_wt + (size_t)i * 65536, 256, 256);
    for (int i = 0; i < 6; ++i) TR(gcn_w + (size_t)i * 65536, gcn_wt + (size_t)i * 65536, 256, 256);
    for (int i = 0; i < 8; ++i) TR(attn_w + (size_t)i * 65536, attn_wt + (size_t)i * 65536, 256, 256);
    for (int i = 0; i < 2; ++i) TR(ffn_w1 + (size_t)i * 262144, w1t + (size_t)i * 262144, 256, 1024);
    for (int i = 0; i < 2; ++i) TR(ffn_w2 + (size_t)i * 262144, w2t + (size_t)i * 262144, 1024, 256);
    TR(out_w1, ow1t, 8704, 512);

    // ---- prep ----
    pe_table<<<32, 256, 0, stream>>>(type_emb, PET);
    gather_e0<<<NN, 256, 0, stream>>>(emb0, E0, Eb3);
    cvt_flat<<<512, 256, 0, stream>>>(emb1, Eb3 + (size_t)NN * DD, NN * DD / 4);
    cvt_flat<<<512, 256, 0, stream>>>(emb2, Eb3 + (size_t)2 * NN * DD, NN * DD / 4);
    detect_mode<<<1, 64, 0, stream>>>(msk1, (int*)SC + 16);
    build_masks<<<(NN * LTOK + 255) / 256, 256, 0, stream>>>(msk0, msk1, msk2,
                                                             (int*)SC + 16, MK, TOK);
    gcn_bias_cat<<<dim3(3, 2), 256, 0, stream>>>(gcn_b, Bcat);

    const float* Ef[3] = {E0, emb1, emb2};

    // ---- Stage A ----
    // |E|^2 partials (once)
    for (int m = 0; m < 3; ++m)
        sumsq_partial<<<512, 256, 0, stream>>>(Ef[m], NN * DD, PART + 512 + m * 512);
    // batched 3-layer MLP over modals (z = modal); layer 3 fuses |P|^2 partials
    gemm_batch<1, true, true, false><<<dim3(2, 16, 3), 256, 0, stream>>>(
        (const ushort*)Eb3, 256, (size_t)NN * DD, (const ushort*)simi_wt,
        (size_t)3 * 65536, simi_b, 3 * 256, T1b3, 256, (size_t)NN * DD,
        nullptr, NN, 256, 256);
    gemm_batch<1, true, true, false><<<dim3(2, 16, 3), 256, 0, stream>>>(
        (const ushort*)T1b3, 256, (size_t)NN * DD, (const ushort*)(simi_wt + 65536),
        (size_t)3 * 65536, simi_b + 256, 3 * 256, T2b3, 256, (size_t)NN * DD,
        nullptr, NN, 256, 256);
    gemm_batch<0, false, true, true><<<dim3(2, 16, 3), 256, 0, stream>>>(
        (const ushort*)T2b3, 256, (size_t)NN * DD, (const ushort*)(simi_wt + 2 * 65536),
        (size_t)3 * 65536, simi_b + 2 * 256, 3 * 256, P3, 256, (size_t)NN * DD,
        PART + 2048, NN, 256, 256);
    reduce6<<<6, 256, 0, stream>>>(PART, SC);

    for (int m = 0; m < 3; ++m) {
        const float* Pm = P3 + (size_t)m * NN * DD;
        colstats2<<<dim3(256, 2), 256, 0, stream>>>(Pm, Ef[m], MV2, NN);
        bn_fuse2<<<dim3(NN, 2), 256, 0, stream>>>(Pm, Ef[m], MV2, bn_g, bn_b, XB2, SQ2);
        gemm_dist2<<<dim3(16, 16, 2), 256, 0, stream>>>(XB2, SQ2, Gx, PART);
        reduce2<<<2, 256, 0, stream>>>(PART, SC);
        if (m == 0)
            gk_sim_fused<true><<<4096, 256, 0, stream>>>(
                (const float4*)Gx, (const float4*)(Gx + (size_t)NN * NN), SC, MK,
                simi_eps + m, (float4*)S);
        else
            gk_sim_fused<false><<<4096, 256, 0, stream>>>(
                (const float4*)Gx, (const float4*)(Gx + (size_t)NN * NN), SC,
                MK + m * NN, simi_eps + m, (float4*)S);
    }

    // ---- Stage B: aggregation + GCN (modal-stacked N=768, split-K Z=4) ----
    agg_cvt<<<4096, 256, 0, stream>>>((const float4*)S, MK, MK + NN, MK + 2 * NN,
                                      dissim, (ushort4*)Sb);
    // layer 1: TBt3[z] = (E_z @ W_z0)^T
    gemm_batch<2, false, false, false><<<dim3(2, 16, 3), 256, 0, stream>>>(
        (const ushort*)Eb3, 256, (size_t)NN * DD, (const ushort*)gcn_wt,
        (size_t)2 * 65536, nullptr, 0, TBt3, 256, (size_t)NN * DD,
        nullptr, NN, 256, 256);
    GEMMZ(Sb, TBt3, SLICE, NN, 768, NN, 4);
    slice_fin<4, true><<<1536, 256, 0, stream>>>(SLICE, Bcat, HB3, 768,
                                                 (size_t)NN * 768);
    // layer 2: TBt3[z] = (H_z @ W_z1)^T   (A = HB3 col-slice, lda=768)
    gemm_batch<2, false, false, false><<<dim3(2, 16, 3), 256, 0, stream>>>(
        (const ushort*)HB3, 768, (size_t)256, (const ushort*)(gcn_wt + 65536),
        (size_t)2 * 65536, nullptr, 0, TBt3, 256, (size_t)NN * DD,
        nullptr, NN, 256, 256);
    GEMMZ(Sb, TBt3, SLICE, NN, 768, NN, 4);
    slice_fin<4, true><<<1536, 256, 0, stream>>>(SLICE, Bcat + 768, HB2_3, 768,
                                                 (size_t)NN * 768);
    float* IMP[3] = {I0, I1, I2};
    for (int m = 0; m < 3; ++m)
        impute_k<<<NN, 256, 0, stream>>>(Ef[m], HB2_3 + m * 256, 768,
                                         adapt_w + m * 256, adapt_b + m,
                                         MK + m * NN, IMP[m]);

    // ---- Stage C: 34-token transformer ----
    build_z2<<<NN * LTOK * 64 / 256, 256, 0, stream>>>(
        (const float4*)emb0, (const float4*)I0, (const float4*)I1, (const float4*)I2,
        (const float4*)PET, (const float4*)type_emb, (ushort4*)Zb);
    const int NCHUNK = NN / ACH;  // 4
    for (int li = 0; li < 2; ++li) {
        for (int c = 0; c < NCHUNK; ++c) {
            __hip_bfloat16* Zc = Zb + (size_t)c * ACROWS * DD;
            GEMM(1, true, false, Zc, attn_wt + (size_t)(li * 4) * 65536,
                 attn_b + li * 4 * 256, QKVb, ACROWS, 768, 256);
            if (li == 0)
                attn_fused<64><<<dim3(ACH, 4), 256, 0, stream>>>(QKVb, TOK, Ob, c * ACH);
            else
                attn_fused<256><<<dim3(ACH, 1), 256, 0, stream>>>(QKVb, TOK, Ob, c * ACH);
            GEMM(3, true, false, Ob, attn_wt + (size_t)(li * 4 + 3) * 65536,
                 attn_b + (li * 4 + 3) * 256, Zc, ACROWS, 256, 256);
        }
        ln_rows<false><<<NN * LTOK / 4, 256, 0, stream>>>(Zb, ln_g + (li * 2 + 0) * 256,
                                                          ln_b + (li * 2 + 0) * 256);
        for (int c = 0; c < NCHUNK; ++c) {
            __hip_bfloat16* Zc = Zb + (size_t)c * ACROWS * DD;
            GEMM(1, true, true, Zc, w1t + (size_t)li * 262144, ffn_b1 + li * 1024,
                 Hfb, ACROWS, 1024, 256);
            GEMM(3, true, false, Hfb, w2t + (size_t)li * 262144, ffn_b2 + li * 256,
                 Zc, ACROWS, 256, 1024);
        }
        ln_rows<true><<<NN * LTOK / 4, 256, 0, stream>>>(Zb, ln_g + (li * 2 + 1) * 256,
                                                         ln_b + (li * 2 + 1) * 256);
    }

    // ---- head (split-K Z=4, SLICE aliases UN which is now free) ----
    GEMMZ(Zb, ow1t, SLICE, NN, 512, LTOK * DD, 4);
    slice_fin<4, true><<<1024, 256, 0, stream>>>(SLICE, out_b1, Y1b, 512,
                                                 (size_t)NN * 512);
    head2<<<NN, 256, 0, stream>>>(Y1b, out_w2, out_b2, out);
    lstab_k<<<1, 64, 0, stream>>>(SC, out + NN);
}

// Round 6
// 1293.131 us; speedup vs baseline: 5.3265x; 1.0990x over previous
//
#include <hip/hip_runtime.h>
#include <hip/hip_bf16.h>

// ---------------------------------------------------------------------------
// M3Care forward — bf16 MFMA GEMMs (global_load_lds staging + XCD swizzle +
// split-K + z-batched small GEMMs), fused dist+gk+sim epilogue, PE table,
// conflict-free bf16 attention. N=2048, D=256, T=32, NE=34, heads=(4,1).
// ---------------------------------------------------------------------------

#define NN 2048
#define DD 256
#define LTOK 34

typedef __attribute__((ext_vector_type(8))) short bf16x8;
typedef __attribute__((ext_vector_type(4))) float f32x4;

__device__ __forceinline__ float bf2f(__hip_bfloat16 x) { return __bfloat162float(x); }
__device__ __forceinline__ __hip_bfloat16 f2bf(float x) { return __float2bfloat16(x); }
__device__ __forceinline__ float us2f(ushort u) {
    unsigned x = (unsigned)u << 16;
    float f;
    __builtin_memcpy(&f, &x, 4);
    return f;
}

// ---------------- block reduce (blockDim.x == 256) ----------------
__device__ __forceinline__ float block_reduce_sum256(float v, float* red) {
    for (int o = 32; o > 0; o >>= 1) v += __shfl_down(v, o, 64);
    int tid = threadIdx.x;
    if ((tid & 63) == 0) red[tid >> 6] = v;
    __syncthreads();
    float s = red[0] + red[1] + red[2] + red[3];
    __syncthreads();
    return s;
}

// XCD-chunked bijective remap (T1, m204 variant).
__device__ __forceinline__ int xcd_remap(int lin, int nwg) {
    int q = nwg >> 3, r = nwg & 7;
    int xcd = lin & 7, pos = lin >> 3;
    return (xcd < r ? xcd * (q + 1) : r * (q + 1) + (xcd - r) * q) + pos;
}

// Stage one 128x64 bf16 tile via global_load_lds (16B/lane), linear LDS dest,
// inverse-XOR-swizzled per-lane GLOBAL source (rule #21).
__device__ __forceinline__ void stage_tile(const ushort* __restrict__ src,
                                           ushort* lds, int grow0, size_t ldk,
                                           int k0, int wv, int l) {
#pragma unroll
    for (int c = 0; c < 4; ++c) {
        int rowbase = wv * 32 + c * 8;
        int row = rowbase + (l >> 3);
        int sx = ((l & 7) ^ (row & 7)) * 8;
        __builtin_amdgcn_global_load_lds(
            (const __attribute__((address_space(1))) void*)(src + (size_t)(grow0 + row) * ldk + k0 + sx),
            (__attribute__((address_space(3))) void*)(lds + rowbase * 64), 16, 0, 0);
    }
}

// MFMA inner step over the staged 128x64 tiles (one kk half)
#define MFMA_STEP(ACC)                                                          \
    {                                                                           \
        bf16x8 av[4], bv[4];                                                    \
        _Pragma("unroll") for (int f = 0; f < 4; ++f) {                         \
            int ra = wr * 64 + f * 16 + lr;                                     \
            av[f] = *(const bf16x8*)(As + ra * 64 + (((kk * 4 + l16) ^ (ra & 7)) * 8)); \
            int rb = wc * 64 + f * 16 + lr;                                     \
            bv[f] = *(const bf16x8*)(Bs + rb * 64 + (((kk * 4 + l16) ^ (rb & 7)) * 8)); \
        }                                                                       \
        _Pragma("unroll") for (int mf = 0; mf < 4; ++mf)                        \
            _Pragma("unroll") for (int nf = 0; nf < 4; ++nf)                    \
                ACC[mf][nf] = __builtin_amdgcn_mfma_f32_16x16x32_bf16(          \
                    av[mf], bv[nf], ACC[mf][nf], 0, 0, 0);                      \
    }

// ---------------------------------------------------------------------------
// bf16 MFMA GEMM (big/split-K): C[M,N] = A[M,K] @ Bt[N,K]^T (+bias)
// OUTM: 0 = f32 out (slice z*M*N), 1 = bf16 out, 3 = bf16 in-place add.
// ---------------------------------------------------------------------------
template <int OUTM, bool BIAS, bool RELU>
__global__ __launch_bounds__(256) void gemm_mfma(
    const ushort* __restrict__ A, const ushort* __restrict__ Bt,
    const float* __restrict__ bias, void* __restrict__ Cout,
    int M, int N, int K)
{
    __shared__ __align__(16) ushort As[128 * 64];
    __shared__ __align__(16) ushort Bs[128 * 64];
    const int gx = gridDim.x;
    int lin = xcd_remap(blockIdx.y * gx + blockIdx.x, gx * gridDim.y);
    const int bm = (lin / gx) * 128, bn = (lin % gx) * 128;
    const int tid = threadIdx.x;
    const int l = tid & 63, wv = tid >> 6;
    const int wr = wv >> 1, wc = wv & 1;
    const int l16 = l >> 4, lr = l & 15;
    const int kpz = K / gridDim.z;
    const int kbeg = blockIdx.z * kpz, kend = kbeg + kpz;
    f32x4 zero = {0.f, 0.f, 0.f, 0.f};
    f32x4 acc[4][4];
#pragma unroll
    for (int i = 0; i < 4; ++i)
#pragma unroll
        for (int j = 0; j < 4; ++j) acc[i][j] = zero;

    for (int k0 = kbeg; k0 < kend; k0 += 64) {
        stage_tile(A, As, bm, K, k0, wv, l);
        stage_tile(Bt, Bs, bn, K, k0, wv, l);
        __syncthreads();
#pragma unroll
        for (int kk = 0; kk < 2; ++kk) MFMA_STEP(acc)
        __syncthreads();
    }
    float* Cf = (float*)Cout + (size_t)blockIdx.z * M * N;
#pragma unroll
    for (int mf = 0; mf < 4; ++mf) {
#pragma unroll
        for (int nf = 0; nf < 4; ++nf) {
            int col = bn + wc * 64 + nf * 16 + lr;
            float bb = BIAS ? bias[col] : 0.f;
#pragma unroll
            for (int r = 0; r < 4; ++r) {
                int row = bm + wr * 64 + mf * 16 + l16 * 4 + r;
                float v = acc[mf][nf][r] + bb;
                if (OUTM == 3)
                    v += bf2f(((const __hip_bfloat16*)Cout)[(size_t)row * N + col]);
                if (RELU) v = fmaxf(v, 0.f);
                if (OUTM == 0)
                    Cf[(size_t)row * N + col] = v;
                else
                    ((__hip_bfloat16*)Cout)[(size_t)row * N + col] = f2bf(v);
            }
        }
    }
}

// ---------------------------------------------------------------------------
// z-batched small GEMM (K<=256): see round-4 comments.
// ---------------------------------------------------------------------------
template <int OUTM, bool RELU, bool BIAS, bool PSUM>
__global__ __launch_bounds__(256) void gemm_batch(
    const ushort* __restrict__ A, int lda, size_t aoffZ,
    const ushort* __restrict__ Bt, size_t boffZ,
    const float* __restrict__ bias, int biasoffZ,
    void* __restrict__ Cout, int ldc, size_t coffZ,
    float* __restrict__ psum, int M, int N, int K)
{
    __shared__ __align__(16) ushort As[128 * 64];
    __shared__ __align__(16) ushort Bs[128 * 64];
    __shared__ float red[8];
    const int gx = gridDim.x;
    const int lin0 = blockIdx.y * gx + blockIdx.x;
    int lin = xcd_remap(lin0, gx * gridDim.y);
    const int bm = (lin / gx) * 128, bn = (lin % gx) * 128;
    const int z = blockIdx.z;
    A += (size_t)z * aoffZ;
    Bt += (size_t)z * boffZ;
    if (BIAS) bias += (size_t)z * biasoffZ;
    const int tid = threadIdx.x;
    const int l = tid & 63, wv = tid >> 6;
    const int wr = wv >> 1, wc = wv & 1;
    const int l16 = l >> 4, lr = l & 15;
    f32x4 zero = {0.f, 0.f, 0.f, 0.f};
    f32x4 acc[4][4];
#pragma unroll
    for (int i = 0; i < 4; ++i)
#pragma unroll
        for (int j = 0; j < 4; ++j) acc[i][j] = zero;

    for (int k0 = 0; k0 < K; k0 += 64) {
        stage_tile(A, As, bm, lda, k0, wv, l);
        stage_tile(Bt, Bs, bn, K, k0, wv, l);
        __syncthreads();
#pragma unroll
        for (int kk = 0; kk < 2; ++kk) MFMA_STEP(acc)
        __syncthreads();
    }
    float lsq = 0.f;
#pragma unroll
    for (int mf = 0; mf < 4; ++mf) {
#pragma unroll
        for (int nf = 0; nf < 4; ++nf) {
            int col = bn + wc * 64 + nf * 16 + lr;
            float bb = BIAS ? bias[col] : 0.f;
#pragma unroll
            for (int r = 0; r < 4; ++r) {
                int row = bm + wr * 64 + mf * 16 + l16 * 4 + r;
                float v = acc[mf][nf][r] + bb;
                if (RELU) v = fmaxf(v, 0.f);
                if (PSUM) lsq += v * v;
                if (OUTM == 0)
                    ((float*)Cout + (size_t)z * coffZ)[(size_t)row * ldc + col] = v;
                else if (OUTM == 2)
                    ((__hip_bfloat16*)Cout + (size_t)z * coffZ)[(size_t)col * M + row] = f2bf(v);
                else
                    ((__hip_bfloat16*)Cout + (size_t)z * coffZ)[(size_t)row * ldc + col] = f2bf(v);
            }
        }
    }
    if (PSUM) {
        float bs = block_reduce_sum256(lsq, red);
        if (tid == 0) psum[z * gx * gridDim.y + lin0] = bs;
    }
}

// ---------------------------------------------------------------------------
// Fused dual-distance + multi-bandwidth GK + sim accumulation.
// XB holds two BN'd bf16 [2048,256] matrices (z=0: relu(P)-BN, z=1: E-BN).
// Computes d1,d2 per (i,j) via two MFMA phases, then
// S (+)= ((1-eps)*gk3(d1,bw0) + eps) * gk3(d2,bw1) * mask.  No G materialized.
// ---------------------------------------------------------------------------
template <bool FIRST>
__global__ __launch_bounds__(256) void gemm_dist_gk(
    const ushort* __restrict__ XB, const float* __restrict__ SQ,
    const float* __restrict__ bws, const int* __restrict__ mk,
    const float* __restrict__ epsp, float* __restrict__ S)
{
    __shared__ __align__(16) ushort As[128 * 64];
    __shared__ __align__(16) ushort Bs[128 * 64];
    const int gx = gridDim.x;
    int lin = xcd_remap(blockIdx.y * gx + blockIdx.x, gx * gridDim.y);
    const int bm = (lin / gx) * 128, bn = (lin % gx) * 128;
    const int tid = threadIdx.x;
    const int l = tid & 63, wv = tid >> 6;
    const int wr = wv >> 1, wc = wv & 1;
    const int l16 = l >> 4, lr = l & 15;
    f32x4 zero = {0.f, 0.f, 0.f, 0.f};
    f32x4 acc1[4][4], acc2[4][4];
#pragma unroll
    for (int i = 0; i < 4; ++i)
#pragma unroll
        for (int j = 0; j < 4; ++j) { acc1[i][j] = zero; acc2[i][j] = zero; }

    // phase 1: z=0 (X0 . X0^T block)
    for (int k0 = 0; k0 < 256; k0 += 64) {
        stage_tile(XB, As, bm, 256, k0, wv, l);
        stage_tile(XB, Bs, bn, 256, k0, wv, l);
        __syncthreads();
#pragma unroll
        for (int kk = 0; kk < 2; ++kk) MFMA_STEP(acc1)
        __syncthreads();
    }
    // phase 2: z=1
    const ushort* X1 = XB + (size_t)NN * DD;
    for (int k0 = 0; k0 < 256; k0 += 64) {
        stage_tile(X1, As, bm, 256, k0, wv, l);
        stage_tile(X1, Bs, bn, 256, k0, wv, l);
        __syncthreads();
#pragma unroll
        for (int kk = 0; kk < 2; ++kk) MFMA_STEP(acc2)
        __syncthreads();
    }
    float eps = 1.f / (1.f + __expf(-epsp[0]));
    const float cnn = 1.f / ((float)NN * NN - (float)NN);
    float ia = 2.f / (bws[0] * cnn);
    float ib = 2.f / (bws[1] * cnn);
#pragma unroll
    for (int mf = 0; mf < 4; ++mf) {
#pragma unroll
        for (int nf = 0; nf < 4; ++nf) {
            int col = bn + wc * 64 + nf * 16 + lr;
            int mcol = mk[col];
            float sqc0 = SQ[col], sqc1 = SQ[NN + col];
#pragma unroll
            for (int r = 0; r < 4; ++r) {
                int row = bm + wr * 64 + mf * 16 + l16 * 4 + r;
                float d1 = fmaxf(SQ[row] + sqc0 - 2.f * acc1[mf][nf][r], 0.f);
                float d2 = fmaxf(SQ[NN + row] + sqc1 - 2.f * acc2[mf][nf][r], 0.f);
                float w = __expf(-d1 * ia) + __expf(-d1 * (0.5f * ia)) +
                          __expf(-d1 * (0.25f * ia));
                float g = __expf(-d2 * ib) + __expf(-d2 * (0.5f * ib)) +
                          __expf(-d2 * (0.25f * ib));
                float val = ((1.f - eps) * w + eps) * g;
                val = (mk[row] && mcol) ? val : 0.f;
                size_t idx = (size_t)row * NN + col;
                S[idx] = FIRST ? val : S[idx] + val;
            }
        }
    }
}

// ---------------- bw closed form: sum_ij l2 = 2N*S1 - 2*|colsum|^2 ---------
__global__ __launch_bounds__(256) void bw_calc(const ushort* __restrict__ XB,
                                               const float* __restrict__ SQ,
                                               float* __restrict__ SC) {
    __shared__ float red[8];
    int z = blockIdx.x, tid = threadIdx.x;
    const ushort* X = XB + (size_t)z * NN * DD;
    float v = 0.f;
    for (int r = 0; r < NN; r += 8) {
#pragma unroll
        for (int u = 0; u < 8; ++u) v += us2f(X[(size_t)(r + u) * DD + tid]);
    }
    float s1p = 0.f;
    for (int r = tid; r < NN; r += 256) s1p += SQ[z * NN + r];
    float vsq = block_reduce_sum256(v * v, red);
    float s1 = block_reduce_sum256(s1p, red);
    if (tid == 0) SC[z] = 2.f * (float)NN * s1 - 2.f * vsq;
}

// ---------------- split-K finalize ----------------
template <int Z, bool RELU>
__global__ __launch_bounds__(256) void slice_fin(const float* __restrict__ SL,
                                                 const float* __restrict__ bias,
                                                 __hip_bfloat16* __restrict__ out,
                                                 int N, size_t MN) {
    size_t v = (size_t)blockIdx.x * 256 + threadIdx.x;
    const float4* S4 = (const float4*)SL;
    size_t MN4 = MN >> 2;
    float4 s = S4[v];
#pragma unroll
    for (int z = 1; z < Z; ++z) {
        float4 t = S4[(size_t)z * MN4 + v];
        s.x += t.x; s.y += t.y; s.z += t.z; s.w += t.w;
    }
    float4 bb = ((const float4*)bias)[v % (size_t)(N >> 2)];
    s.x += bb.x; s.y += bb.y; s.z += bb.z; s.w += bb.w;
    if (RELU) {
        s.x = fmaxf(s.x, 0.f); s.y = fmaxf(s.y, 0.f);
        s.z = fmaxf(s.z, 0.f); s.w = fmaxf(s.w, 0.f);
    }
    union { __hip_bfloat16 h[4]; ushort4 u; } pk;
    pk.h[0] = f2bf(s.x); pk.h[1] = f2bf(s.y);
    pk.h[2] = f2bf(s.z); pk.h[3] = f2bf(s.w);
    ((ushort4*)out)[v] = pk.u;
}

// ---------------- conversions ----------------
__global__ void cvt_flat(const float* __restrict__ in, __hip_bfloat16* __restrict__ out,
                         int n4) {
    int i = blockIdx.x * 256 + threadIdx.x;
    if (i < n4) {
        float4 v = ((const float4*)in)[i];
        union { __hip_bfloat16 h[4]; ushort4 u; } pk;
        pk.h[0] = f2bf(v.x); pk.h[1] = f2bf(v.y);
        pk.h[2] = f2bf(v.z); pk.h[3] = f2bf(v.w);
        ((ushort4*)out)[i] = pk.u;
    }
}

__global__ __launch_bounds__(256) void cvt_trans(const float* __restrict__ in,
                                                 __hip_bfloat16* __restrict__ out,
                                                 int R, int C) {
    __shared__ float t[32][33];
    int bc = blockIdx.x * 32, br = blockIdx.y * 32;
    int tx = threadIdx.x & 31, ty = threadIdx.x >> 5;
#pragma unroll
    for (int i = 0; i < 32; i += 8)
        t[ty + i][tx] = in[(size_t)(br + ty + i) * C + bc + tx];
    __syncthreads();
#pragma unroll
    for (int i = 0; i < 32; i += 8)
        out[(size_t)(bc + ty + i) * R + br + tx] = f2bf(t[tx][ty + i]);
}

// ---------------- aggregation + threshold gate + bf16 convert --------------
__global__ __launch_bounds__(256) void agg_cvt(
    const float4* __restrict__ S, const int* __restrict__ mk0,
    const int* __restrict__ mk1, const int* __restrict__ mk2,
    const float* __restrict__ dissim, ushort4* __restrict__ Sb) {
    size_t v = (size_t)blockIdx.x * 256 + threadIdx.x;
    int i = (int)(v >> 9);
    int j0 = (int)((v & 511) << 2);
    float thr = 1.f / (1.f + __expf(-dissim[0]));
    float4 s = S[v];
    int m0i = mk0[i], m1i = mk1[i], m2i = mk2[i];
    union { __hip_bfloat16 h[4]; ushort4 u; } pk;
#define AGGC(X, J)                                                                \
    {                                                                             \
        int j = j0 + J;                                                           \
        int cnt = ((m0i && mk0[j]) ? 1 : 0) + ((m1i && mk1[j]) ? 1 : 0) +         \
                  ((m2i && mk2[j]) ? 1 : 0);                                      \
        float a = cnt ? s.X / (float)cnt : 0.f;                                   \
        pk.h[J] = f2bf((a > thr) ? a : 0.f);                                      \
    }
    AGGC(x, 0) AGGC(y, 1) AGGC(z, 2) AGGC(w, 3)
#undef AGGC
    Sb[v] = pk.u;
}

// ---------------- BatchNorm column stats, z-batched over {P(relu), E} ------
__global__ __launch_bounds__(256) void colstats2(const float* __restrict__ X0,
                                                 const float* __restrict__ X1,
                                                 float* __restrict__ mv, int nrows) {
    __shared__ float red[8];
    int c = blockIdx.x, z = blockIdx.y, tid = threadIdx.x;
    const float* X = z ? X1 : X0;
    float s = 0.f, sq = 0.f;
    for (int r = tid; r < nrows; r += 256) {
        float v = X[(size_t)r * DD + c];
        if (z == 0) v = fmaxf(v, 0.f);
        s += v; sq += v * v;
    }
    float ts = block_reduce_sum256(s, red);
    float tq = block_reduce_sum256(sq, red);
    if (tid == 0) {
        float m = ts / (float)nrows;
        mv[z * 512 + c] = m;
        mv[z * 512 + 256 + c] = tq / (float)nrows - m * m;
    }
}

// ---------------- fused BN-apply + rowsq, z-batched (block = row) ----------
__global__ __launch_bounds__(256) void bn_fuse2(const float* __restrict__ X0,
                                                const float* __restrict__ X1,
                                                const float* __restrict__ mv,
                                                const float* __restrict__ g,
                                                const float* __restrict__ b,
                                                ushort* __restrict__ XB,
                                                float* __restrict__ SQ) {
    __shared__ float red[8];
    int r = blockIdx.x, z = blockIdx.y, c = threadIdx.x;
    float v = (z ? X1 : X0)[(size_t)r * DD + c];
    if (z == 0) v = fmaxf(v, 0.f);
    float y = (v - mv[z * 512 + c]) * rsqrtf(mv[z * 512 + 256 + c] + 1e-5f) * g[c] + b[c];
    __hip_bfloat16 yb = f2bf(y);
    XB[(size_t)z * NN * DD + (size_t)r * DD + c] = *(ushort*)&yb;
    float yr = bf2f(yb);
    float s = block_reduce_sum256(yr * yr, red);
    if (c == 0) SQ[z * NN + r] = s;
}

// ---------------- sum-of-squares partial (deterministic) ----------------
__global__ __launch_bounds__(256) void sumsq_partial(const float* __restrict__ X, int n,
                                                     float* __restrict__ part) {
    __shared__ float red[8];
    int tid = threadIdx.x;
    float s = 0.f;
    for (size_t idx = (size_t)blockIdx.x * 256 + tid; idx < (size_t)n;
         idx += (size_t)gridDim.x * 256) {
        float v = X[idx];
        s += v * v;
    }
    float bs = block_reduce_sum256(s, red);
    if (tid == 0) part[blockIdx.x] = bs;
}

// reduce6: blocks 0..2 -> |E|^2 (PART+512+b*512, n=512) -> SC[9+b];
//          blocks 3..5 -> |P|^2 (PART+2048+(b-3)*32, n=32) -> SC[6+(b-3)]
__global__ __launch_bounds__(256) void reduce6(const float* __restrict__ part,
                                               float* __restrict__ SC) {
    __shared__ float red[8];
    int b = blockIdx.x, tid = threadIdx.x;
    const float* src; int n, dst;
    if (b < 3) { src = part + 512 + b * 512; n = 512; dst = 9 + b; }
    else { src = part + 2048 + (b - 3) * 32; n = 32; dst = 6 + (b - 3); }
    float s = 0.f;
    for (int i = tid; i < n; i += 256) s += src[i];
    float bs = block_reduce_sum256(s, red);
    if (tid == 0) SC[dst] = bs;
}

// ---------------- adapt-gate imputation (one block per sample) -------------
__global__ __launch_bounds__(256) void impute_k(
    const float* __restrict__ E, const __hip_bfloat16* __restrict__ H, int ldh,
    const float* __restrict__ aw, const float* __restrict__ ab,
    const int* __restrict__ mk, float* __restrict__ OUT) {
    __shared__ float red[8];
    int i = blockIdx.x, tid = threadIdx.x;
    float e = E[(size_t)i * DD + tid], h = bf2f(H[(size_t)i * ldh + tid]), w = aw[tid];
    float se = block_reduce_sum256(e * w, red);
    float sh = block_reduce_sum256(h * w, red);
    float s = 1.f / (1.f + __expf(-(se + ab[0])));
    float o = 1.f / (1.f + __expf(-(sh + ab[0])));
    s = s / (s + o);
    float imp = s * e + (1.f - s) * h;
    float m = mk[i] ? 1.f : 0.f;
    OUT[(size_t)i * DD + tid] = imp * m + (1.f - m) * h;
}

// ---------------- masks ----------------
__global__ void detect_mode(const void* __restrict__ m1, int* __restrict__ modep) {
    if (threadIdx.x == 0 && blockIdx.x == 0) {
        int vi = ((const int*)m1)[0];
        float vf = ((const float*)m1)[0];
        modep[0] = (vi == 1) ? 0 : ((vf == 1.0f) ? 2 : 1);
    }
}

__device__ __forceinline__ int rd_mask(const void* p, int idx, int mode) {
    if (mode == 0) return ((const int*)p)[idx] != 0;
    if (mode == 1) return ((const unsigned char*)p)[idx] != 0;
    return ((const float*)p)[idx] != 0.f;
}

__global__ void build_masks(const void* __restrict__ m0, const void* __restrict__ m1,
                            const void* __restrict__ m2, const int* __restrict__ modep,
                            int* __restrict__ MK, int* __restrict__ TOK) {
    int mode = modep[0];
    int idx = blockIdx.x * 256 + threadIdx.x;
    if (idx < NN) {
        MK[idx] = rd_mask(m0, idx * 32, mode);
        MK[NN + idx] = rd_mask(m1, idx, mode);
        MK[2 * NN + idx] = rd_mask(m2, idx, mode);
    }
    if (idx < NN * LTOK) {
        int i = idx / LTOK, t = idx - i * LTOK;
        TOK[idx] = (t < 32) ? rd_mask(m0, i * 32 + t, mode)
                            : ((t == 32) ? rd_mask(m1, i, mode) : rd_mask(m2, i, mode));
    }
}

// ---------------- gather emb0[:,0,:] ----------------
__global__ void gather_e0(const float* __restrict__ emb0, float* __restrict__ E0,
                          __hip_bfloat16* __restrict__ E0b) {
    int i = blockIdx.x, c = threadIdx.x;
    float v = emb0[(size_t)i * 32 * DD + c];
    E0[(size_t)i * DD + c] = v;
    E0b[(size_t)i * DD + c] = f2bf(v);
}

// ---------------- PE + type_emb[0] table: PET[t][c] ----------------
__global__ void pe_table(const float* __restrict__ type_emb, float* __restrict__ PET) {
    int t = blockIdx.x, c = threadIdx.x;
    float div = __expf((float)((c >> 1) << 1) * (-9.210340371976184f / 256.f));
    float ang = (float)t * div;
    float pe = (c & 1) ? __cosf(ang) : __sinf(ang);
    PET[t * 256 + c] = type_emb[c] + pe;
}

// ---------------- build token sequence (vectorized, table-driven) ----------
__global__ void build_z2(const float4* __restrict__ emb0, const float4* __restrict__ i0,
                         const float4* __restrict__ i1, const float4* __restrict__ i2,
                         const float4* __restrict__ PET,
                         const float4* __restrict__ type_emb,
                         ushort4* __restrict__ Z) {
    int idx = blockIdx.x * 256 + threadIdx.x;   // float4 units
    int c4 = idx & 63;
    int t = (idx >> 6) % LTOK;
    int i = idx / (LTOK * 64);
    float4 v, a;
    if (t < 32) {
        v = (t == 0) ? i0[(size_t)i * 64 + c4]
                     : emb0[((size_t)i * 32 + t) * 64 + c4];
        a = PET[t * 64 + c4];
    } else if (t == 32) {
        v = i1[(size_t)i * 64 + c4];
        a = type_emb[64 + c4];
    } else {
        v = i2[(size_t)i * 64 + c4];
        a = type_emb[128 + c4];
    }
    union { __hip_bfloat16 h[4]; ushort4 u; } pk;
    pk.h[0] = f2bf(v.x + a.x); pk.h[1] = f2bf(v.y + a.y);
    pk.h[2] = f2bf(v.z + a.z); pk.h[3] = f2bf(v.w + a.w);
    Z[idx] = pk.u;
}

// ---------------- fused attention (bf16 LDS, KT pad-38) ----------
template <int DH>
__global__ __launch_bounds__(256) void attn_fused(
    const __hip_bfloat16* __restrict__ QKV, const int* __restrict__ tok,
    __hip_bfloat16* __restrict__ O, int sample0) {
    const int L = LTOK;
    __shared__ ushort Qs[L * DH];
    __shared__ ushort KT[DH * 38];
    __shared__ ushort Vs[L * DH];
    __shared__ float Sc[L][35];
    int b = blockIdx.x, hh = blockIdx.y;
    int tid = threadIdx.x;
    const float scale = rsqrtf((float)DH);
    for (int idx = tid; idx < L * DH; idx += 256) {
        int t = idx / DH, d = idx - t * DH;
        size_t g = (size_t)(b * L + t) * 768 + hh * DH + d;
        const ushort* q = (const ushort*)QKV;
        Qs[idx] = q[g];
        KT[d * 38 + t] = q[g + 256];
        Vs[idx] = q[g + 512];
    }
    __syncthreads();
    const int* tk = tok + (size_t)(sample0 + b) * L;
    for (int idx = tid; idx < L * L; idx += 256) {
        int i = idx / L, j = idx - i * L;
        float acc = 0.f;
#pragma unroll 16
        for (int d = 0; d < DH; ++d)
            acc = fmaf(us2f(Qs[i * DH + d]), us2f(KT[d * 38 + j]), acc);
        Sc[i][j] = (tk[i] && tk[j]) ? acc * scale : -1e9f;
    }
    __syncthreads();
    if (tid < L) {
        float mx = -1e30f;
        for (int j = 0; j < L; ++j) mx = fmaxf(mx, Sc[tid][j]);
        float s = 0.f;
        for (int j = 0; j < L; ++j) {
            float e = __expf(Sc[tid][j] - mx);
            Sc[tid][j] = e; s += e;
        }
        float inv = 1.f / s;
        for (int j = 0; j < L; ++j) Sc[tid][j] *= inv;
    }
    __syncthreads();
    for (int idx = tid; idx < L * DH; idx += 256) {
        int i = idx / DH, d = idx - i * DH;
        float acc = 0.f;
#pragma unroll
        for (int j = 0; j < L; ++j) acc = fmaf(Sc[i][j], us2f(Vs[j * DH + d]), acc);
        O[(size_t)(b * L + i) * DD + hh * DH + d] = f2bf(acc);
    }
}

// ---------------- wave-per-row LayerNorm ----------------
template <bool RELU>
__global__ __launch_bounds__(256) void ln_rows(__hip_bfloat16* __restrict__ Z,
                                               const float* __restrict__ g,
                                               const float* __restrict__ b) {
    int row = (blockIdx.x << 2) + (threadIdx.x >> 6);
    int l = threadIdx.x & 63;
    ushort4 u = ((ushort4*)(Z + (size_t)row * DD))[l];
    float x0 = us2f(u.x), x1 = us2f(u.y), x2 = us2f(u.z), x3 = us2f(u.w);
    float s = x0 + x1 + x2 + x3;
    for (int o = 1; o < 64; o <<= 1) s += __shfl_xor(s, o, 64);
    float mean = s * (1.f / 256.f);
    float d0 = x0 - mean, d1 = x1 - mean, d2 = x2 - mean, d3 = x3 - mean;
    float q = d0 * d0 + d1 * d1 + d2 * d2 + d3 * d3;
    for (int o = 1; o < 64; o <<= 1) q += __shfl_xor(q, o, 64);
    float rst = rsqrtf(q * (1.f / 256.f) + 1e-5f);
    float4 gg = ((const float4*)g)[l], bb = ((const float4*)b)[l];
    float y0 = d0 * rst * gg.x + bb.x, y1 = d1 * rst * gg.y + bb.y;
    float y2 = d2 * rst * gg.z + bb.z, y3 = d3 * rst * gg.w + bb.w;
    if (RELU) {
        y0 = fmaxf(y0, 0.f); y1 = fmaxf(y1, 0.f);
        y2 = fmaxf(y2, 0.f); y3 = fmaxf(y3, 0.f);
    }
    union { __hip_bfloat16 h[4]; ushort4 v; } pk;
    pk.h[0] = f2bf(y0); pk.h[1] = f2bf(y1); pk.h[2] = f2bf(y2); pk.h[3] = f2bf(y3);
    ((ushort4*)(Z + (size_t)row * DD))[l] = pk.v;
}

// ---------------- final head ----------------
__global__ __launch_bounds__(256) void head2(const __hip_bfloat16* __restrict__ Y1,
                                             const float* __restrict__ w,
                                             const float* __restrict__ b,
                                             float* __restrict__ out) {
    __shared__ float red[8];
    int i = blockIdx.x, tid = threadIdx.x;
    float s = bf2f(Y1[(size_t)i * 512 + tid]) * w[tid] +
              bf2f(Y1[(size_t)i * 512 + 256 + tid]) * w[256 + tid];
    float bs = block_reduce_sum256(s, red);
    if (tid == 0) out[i] = bs + b[0];
}

__global__ void lstab_k(const float* __restrict__ SC, float* __restrict__ dst) {
    if (threadIdx.x == 0 && blockIdx.x == 0) {
        float s = 0.f;
        for (int m = 0; m < 3; ++m)
            s += fabsf(sqrtf(SC[6 + m]) - sqrtf(SC[9 + m]));
        dst[0] = s;
    }
}

// gcn bias concat
__global__ void gcn_bias_cat(const float* __restrict__ gcn_b, float* __restrict__ Bcat) {
    int m = blockIdx.x, l = blockIdx.y, c = threadIdx.x;
    Bcat[l * 768 + m * 256 + c] = gcn_b[(m * 2 + l) * 256 + c];
}

// ===========================================================================
#define GEMM(OUTM_, BIAS_, RELU_, A_, Bt_, BI_, C_, M_, N_, K_)                 \
    gemm_mfma<OUTM_, BIAS_, RELU_>                                              \
        <<<dim3((N_) / 128, (M_) / 128), 256, 0, stream>>>(                     \
            (const ushort*)(A_), (const ushort*)(Bt_), (BI_), (void*)(C_),      \
            (M_), (N_), (K_))
#define GEMMZ(A_, Bt_, C_, M_, N_, K_, Z_)                                      \
    gemm_mfma<0, false, false>                                                  \
        <<<dim3((N_) / 128, (M_) / 128, (Z_)), 256, 0, stream>>>(               \
            (const ushort*)(A_), (const ushort*)(Bt_), (const float*)nullptr,   \
            (void*)(C_), (M_), (N_), (K_))

extern "C" void kernel_launch(void* const* d_in, const int* in_sizes, int n_in,
                              void* d_out, int out_size, void* d_ws, size_t ws_size,
                              hipStream_t stream) {
    (void)in_sizes; (void)n_in; (void)out_size; (void)ws_size;
    const float* emb0 = (const float*)d_in[0];
    const float* emb1 = (const float*)d_in[1];
    const float* emb2 = (const float*)d_in[2];
    const void* msk0 = d_in[3];
    const void* msk1 = d_in[4];
    const void* msk2 = d_in[5];
    const float* simi_w = (const float*)d_in[6];
    const float* simi_b = (const float*)d_in[7];
    const float* bn_g = (const float*)d_in[8];
    const float* bn_b = (const float*)d_in[9];
    const float* simi_eps = (const float*)d_in[10];
    const float* dissim = (const float*)d_in[11];
    const float* gcn_w = (const float*)d_in[12];
    const float* gcn_b = (const float*)d_in[13];
    const float* adapt_w = (const float*)d_in[14];
    const float* adapt_b = (const float*)d_in[15];
    const float* type_emb = (const float*)d_in[16];
    const float* attn_w = (const float*)d_in[17];
    const float* attn_b = (const float*)d_in[18];
    const float* ffn_w1 = (const float*)d_in[19];
    const float* ffn_b1 = (const float*)d_in[20];
    const float* ffn_w2 = (const float*)d_in[21];
    const float* ffn_b2 = (const float*)d_in[22];
    const float* ln_g = (const float*)d_in[23];
    const float* ln_b = (const float*)d_in[24];
    const float* out_w1 = (const float*)d_in[25];
    const float* out_b1 = (const float*)d_in[26];
    const float* out_w2 = (const float*)d_in[27];
    const float* out_b2 = (const float*)d_in[28];
    float* out = (float*)d_out;

    // ---- workspace layout (~187 MB) ----
    char* wp = (char*)d_ws;
    auto alloc = [&](size_t bytes) -> char* {
        char* p = wp;
        wp += (bytes + 255) & ~(size_t)255;
        return p;
    };
    const int ACH = 1024, ACROWS = ACH * LTOK;  // 34816 rows/chunk, 2 chunks
    __hip_bfloat16* Zb = (__hip_bfloat16*)alloc((size_t)NN * LTOK * DD * 2);  // 35.7MB
    char* UN = alloc((size_t)ACROWS * 1024 * 2);   // 71.3MB union
    __hip_bfloat16* QKVb = (__hip_bfloat16*)UN;
    __hip_bfloat16* Ob = (__hip_bfloat16*)(UN + (size_t)ACROWS * 768 * 2);
    __hip_bfloat16* Hfb = (__hip_bfloat16*)UN;
    float* SLICE = (float*)UN;                     // stage-B Z=8 (50.3MB) & head Z=8 (33.5MB)
    float* S = (float*)alloc((size_t)NN * NN * 4);        // 16MB
    __hip_bfloat16* Sb = (__hip_bfloat16*)alloc((size_t)NN * NN * 2);  // 8MB
    float* P3 = (float*)alloc((size_t)3 * NN * DD * 4);   // 6MB
    float* E0 = (float*)alloc((size_t)NN * DD * 4);
    __hip_bfloat16* Eb3 = (__hip_bfloat16*)alloc((size_t)3 * NN * DD * 2);
    __hip_bfloat16* T1b3 = (__hip_bfloat16*)alloc((size_t)3 * NN * DD * 2);
    __hip_bfloat16* T2b3 = (__hip_bfloat16*)alloc((size_t)3 * NN * DD * 2);
    ushort* XB2 = (ushort*)alloc((size_t)2 * NN * DD * 2);
    __hip_bfloat16* TBt3 = (__hip_bfloat16*)alloc((size_t)3 * NN * DD * 2);
    __hip_bfloat16* HB3 = (__hip_bfloat16*)alloc((size_t)NN * 768 * 2);
    __hip_bfloat16* HB2_3 = (__hip_bfloat16*)alloc((size_t)NN * 768 * 2);
    float* I0 = (float*)alloc((size_t)NN * DD * 4);
    float* I1 = (float*)alloc((size_t)NN * DD * 4);
    float* I2 = (float*)alloc((size_t)NN * DD * 4);
    __hip_bfloat16* Y1b = (__hip_bfloat16*)alloc((size_t)NN * 512 * 2);
    __hip_bfloat16* simi_wt = (__hip_bfloat16*)alloc((size_t)9 * 65536 * 2);
    __hip_bfloat16* gcn_wt = (__hip_bfloat16*)alloc((size_t)6 * 65536 * 2);
    __hip_bfloat16* attn_wt = (__hip_bfloat16*)alloc((size_t)8 * 65536 * 2);
    __hip_bfloat16* w1t = (__hip_bfloat16*)alloc((size_t)2 * 262144 * 2);
    __hip_bfloat16* w2t = (__hip_bfloat16*)alloc((size_t)2 * 262144 * 2);
    __hip_bfloat16* ow1t = (__hip_bfloat16*)alloc((size_t)8704 * 512 * 2);
    float* PET = (float*)alloc(32 * 256 * 4);
    float* MV2 = (float*)alloc(1024 * 4);
    float* SQ2 = (float*)alloc(2 * NN * 4);
    float* PART = (float*)alloc(4096 * 4);  // [512:2048) E, [2048:2144) P
    float* SC = (float*)alloc(64 * 4);
    float* Bcat = (float*)alloc(1536 * 4);
    int* TOK = (int*)alloc((size_t)NN * LTOK * 4);
    int* MK = (int*)alloc((size_t)3 * NN * 4);

    // ---- weight transpose-convert ----
    auto TR = [&](const float* src, __hip_bfloat16* dst, int R, int C) {
        cvt_trans<<<dim3(C / 32, R / 32), 256, 0, stream>>>(src, dst, R, C);
    };
    for (int i = 0; i < 9; ++i) TR(simi_w + (size_t)i * 65536, simi_wt + (size_t)i * 65536, 256, 256);
    for (int i = 0; i < 6; ++i) TR(gcn_w + (size_t)i * 65536, gcn_wt + (size_t)i * 65536, 256, 256);
    for (int i = 0; i < 8; ++i) TR(attn_w + (size_t)i * 65536, attn_wt + (size_t)i * 65536, 256, 256);
    for (int i = 0; i < 2; ++i) TR(ffn_w1 + (size_t)i * 262144, w1t + (size_t)i * 262144, 256, 1024);
    for (int i = 0; i < 2; ++i) TR(ffn_w2 + (size_t)i * 262144, w2t + (size_t)i * 262144, 1024, 256);
    TR(out_w1, ow1t, 8704, 512);

    // ---- prep ----
    pe_table<<<32, 256, 0, stream>>>(type_emb, PET);
    gather_e0<<<NN, 256, 0, stream>>>(emb0, E0, Eb3);
    cvt_flat<<<512, 256, 0, stream>>>(emb1, Eb3 + (size_t)NN * DD, NN * DD / 4);
    cvt_flat<<<512, 256, 0, stream>>>(emb2, Eb3 + (size_t)2 * NN * DD, NN * DD / 4);
    detect_mode<<<1, 64, 0, stream>>>(msk1, (int*)SC + 16);
    build_masks<<<(NN * LTOK + 255) / 256, 256, 0, stream>>>(msk0, msk1, msk2,
                                                             (int*)SC + 16, MK, TOK);
    gcn_bias_cat<<<dim3(3, 2), 256, 0, stream>>>(gcn_b, Bcat);

    const float* Ef[3] = {E0, emb1, emb2};

    // ---- Stage A ----
    for (int m = 0; m < 3; ++m)
        sumsq_partial<<<512, 256, 0, stream>>>(Ef[m], NN * DD, PART + 512 + m * 512);
    gemm_batch<1, true, true, false><<<dim3(2, 16, 3), 256, 0, stream>>>(
        (const ushort*)Eb3, 256, (size_t)NN * DD, (const ushort*)simi_wt,
        (size_t)3 * 65536, simi_b, 3 * 256, T1b3, 256, (size_t)NN * DD,
        nullptr, NN, 256, 256);
    gemm_batch<1, true, true, false><<<dim3(2, 16, 3), 256, 0, stream>>>(
        (const ushort*)T1b3, 256, (size_t)NN * DD, (const ushort*)(simi_wt + 65536),
        (size_t)3 * 65536, simi_b + 256, 3 * 256, T2b3, 256, (size_t)NN * DD,
        nullptr, NN, 256, 256);
    gemm_batch<0, false, true, true><<<dim3(2, 16, 3), 256, 0, stream>>>(
        (const ushort*)T2b3, 256, (size_t)NN * DD, (const ushort*)(simi_wt + 2 * 65536),
        (size_t)3 * 65536, simi_b + 2 * 256, 3 * 256, P3, 256, (size_t)NN * DD,
        PART + 2048, NN, 256, 256);
    reduce6<<<6, 256, 0, stream>>>(PART, SC);

    for (int m = 0; m < 3; ++m) {
        const float* Pm = P3 + (size_t)m * NN * DD;
        colstats2<<<dim3(256, 2), 256, 0, stream>>>(Pm, Ef[m], MV2, NN);
        bn_fuse2<<<dim3(NN, 2), 256, 0, stream>>>(Pm, Ef[m], MV2, bn_g, bn_b, XB2, SQ2);
        bw_calc<<<2, 256, 0, stream>>>(XB2, SQ2, SC);
        if (m == 0)
            gemm_dist_gk<true><<<dim3(16, 16), 256, 0, stream>>>(
                XB2, SQ2, SC, MK, simi_eps + m, S);
        else
            gemm_dist_gk<false><<<dim3(16, 16), 256, 0, stream>>>(
                XB2, SQ2, SC, MK + m * NN, simi_eps + m, S);
    }

    // ---- Stage B: aggregation + GCN (modal-stacked N=768, split-K Z=8) ----
    agg_cvt<<<4096, 256, 0, stream>>>((const float4*)S, MK, MK + NN, MK + 2 * NN,
                                      dissim, (ushort4*)Sb);
    gemm_batch<2, false, false, false><<<dim3(2, 16, 3), 256, 0, stream>>>(
        (const ushort*)Eb3, 256, (size_t)NN * DD, (const ushort*)gcn_wt,
        (size_t)2 * 65536, nullptr, 0, TBt3, 256, (size_t)NN * DD,
        nullptr, NN, 256, 256);
    GEMMZ(Sb, TBt3, SLICE, NN, 768, NN, 8);
    slice_fin<8, true><<<1536, 256, 0, stream>>>(SLICE, Bcat, HB3, 768,
                                                 (size_t)NN * 768);
    gemm_batch<2, false, false, false><<<dim3(2, 16, 3), 256, 0, stream>>>(
        (const ushort*)HB3, 768, (size_t)256, (const ushort*)(gcn_wt + 65536),
        (size_t)2 * 65536, nullptr, 0, TBt3, 256, (size_t)NN * DD,
        nullptr, NN, 256, 256);
    GEMMZ(Sb, TBt3, SLICE, NN, 768, NN, 8);
    slice_fin<8, true><<<1536, 256, 0, stream>>>(SLICE, Bcat + 768, HB2_3, 768,
                                                 (size_t)NN * 768);
    float* IMP[3] = {I0, I1, I2};
    for (int m = 0; m < 3; ++m)
        impute_k<<<NN, 256, 0, stream>>>(Ef[m], HB2_3 + m * 256, 768,
                                         adapt_w + m * 256, adapt_b + m,
                                         MK + m * NN, IMP[m]);

    // ---- Stage C: 34-token transformer (2 chunks of 1024 samples) ----
    build_z2<<<NN * LTOK * 64 / 256, 256, 0, stream>>>(
        (const float4*)emb0, (const float4*)I0, (const float4*)I1, (const float4*)I2,
        (const float4*)PET, (const float4*)type_emb, (ushort4*)Zb);
    const int NCHUNK = NN / ACH;  // 2
    for (int li = 0; li < 2; ++li) {
        for (int c = 0; c < NCHUNK; ++c) {
            __hip_bfloat16* Zc = Zb + (size_t)c * ACROWS * DD;
            GEMM(1, true, false, Zc, attn_wt + (size_t)(li * 4) * 65536,
                 attn_b + li * 4 * 256, QKVb, ACROWS, 768, 256);
            if (li == 0)
                attn_fused<64><<<dim3(ACH, 4), 256, 0, stream>>>(QKVb, TOK, Ob, c * ACH);
            else
                attn_fused<256><<<dim3(ACH, 1), 256, 0, stream>>>(QKVb, TOK, Ob, c * ACH);
            GEMM(3, true, false, Ob, attn_wt + (size_t)(li * 4 + 3) * 65536,
                 attn_b + (li * 4 + 3) * 256, Zc, ACROWS, 256, 256);
        }
        ln_rows<false><<<NN * LTOK / 4, 256, 0, stream>>>(Zb, ln_g + (li * 2 + 0) * 256,
                                                          ln_b + (li * 2 + 0) * 256);
        for (int c = 0; c < NCHUNK; ++c) {
            __hip_bfloat16* Zc = Zb + (size_t)c * ACROWS * DD;
            GEMM(1, true, true, Zc, w1t + (size_t)li * 262144, ffn_b1 + li * 1024,
                 Hfb, ACROWS, 1024, 256);
            GEMM(3, true, false, Hfb, w2t + (size_t)li * 262144, ffn_b2 + li * 256,
                 Zc, ACROWS, 256, 1024);
        }
        ln_rows<true><<<NN * LTOK / 4, 256, 0, stream>>>(Zb, ln_g + (li * 2 + 1) * 256,
                                                         ln_b + (li * 2 + 1) * 256);
    }

    // ---- head (split-K Z=8, SLICE in UN which is now free) ----
    GEMMZ(Zb, ow1t, SLICE, NN, 512, LTOK * DD, 8);
    slice_fin<8, true><<<1024, 256, 0, stream>>>(SLICE, out_b1, Y1b, 512,
                                                 (size_t)NN * 512);
    head2<<<NN, 256, 0, stream>>>(Y1b, out_w2, out_b2, out);
    lstab_k<<<1, 64, 0, stream>>>(SC, out + NN);
}